// Round 5
// baseline (346.771 us; speedup 1.0000x reference)
//
#include <hip/hip_runtime.h>
#include <hip/hip_bf16.h>
#include <hip/hip_fp16.h>

// Problem constants (fixed by the reference setup)
#define N_NODES 50000
#define N_EDGES 800000
#define E_TOT   (N_EDGES + N_NODES)   // 850000 (self-loops appended)
#define IN_C    256
#define H1C     256                    // HEADS * HID_C = 4*64
#define HEADS   4
#define HID_C   64
#define OUT_C   128
#define N_GRAPHS 100
#define NEG_SLOPE 0.2f
#define EPS_F 1e-16f
#define SCAN_BLOCKS 196               // ceil(N_NODES / 256)

// Bucket sort (replaces atomic scatter; kills 64B partial-line write-through)
#define NBUCKET 391                   // ceil(50000 / 128), bucket = dst >> 7
#define SORT_BLOCKS 104
#define EDGES_PER_SB 8192             // 104*8192 = 851968 >= E_TOT
#define BH_STRIDE 392                 // padded bucket-hist row
#define STAGE_CAP 3072                // LDS staging (span avg ~2176, +19 sigma)

// prep_kernel block partition
#define PREP_CAST_BLOCKS   12500      // 3,200,000 uint2 / 256
#define PREP_W1_BLOCKS     256        // 65536 / 256
#define PREP_W2_BLOCKS     128        // 32768 / 256
#define PREP_HIST_BLOCKS   3321       // ceil(850000/256)
#define PREP_BOUNDS_BLOCKS 196
#define PREP_DOUT_BLOCKS   50         // 12800 floats / 256
#define PREP_TOTAL (PREP_CAST_BLOCKS + PREP_W1_BLOCKS + PREP_W2_BLOCKS + PREP_HIST_BLOCKS + PREP_BOUNDS_BLOCKS + PREP_DOUT_BLOCKS)

typedef _Float16 half8_t __attribute__((ext_vector_type(8)));
typedef float f32x4 __attribute__((ext_vector_type(4)));

// ---------------------------------------------------------------------------
// Fused prep: cast_x + W1 transpose + W2 transpose + hist + bounds + d_out=0.
// ---------------------------------------------------------------------------
__global__ __launch_bounds__(256) void prep_kernel(const float* __restrict__ x,
                                                   _Float16* __restrict__ xh,
                                                   const float* __restrict__ W1,
                                                   _Float16* __restrict__ W1t,
                                                   const float* __restrict__ W2,
                                                   _Float16* __restrict__ W2t,
                                                   const int* __restrict__ ei,
                                                   int* __restrict__ hist,
                                                   const int* __restrict__ batch,
                                                   int* __restrict__ gstart,
                                                   float* __restrict__ d_out) {
    int b = blockIdx.x;
    int tid = threadIdx.x;
    if (b < PREP_CAST_BLOCKS) {
        int idx = b * 256 + tid;                      // < 3,200,000 exactly
        float4 v = reinterpret_cast<const float4*>(x)[idx];
        union { _Float16 h[4]; uint2 u; } p;
        p.h[0] = (_Float16)v.x; p.h[1] = (_Float16)v.y;
        p.h[2] = (_Float16)v.z; p.h[3] = (_Float16)v.w;
        reinterpret_cast<uint2*>(xh)[idx] = p.u;
        return;
    }
    b -= PREP_CAST_BLOCKS;
    if (b < PREP_W1_BLOCKS) {
        int idx = b * 256 + tid;                      // < 65536 exactly
        int n = idx >> 8, k = idx & 255;
        W1t[idx] = (_Float16)W1[k * 256 + n];
        return;
    }
    b -= PREP_W1_BLOCKS;
    if (b < PREP_W2_BLOCKS) {
        int idx = b * 256 + tid;                      // < 32768 exactly
        int n = idx >> 8, k = idx & 255;
        W2t[idx] = (_Float16)W2[k * 128 + n];
        return;
    }
    b -= PREP_W2_BLOCKS;
    if (b < PREP_HIST_BLOCKS) {
        int idx = b * 256 + tid;
        if (idx < N_EDGES) {
            int d = ei[N_EDGES + idx];
            if (d >= 0 && d < N_NODES) atomicAdd(&hist[d], 1);
        } else if (idx < E_TOT) {
            atomicAdd(&hist[idx - N_EDGES], 1);       // self loop
        }
        return;
    }
    b -= PREP_HIST_BLOCKS;
    if (b < PREP_BOUNDS_BLOCKS) {   // bounds: batch sorted; each gstart entry written exactly once
        int idx = b * 256 + tid;
        if (idx >= N_NODES) return;
        int g = batch[idx];
        if (g < 0) g = 0; if (g >= N_GRAPHS) g = N_GRAPHS - 1;
        if (idx == 0) {
            for (int j = 0; j <= g; ++j) gstart[j] = 0;
        } else {
            int gp = batch[idx - 1];
            if (gp < 0) gp = 0; if (gp >= N_GRAPHS) gp = N_GRAPHS - 1;
            for (int j = gp + 1; j <= g; ++j) gstart[j] = idx;
        }
        if (idx == N_NODES - 1) {
            for (int j = g + 1; j <= N_GRAPHS; ++j) gstart[j] = N_NODES;
        }
        return;
    }
    b -= PREP_BOUNDS_BLOCKS;
    {   // zero d_out (pool accumulates atomically much later in the stream)
        int idx = b * 256 + tid;
        if (idx < N_GRAPHS * 128) d_out[idx] = 0.f;
    }
}

// ---------------------------------------------------------------------------
// CSR scan (phase2 folded into phase3)
// ---------------------------------------------------------------------------
__global__ __launch_bounds__(256) void scan_phase1(const int* __restrict__ hist,
                                                   int* __restrict__ blockSums) {
    __shared__ int lds[256];
    int idx = blockIdx.x * 256 + threadIdx.x;
    int v = (idx < N_NODES) ? hist[idx] : 0;
    lds[threadIdx.x] = v;
    __syncthreads();
#pragma unroll
    for (int off = 128; off > 0; off >>= 1) {
        if (threadIdx.x < off) lds[threadIdx.x] += lds[threadIdx.x + off];
        __syncthreads();
    }
    if (threadIdx.x == 0) blockSums[blockIdx.x] = lds[0];
}

__global__ __launch_bounds__(256) void scan_phase3(const int* __restrict__ hist,
                                                   const int* __restrict__ blockSums,
                                                   int* __restrict__ row_ptr) {
    __shared__ int lds[256];
    __shared__ int s_off;
    int b = blockIdx.x;
    int t = threadIdx.x;
    // wave 0: exclusive block offset = sum(blockSums[0..b-1])
    if (t < 64) {
        int acc = 0;
        for (int i = t; i < b; i += 64) acc += blockSums[i];
#pragma unroll
        for (int off = 32; off > 0; off >>= 1) acc += __shfl_down(acc, off);
        if (t == 0) s_off = acc;
    }
    int idx = b * 256 + t;
    int v = (idx < N_NODES) ? hist[idx] : 0;
    lds[t] = v;
    __syncthreads();
#pragma unroll
    for (int off = 1; off < 256; off <<= 1) {
        int u = (t >= off) ? lds[t - off] : 0;
        __syncthreads();
        lds[t] += u;
        __syncthreads();
    }
    int excl = lds[t] - v + s_off;
    if (idx < N_NODES) row_ptr[idx] = excl;
    if (idx == N_NODES - 1) row_ptr[N_NODES] = excl + v;
}

// ---------------------------------------------------------------------------
// Bucket counting sort: dest-sorted ssrc with coalesced writes.
// ---------------------------------------------------------------------------
__global__ __launch_bounds__(256) void bucket_hist(const int* __restrict__ ei,
                                                   int* __restrict__ bhist) {
    __shared__ int bh[NBUCKET];
    int tid = threadIdx.x;
    for (int t = tid; t < NBUCKET; t += 256) bh[t] = 0;
    __syncthreads();
    int base = blockIdx.x * EDGES_PER_SB;
#pragma unroll 4
    for (int k = 0; k < EDGES_PER_SB / 256; ++k) {
        int idx = base + k * 256 + tid;
        int d = -1;
        if (idx < N_EDGES) d = ei[N_EDGES + idx];
        else if (idx < E_TOT) d = idx - N_EDGES;
        if (d >= 0 && d < N_NODES) atomicAdd(&bh[d >> 7], 1);
    }
    __syncthreads();
    for (int t = tid; t < NBUCKET; t += 256)
        bhist[blockIdx.x * BH_STRIDE + t] = bh[t];
}

__global__ __launch_bounds__(64) void bucket_scan(int* __restrict__ bhist) {
    int j = blockIdx.x;              // bucket
    int lane = threadIdx.x;          // 0..63
    int carry = 0;
    for (int b0 = 0; b0 < SORT_BLOCKS; b0 += 64) {
        int b = b0 + lane;
        int v = (b < SORT_BLOCKS) ? bhist[b * BH_STRIDE + j] : 0;
        int inc = v;
#pragma unroll
        for (int off = 1; off < 64; off <<= 1) {
            int u = __shfl_up(inc, off);
            if (lane >= off) inc += u;
        }
        if (b < SORT_BLOCKS) bhist[b * BH_STRIDE + j] = inc - v + carry;
        carry += __shfl(inc, 63);
    }
}

__global__ __launch_bounds__(256) void bucket_bin(const int* __restrict__ ei,
                                                  const int* __restrict__ row_ptr,
                                                  const int* __restrict__ bhist,
                                                  int* __restrict__ ebuf) {
    __shared__ int cur[NBUCKET];
    int tid = threadIdx.x;
    for (int t = tid; t < NBUCKET; t += 256)
        cur[t] = row_ptr[t << 7] + bhist[blockIdx.x * BH_STRIDE + t];
    __syncthreads();
    int base = blockIdx.x * EDGES_PER_SB;
#pragma unroll 4
    for (int k = 0; k < EDGES_PER_SB / 256; ++k) {
        int idx = base + k * 256 + tid;
        int s = 0, d = -1;
        if (idx < N_EDGES) { s = ei[idx]; d = ei[N_EDGES + idx]; }
        else if (idx < E_TOT) { s = idx - N_EDGES; d = s; }
        if (d >= 0 && d < N_NODES) {
            int p = atomicAdd(&cur[d >> 7], 1);
            ebuf[p] = (s & 0xFFFF) | ((d & 127) << 16);
        }
    }
}

__global__ __launch_bounds__(256) void bucket_sort(const int* __restrict__ row_ptr,
                                                   const int* __restrict__ ebuf,
                                                   int* __restrict__ ssrc) {
    __shared__ int cur2[128];
    __shared__ int stage[STAGE_CAP];
    int j = blockIdx.x;
    int tid = threadIdx.x;
    int jn0 = j << 7;
    int nEnd = jn0 + 128; if (nEnd > N_NODES) nEnd = N_NODES;
    int lo = row_ptr[jn0];
    int hi = row_ptr[nEnd];
    int span = hi - lo;
    if (tid < nEnd - jn0) cur2[tid] = row_ptr[jn0 + tid] - lo;
    __syncthreads();
    if (span <= STAGE_CAP) {
        for (int t = lo + tid; t < hi; t += 256) {
            int v = ebuf[t];
            int p = atomicAdd(&cur2[v >> 16], 1);
            stage[p] = v & 0xFFFF;
        }
        __syncthreads();
        for (int t = tid; t < span; t += 256) ssrc[lo + t] = stage[t];
    } else {                         // overflow fallback (never for this input)
        for (int t = lo + tid; t < hi; t += 256) {
            int v = ebuf[t];
            int p = atomicAdd(&cur2[v >> 16], 1);
            ssrc[lo + p] = v & 0xFFFF;
        }
    }
}

// ---------------------------------------------------------------------------
// MFMA fp16 GEMM with folded attention dots. LDS ldk padded 48 -> 56 halfs
// (112B row stride): ds_read_b128 bank pattern (28*mlane+4*quad)%32 is 2-way
// (free, m136) vs 4-way at 48 (800K conflicts/dispatch measured round 4).
// LDS 29.7KB; occupancy stays VGPR-limited at 4 blocks/CU.
// ---------------------------------------------------------------------------
__global__ __launch_bounds__(256) void gemm_mfma_kernel(const _Float16* __restrict__ A,
                                                        const _Float16* __restrict__ Bt,
                                                        _Float16* __restrict__ C,
                                                        int mode,
                                                        const float* __restrict__ attS,
                                                        const float* __restrict__ attD,
                                                        float* __restrict__ a_src_o,
                                                        float* __restrict__ a_dst_o,
                                                        int M, int N) {
    __shared__ _Float16 As[128][56];   // ldk=56: 16B-aligned rows, 2-way banks
    __shared__ _Float16 Bs[128][56];
    __shared__ float lds_ps[128];
    __shared__ float lds_pd[128];
    const int tid = threadIdx.x;
    const int tileM = blockIdx.x * 128;
    const int tileN = blockIdx.y * 128;
    const int w = tid >> 6, lane = tid & 63;
    const int wm = (w >> 1) * 64, wn = (w & 1) * 64;
    const int quad = lane >> 4, mlane = lane & 15;
    const int srow = tid >> 2;           // 0..63 (rows srow and srow+64)
    const int schunk = (tid & 3) * 8;    // f16 offset within 32-k slab

    f32x4 zero = {0.f, 0.f, 0.f, 0.f};
    f32x4 acc[4][4];
#pragma unroll
    for (int i = 0; i < 4; ++i)
#pragma unroll
        for (int j = 0; j < 4; ++j) acc[i][j] = zero;

    const uint4* Av = reinterpret_cast<const uint4*>(A);   // 8 f16 per uint4; 32/row
    const uint4* Bv = reinterpret_cast<const uint4*>(Bt);
    const int r0 = tileM + srow, r1 = r0 + 64;
    const bool ok0 = r0 < M, ok1 = r1 < M;
    const int bn0 = tileN + srow, bn1 = bn0 + 64;          // N mult of 128: no guard
    const uint4 z4 = make_uint4(0, 0, 0, 0);

    for (int k0 = 0; k0 < 256; k0 += 32) {
        const int kc = (k0 >> 3) + (tid & 3);
        uint4 a0 = ok0 ? Av[(size_t)r0 * 32 + kc] : z4;
        uint4 a1 = ok1 ? Av[(size_t)r1 * 32 + kc] : z4;
        uint4 b0 = Bv[(size_t)bn0 * 32 + kc];
        uint4 b1 = Bv[(size_t)bn1 * 32 + kc];
        __syncthreads();
        *reinterpret_cast<uint4*>(&As[srow][schunk]) = a0;
        *reinterpret_cast<uint4*>(&As[srow + 64][schunk]) = a1;
        *reinterpret_cast<uint4*>(&Bs[srow][schunk]) = b0;
        *reinterpret_cast<uint4*>(&Bs[srow + 64][schunk]) = b1;
        __syncthreads();
        half8_t af[4], bf[4];
#pragma unroll
        for (int mt = 0; mt < 4; ++mt)
            af[mt] = *reinterpret_cast<const half8_t*>(&As[wm + mt * 16 + mlane][quad * 8]);
#pragma unroll
        for (int nt = 0; nt < 4; ++nt)
            bf[nt] = *reinterpret_cast<const half8_t*>(&Bs[wn + nt * 16 + mlane][quad * 8]);
#pragma unroll
        for (int mt = 0; mt < 4; ++mt)
#pragma unroll
            for (int nt = 0; nt < 4; ++nt)
                acc[mt][nt] = __builtin_amdgcn_mfma_f32_16x16x32_f16(af[mt], bf[nt], acc[mt][nt], 0, 0, 0);
    }
#pragma unroll
    for (int mt = 0; mt < 4; ++mt) {
#pragma unroll
        for (int i = 0; i < 4; ++i) {
            int row = tileM + wm + mt * 16 + quad * 4 + i;
            if (row < M) {
                _Float16* cp = C + (size_t)row * N + tileN + wn;
#pragma unroll
                for (int nt = 0; nt < 4; ++nt)
                    cp[nt * 16 + mlane] = (_Float16)acc[mt][nt][i];
            }
        }
    }
    if (mode == 1) {
        int hd = (tileN + wn) >> 6;          // this wave's head (64 cols/head)
        float as[4], ad[4];
#pragma unroll
        for (int nt = 0; nt < 4; ++nt) {
            as[nt] = attS[hd * 64 + nt * 16 + mlane];
            ad[nt] = attD[hd * 64 + nt * 16 + mlane];
        }
#pragma unroll
        for (int mt = 0; mt < 4; ++mt) {
#pragma unroll
            for (int i = 0; i < 4; ++i) {
                float ps = acc[mt][0][i] * as[0] + acc[mt][1][i] * as[1]
                         + acc[mt][2][i] * as[2] + acc[mt][3][i] * as[3];
                float pd = acc[mt][0][i] * ad[0] + acc[mt][1][i] * ad[1]
                         + acc[mt][2][i] * ad[2] + acc[mt][3][i] * ad[3];
#pragma unroll
                for (int off = 1; off < 16; off <<= 1) {
                    ps += __shfl_xor(ps, off);
                    pd += __shfl_xor(pd, off);
                }
                if (mlane == 0) {
                    int row = tileM + wm + mt * 16 + quad * 4 + i;
                    if (row < M) {
                        a_src_o[row * 4 + hd] = ps;
                        a_dst_o[row * 4 + hd] = pd;
                    }
                }
            }
        }
    } else if (mode == 2) {
        // single-head: wave covers cols wn..wn+63 of 128 -> partial dots
        float as[4], ad[4];
#pragma unroll
        for (int nt = 0; nt < 4; ++nt) {
            as[nt] = attS[wn + nt * 16 + mlane];
            ad[nt] = attD[wn + nt * 16 + mlane];
        }
        float psa[4][4], pda[4][4];
#pragma unroll
        for (int mt = 0; mt < 4; ++mt) {
#pragma unroll
            for (int i = 0; i < 4; ++i) {
                float ps = acc[mt][0][i] * as[0] + acc[mt][1][i] * as[1]
                         + acc[mt][2][i] * as[2] + acc[mt][3][i] * as[3];
                float pd = acc[mt][0][i] * ad[0] + acc[mt][1][i] * ad[1]
                         + acc[mt][2][i] * ad[2] + acc[mt][3][i] * ad[3];
#pragma unroll
                for (int off = 1; off < 16; off <<= 1) {
                    ps += __shfl_xor(ps, off);
                    pd += __shfl_xor(pd, off);
                }
                psa[mt][i] = ps; pda[mt][i] = pd;
            }
        }
        __syncthreads();
        if (wn == 0 && mlane == 0) {
#pragma unroll
            for (int mt = 0; mt < 4; ++mt)
#pragma unroll
                for (int i = 0; i < 4; ++i) {
                    int lr = wm + mt * 16 + quad * 4 + i;
                    lds_ps[lr] = psa[mt][i];
                    lds_pd[lr] = pda[mt][i];
                }
        }
        __syncthreads();
        if (wn == 64 && mlane == 0) {
#pragma unroll
            for (int mt = 0; mt < 4; ++mt)
#pragma unroll
                for (int i = 0; i < 4; ++i) {
                    int lr = wm + mt * 16 + quad * 4 + i;
                    int row = tileM + lr;
                    if (row < M) {
                        a_src_o[row] = psa[mt][i] + lds_ps[lr];
                        a_dst_o[row] = pda[mt][i] + lds_pd[lr];
                    }
                }
        }
    }
}

__device__ __forceinline__ float lrelu(float x) { return x > 0.f ? x : NEG_SLOPE * x; }

// ---------------------------------------------------------------------------
// Edge aggregation, layer 1 — round-2 body + NEW full software pipeline:
// the 512B payload GATHERS (not just indices) are issued one iteration
// ahead; indices run two ahead. Doubles per-wave memory-level parallelism —
// the untested lever (r1 pipelined only the 4B index; r2 cut instructions;
// r3 cut bytes; none moved the 65us latency floor).
// ---------------------------------------------------------------------------
__global__ __launch_bounds__(256) void edge1_kernel(const int* __restrict__ row_ptr,
                                                    const int* __restrict__ ssrc,
                                                    const __half* __restrict__ h1h,
                                                    const float* __restrict__ a_src,
                                                    const float* __restrict__ a_dst,
                                                    const float* __restrict__ bias,
                                                    __half* __restrict__ out) {
    int node = blockIdx.x * 4 + (threadIdx.x >> 6);
    int lane = threadIdx.x & 63;
    int hf   = lane >> 5;              // 0: even edges, 1: odd edges
    int cl   = lane & 31;              // channel-lane: ch [cl*8, cl*8+8)
    int hd   = cl >> 3;                // head = ch/64
    int start = row_ptr[node], end = row_ptr[node + 1];
    int em1 = end - 1;                 // >= start (self-loop guarantees deg>=1)
    float adh = a_dst[node * 4 + hd];

    const uint4* h1v = reinterpret_cast<const uint4*>(h1h);   // 8 halfs/uint4; 32 per row
    float4 aA0 = make_float4(0.f,0.f,0.f,0.f), aA1 = make_float4(0.f,0.f,0.f,0.f);
    float4 aB0 = make_float4(0.f,0.f,0.f,0.f), aB1 = make_float4(0.f,0.f,0.f,0.f);
    float s = 0.f;

    // prologue: iteration-0 payloads + iteration-1 indices
    int e0 = start + hf, e1 = start + 2 + hf;
    int i0 = ssrc[e0 <= em1 ? e0 : em1];
    int i1 = ssrc[e1 <= em1 ? e1 : em1];
    uint4 q0 = h1v[(size_t)i0 * 32 + cl];
    uint4 q1 = h1v[(size_t)i1 * 32 + cl];
    float r0 = a_src[i0 * 4 + hd];
    float r1 = a_src[i1 * 4 + hd];
    int f0 = start + 4 + hf, f1 = start + 6 + hf;
    int j0 = ssrc[f0 <= em1 ? f0 : em1];
    int j1 = ssrc[f1 <= em1 ? f1 : em1];

    for (int e = start; e < end; e += 4) {
        uint4 p0, p1; float t0, t1;
        if (e + 4 < end) {             // wave-uniform: issue next payloads
            p0 = h1v[(size_t)j0 * 32 + cl];
            p1 = h1v[(size_t)j1 * 32 + cl];
            t0 = a_src[j0 * 4 + hd];
            t1 = a_src[j1 * 4 + hd];
        }
        int g0 = e + 8 + hf, g1 = e + 10 + hf;
        int k0 = ssrc[g0 <= em1 ? g0 : em1];
        int k1 = ssrc[g1 <= em1 ? g1 : em1];
        // consume current
        float w0 = (e + hf < end)     ? __expf(lrelu(r0 + adh)) : 0.f;
        float w1 = (e + 2 + hf < end) ? __expf(lrelu(r1 + adh)) : 0.f;
        s += w0 + w1;
        float2 f;
        f = __half22float2(*reinterpret_cast<const __half2*>(&q0.x)); aA0.x += w0*f.x; aA0.y += w0*f.y;
        f = __half22float2(*reinterpret_cast<const __half2*>(&q0.y)); aA0.z += w0*f.x; aA0.w += w0*f.y;
        f = __half22float2(*reinterpret_cast<const __half2*>(&q0.z)); aA1.x += w0*f.x; aA1.y += w0*f.y;
        f = __half22float2(*reinterpret_cast<const __half2*>(&q0.w)); aA1.z += w0*f.x; aA1.w += w0*f.y;
        f = __half22float2(*reinterpret_cast<const __half2*>(&q1.x)); aB0.x += w1*f.x; aB0.y += w1*f.y;
        f = __half22float2(*reinterpret_cast<const __half2*>(&q1.y)); aB0.z += w1*f.x; aB0.w += w1*f.y;
        f = __half22float2(*reinterpret_cast<const __half2*>(&q1.z)); aB1.x += w1*f.x; aB1.y += w1*f.y;
        f = __half22float2(*reinterpret_cast<const __half2*>(&q1.w)); aB1.z += w1*f.x; aB1.w += w1*f.y;
        // rotate pipeline
        q0 = p0; q1 = p1; r0 = t0; r1 = t1; j0 = k0; j1 = k1;
    }
    float4 c0, c1;
    c0.x = aA0.x + aB0.x; c0.y = aA0.y + aB0.y; c0.z = aA0.z + aB0.z; c0.w = aA0.w + aB0.w;
    c1.x = aA1.x + aB1.x; c1.y = aA1.y + aB1.y; c1.z = aA1.z + aB1.z; c1.w = aA1.w + aB1.w;
    // fold even/odd halves (lane L and L+32 cover the same channels & head)
    c0.x += __shfl_xor(c0.x, 32); c0.y += __shfl_xor(c0.y, 32);
    c0.z += __shfl_xor(c0.z, 32); c0.w += __shfl_xor(c0.w, 32);
    c1.x += __shfl_xor(c1.x, 32); c1.y += __shfl_xor(c1.y, 32);
    c1.z += __shfl_xor(c1.z, 32); c1.w += __shfl_xor(c1.w, 32);
    s += __shfl_xor(s, 32);
    float inv = 1.0f / (s + EPS_F);
    if (lane < 32) {
        const float4* b4 = reinterpret_cast<const float4*>(bias);
        float4 b0 = b4[cl * 2], b1 = b4[cl * 2 + 1];
        union { _Float16 h[8]; uint4 u; } st;
        st.h[0] = (_Float16)fmaxf(c0.x * inv + b0.x, 0.f);
        st.h[1] = (_Float16)fmaxf(c0.y * inv + b0.y, 0.f);
        st.h[2] = (_Float16)fmaxf(c0.z * inv + b0.z, 0.f);
        st.h[3] = (_Float16)fmaxf(c0.w * inv + b0.w, 0.f);
        st.h[4] = (_Float16)fmaxf(c1.x * inv + b1.x, 0.f);
        st.h[5] = (_Float16)fmaxf(c1.y * inv + b1.y, 0.f);
        st.h[6] = (_Float16)fmaxf(c1.z * inv + b1.z, 0.f);
        st.h[7] = (_Float16)fmaxf(c1.w * inv + b1.w, 0.f);
        reinterpret_cast<uint4*>(out)[(size_t)node * 32 + cl] = st.u;
    }
}

// ---------------------------------------------------------------------------
// Edge aggregation, layer 2 — round-2 body + same full payload pipeline.
// ---------------------------------------------------------------------------
__global__ __launch_bounds__(256) void edge2_kernel(const int* __restrict__ row_ptr,
                                                    const int* __restrict__ ssrc,
                                                    const __half* __restrict__ h2h,
                                                    const float* __restrict__ a_src,
                                                    const float* __restrict__ a_dst,
                                                    const float* __restrict__ bias,
                                                    float* __restrict__ out) {
    int lane = threadIdx.x & 63;
    int node = blockIdx.x * 8 + ((threadIdx.x >> 6) << 1) + (lane >> 5);
    int sub  = (lane >> 4) & 1;        // edge sub-slot within the 32-lane node group
    int cl   = lane & 15;              // channel-lane: ch [cl*8, cl*8+8)
    int start = row_ptr[node], end = row_ptr[node + 1];
    int em1 = end - 1;
    float ad = a_dst[node];

    const uint4* h2v = reinterpret_cast<const uint4*>(h2h);   // 8 halfs/uint4; 16 per row
    float4 aA0 = make_float4(0.f,0.f,0.f,0.f), aA1 = make_float4(0.f,0.f,0.f,0.f);
    float4 aB0 = make_float4(0.f,0.f,0.f,0.f), aB1 = make_float4(0.f,0.f,0.f,0.f);
    float s = 0.f;

    int e0 = start + sub, e1 = start + 2 + sub;
    int i0 = ssrc[e0 <= em1 ? e0 : em1];
    int i1 = ssrc[e1 <= em1 ? e1 : em1];
    uint4 q0 = h2v[(size_t)i0 * 16 + cl];
    uint4 q1 = h2v[(size_t)i1 * 16 + cl];
    float r0 = a_src[i0];
    float r1 = a_src[i1];
    int f0 = start + 4 + sub, f1 = start + 6 + sub;
    int j0 = ssrc[f0 <= em1 ? f0 : em1];
    int j1 = ssrc[f1 <= em1 ? f1 : em1];

    for (int e = start; e < end; e += 4) {
        uint4 p0, p1; float t0, t1;
        if (e + 4 < end) {
            p0 = h2v[(size_t)j0 * 16 + cl];
            p1 = h2v[(size_t)j1 * 16 + cl];
            t0 = a_src[j0];
            t1 = a_src[j1];
        }
        int g0 = e + 8 + sub, g1 = e + 10 + sub;
        int k0 = ssrc[g0 <= em1 ? g0 : em1];
        int k1 = ssrc[g1 <= em1 ? g1 : em1];
        float w0 = (e + sub < end)     ? __expf(lrelu(r0 + ad)) : 0.f;
        float w1 = (e + 2 + sub < end) ? __expf(lrelu(r1 + ad)) : 0.f;
        s += w0 + w1;
        float2 f;
        f = __half22float2(*reinterpret_cast<const __half2*>(&q0.x)); aA0.x += w0*f.x; aA0.y += w0*f.y;
        f = __half22float2(*reinterpret_cast<const __half2*>(&q0.y)); aA0.z += w0*f.x; aA0.w += w0*f.y;
        f = __half22float2(*reinterpret_cast<const __half2*>(&q0.z)); aA1.x += w0*f.x; aA1.y += w0*f.y;
        f = __half22float2(*reinterpret_cast<const __half2*>(&q0.w)); aA1.z += w0*f.x; aA1.w += w0*f.y;
        f = __half22float2(*reinterpret_cast<const __half2*>(&q1.x)); aB0.x += w1*f.x; aB0.y += w1*f.y;
        f = __half22float2(*reinterpret_cast<const __half2*>(&q1.y)); aB0.z += w1*f.x; aB0.w += w1*f.y;
        f = __half22float2(*reinterpret_cast<const __half2*>(&q1.z)); aB1.x += w1*f.x; aB1.y += w1*f.y;
        f = __half22float2(*reinterpret_cast<const __half2*>(&q1.w)); aB1.z += w1*f.x; aB1.w += w1*f.y;
        q0 = p0; q1 = p1; r0 = t0; r1 = t1; j0 = k0; j1 = k1;
    }
    float4 c0, c1;
    c0.x = aA0.x + aB0.x; c0.y = aA0.y + aB0.y; c0.z = aA0.z + aB0.z; c0.w = aA0.w + aB0.w;
    c1.x = aA1.x + aB1.x; c1.y = aA1.y + aB1.y; c1.z = aA1.z + aB1.z; c1.w = aA1.w + aB1.w;
    // fold the two 16-lane edge groups within this node's 32-lane half
    c0.x += __shfl_xor(c0.x, 16); c0.y += __shfl_xor(c0.y, 16);
    c0.z += __shfl_xor(c0.z, 16); c0.w += __shfl_xor(c0.w, 16);
    c1.x += __shfl_xor(c1.x, 16); c1.y += __shfl_xor(c1.y, 16);
    c1.z += __shfl_xor(c1.z, 16); c1.w += __shfl_xor(c1.w, 16);
    s += __shfl_xor(s, 16);
    float inv = 1.0f / (s + EPS_F);
    if (sub == 0) {                     // 16 lanes per node write the 128-ch row
        const float4* b4 = reinterpret_cast<const float4*>(bias);
        float4 b0 = b4[cl * 2], b1 = b4[cl * 2 + 1];
        float4 o0, o1;
        o0.x = fmaxf(c0.x * inv + b0.x, 0.f);
        o0.y = fmaxf(c0.y * inv + b0.y, 0.f);
        o0.z = fmaxf(c0.z * inv + b0.z, 0.f);
        o0.w = fmaxf(c0.w * inv + b0.w, 0.f);
        o1.x = fmaxf(c1.x * inv + b1.x, 0.f);
        o1.y = fmaxf(c1.y * inv + b1.y, 0.f);
        o1.z = fmaxf(c1.z * inv + b1.z, 0.f);
        o1.w = fmaxf(c1.w * inv + b1.w, 0.f);
        float4* o4 = reinterpret_cast<float4*>(out) + (size_t)node * 32 + cl * 2;
        o4[0] = o0;
        o4[1] = o1;
    }
}

// ---------------------------------------------------------------------------
// Pooling with folded mean division.
// ---------------------------------------------------------------------------
#define POOL_CHUNK 64
__global__ __launch_bounds__(128) void pool_kernel(const float* __restrict__ out2,
                                                   const int* __restrict__ batch,
                                                   const int* __restrict__ gstart,
                                                   float* __restrict__ d_out) {
    int c = threadIdx.x;                 // channel 0..127
    int node0 = blockIdx.x * POOL_CHUNK;
    int nodeEnd = node0 + POOL_CHUNK; if (nodeEnd > N_NODES) nodeEnd = N_NODES;
    if (node0 >= N_NODES) return;
    int gprev = batch[node0];
    float acc = 0.f;
    for (int node = node0; node < nodeEnd; ++node) {
        int g = batch[node];
        if (g != gprev) {
            if (gprev >= 0 && gprev < N_GRAPHS) {
                float cnt = (float)(gstart[gprev + 1] - gstart[gprev]);
                if (cnt < 1.f) cnt = 1.f;
                atomicAdd(&d_out[gprev * 128 + c], acc / cnt);
            }
            acc = 0.f;
            gprev = g;
        }
        acc += out2[(size_t)node * 128 + c];
    }
    if (gprev >= 0 && gprev < N_GRAPHS) {
        float cnt = (float)(gstart[gprev + 1] - gstart[gprev]);
        if (cnt < 1.f) cnt = 1.f;
        atomicAdd(&d_out[gprev * 128 + c], acc / cnt);
    }
}

// ---------------------------------------------------------------------------
extern "C" void kernel_launch(void* const* d_in, const int* in_sizes, int n_in,
                              void* d_out_v, int out_size, void* d_ws, size_t ws_size,
                              hipStream_t stream) {
    const float* x      = (const float*)d_in[0];
    const float* W1     = (const float*)d_in[1];
    const float* att_s1 = (const float*)d_in[2];
    const float* att_d1 = (const float*)d_in[3];
    const float* bias1  = (const float*)d_in[4];
    const float* W2     = (const float*)d_in[5];
    const float* att_s2 = (const float*)d_in[6];
    const float* att_d2 = (const float*)d_in[7];
    const float* bias2  = (const float*)d_in[8];
    const int*   ei     = (const int*)d_in[9];
    const int*   batch  = (const int*)d_in[10];
    float* d_out = (float*)d_out_v;

    // Workspace layout (float units):
    //  [0, 6.4M)        xh fp16 [N,256]      ... later reused as h2h fp16 [N,128]
    //  [6.4M, 12.8M)    h1h fp16 [N,256]     ... later reused as out2 fp32 [N,128]
    //  [12.8M, 19.2M)   out1h fp16 [N,256]
    //  [19.2M, ...)     attention scalars + CSR ints + sort buffers + W transposes
    float* ws = (float*)d_ws;
    _Float16* xh    = (_Float16*)ws;
    _Float16* h1h   = (_Float16*)(ws + 6400000);
    _Float16* out1h = (_Float16*)(ws + 12800000);
    _Float16* h2h   = (_Float16*)ws;            // xh dead after GEMM1
    float*    out2  = ws + 6400000;             // h1h dead after edge1
    float* a_src1 = ws + 19200000;              // N*4
    float* a_dst1 = a_src1 + 200000;            // N*4
    float* a_src2 = a_dst1 + 200000;            // N
    float* a_dst2 = a_src2 + 50000;             // N
    int* hist     = (int*)(a_dst2 + 50000);     // N
    int* row_ptr  = hist + 50000;               // N+1 (padded to 50016)
    int* ssrc     = row_ptr + 50016;            // E_TOT
    int* ebuf     = ssrc + 850000;              // SORT_BLOCKS*EDGES_PER_SB pad
    int* bhist    = ebuf + 851968;              // SORT_BLOCKS * BH_STRIDE
    int* gstart   = bhist + (SORT_BLOCKS * BH_STRIDE); // N_GRAPHS+1 (pad 128)
    int* blockSums = gstart + 128;              // SCAN_BLOCKS (pad 256)
    _Float16* W1t = (_Float16*)(blockSums + 256); // 65536 halfs [256][256]
    _Float16* W2t = W1t + 65536;                  // 32768 halfs [128][256]

    // Zero what must be zero (d_out zeroing folded into prep_kernel)
    hipMemsetAsync(hist, 0, N_NODES * sizeof(int), stream);

    // Fused prep: cast x, transpose W1/W2, histogram, graph bounds, d_out=0
    prep_kernel<<<PREP_TOTAL, 256, 0, stream>>>(x, xh, W1, W1t, W2, W2t,
                                                ei, hist, batch, gstart, d_out);

    // CSR scan
    scan_phase1<<<SCAN_BLOCKS, 256, 0, stream>>>(hist, blockSums);
    scan_phase3<<<SCAN_BLOCKS, 256, 0, stream>>>(hist, blockSums, row_ptr);

    // Bucket counting sort (replaces the partial-line-write-through scatter)
    bucket_hist<<<SORT_BLOCKS, 256, 0, stream>>>(ei, bhist);
    bucket_scan<<<NBUCKET, 64, 0, stream>>>(bhist);
    bucket_bin<<<SORT_BLOCKS, 256, 0, stream>>>(ei, row_ptr, bhist, ebuf);
    bucket_sort<<<NBUCKET, 256, 0, stream>>>(row_ptr, ebuf, ssrc);

    // Layer 1: h1 = x @ W1 (MFMA fp16, att1 folded into epilogue, mode 1)
    {
        dim3 g((N_NODES + 127) / 128, H1C / 128);
        gemm_mfma_kernel<<<g, 256, 0, stream>>>(xh, W1t, h1h, 1,
                                                att_s1, att_d1, a_src1, a_dst1,
                                                N_NODES, H1C);
    }
    edge1_kernel<<<N_NODES / 4, 256, 0, stream>>>(row_ptr, ssrc, (const __half*)h1h,
                                                  a_src1, a_dst1, bias1, (__half*)out1h);

    // Layer 2: h2 = out1 @ W2 (MFMA fp16, att2 folded via LDS combine, mode 2)
    {
        dim3 g((N_NODES + 127) / 128, OUT_C / 128);
        gemm_mfma_kernel<<<g, 256, 0, stream>>>(out1h, W2t, h2h, 2,
                                                att_s2, att_d2, a_src2, a_dst2,
                                                N_NODES, OUT_C);
    }
    edge2_kernel<<<N_NODES / 8, 256, 0, stream>>>(row_ptr, ssrc, (const __half*)h2h,
                                                  a_src2, a_dst2, bias2, out2);

    // Pooling (mean division folded into the atomic flush)
    pool_kernel<<<(N_NODES + POOL_CHUNK - 1) / POOL_CHUNK, 128, 0, stream>>>(out2, batch, gstart, d_out);
}

// Round 6
// 302.200 us; speedup vs baseline: 1.1475x; 1.1475x over previous
//
#include <hip/hip_runtime.h>
#include <hip/hip_bf16.h>
#include <hip/hip_fp16.h>

// Problem constants (fixed by the reference setup)
#define N_NODES 50000
#define N_EDGES 800000
#define E_TOT   (N_EDGES + N_NODES)   // 850000 (self-loops appended)
#define IN_C    256
#define H1C     256                    // HEADS * HID_C = 4*64
#define HEADS   4
#define HID_C   64
#define OUT_C   128
#define N_GRAPHS 100
#define NEG_SLOPE 0.2f
#define EPS_F 1e-16f

// Bucket sort (replaces atomic scatter; kills 64B partial-line write-through)
#define NBUCKET 391                   // ceil(50000 / 128), bucket = dst >> 7
#define SORT_BLOCKS 104
#define EDGES_PER_SB 8192             // 104*8192 = 851968 >= E_TOT
#define BH_STRIDE 392                 // padded bucket-hist row
#define STAGE_CAP 3072                // LDS staging (span avg ~2176, +19 sigma)

// prep_kernel block partition (bhist FIRST: heaviest blocks dispatch earliest)
#define PREP_BHIST_BLOCKS  104
#define PREP_CAST_BLOCKS   12500      // 3,200,000 uint2 / 256
#define PREP_W1_BLOCKS     256        // 65536 / 256
#define PREP_W2_BLOCKS     128        // 32768 / 256
#define PREP_BOUNDS_BLOCKS 196
#define PREP_DOUT_BLOCKS   50         // 12800 floats / 256
#define PREP_TOTAL (PREP_BHIST_BLOCKS + PREP_CAST_BLOCKS + PREP_W1_BLOCKS + PREP_W2_BLOCKS + PREP_BOUNDS_BLOCKS + PREP_DOUT_BLOCKS)

typedef _Float16 half8_t __attribute__((ext_vector_type(8)));
typedef float f32x4 __attribute__((ext_vector_type(4)));

// ---------------------------------------------------------------------------
// Fused prep: bucket-hist + cast_x + W1t + W2t + bounds + d_out=0.
// The old per-node global-atomic histogram (850K device-scope atomicAdds,
// same cross-XCD partial-line pathology as the round-3 scatter) is GONE:
// per-node counts are now derived inside bucket_sort from ebuf.
// ---------------------------------------------------------------------------
__global__ __launch_bounds__(256) void prep_kernel(const float* __restrict__ x,
                                                   _Float16* __restrict__ xh,
                                                   const float* __restrict__ W1,
                                                   _Float16* __restrict__ W1t,
                                                   const float* __restrict__ W2,
                                                   _Float16* __restrict__ W2t,
                                                   const int* __restrict__ ei,
                                                   int* __restrict__ bhist,
                                                   const int* __restrict__ batch,
                                                   int* __restrict__ gstart,
                                                   float* __restrict__ d_out) {
    __shared__ int bh[NBUCKET];
    int b = blockIdx.x;
    int tid = threadIdx.x;
    if (b < PREP_BHIST_BLOCKS) {      // per-(block,bucket) histogram, LDS atomics
        for (int t = tid; t < NBUCKET; t += 256) bh[t] = 0;
        __syncthreads();
        int base = b * EDGES_PER_SB;
#pragma unroll 4
        for (int k = 0; k < EDGES_PER_SB / 256; ++k) {
            int idx = base + k * 256 + tid;
            int d = -1;
            if (idx < N_EDGES) d = ei[N_EDGES + idx];
            else if (idx < E_TOT) d = idx - N_EDGES;
            if (d >= 0 && d < N_NODES) atomicAdd(&bh[d >> 7], 1);
        }
        __syncthreads();
        for (int t = tid; t < NBUCKET; t += 256)
            bhist[b * BH_STRIDE + t] = bh[t];
        return;
    }
    b -= PREP_BHIST_BLOCKS;
    if (b < PREP_CAST_BLOCKS) {
        int idx = b * 256 + tid;                      // < 3,200,000 exactly
        float4 v = reinterpret_cast<const float4*>(x)[idx];
        union { _Float16 h[4]; uint2 u; } p;
        p.h[0] = (_Float16)v.x; p.h[1] = (_Float16)v.y;
        p.h[2] = (_Float16)v.z; p.h[3] = (_Float16)v.w;
        reinterpret_cast<uint2*>(xh)[idx] = p.u;
        return;
    }
    b -= PREP_CAST_BLOCKS;
    if (b < PREP_W1_BLOCKS) {
        int idx = b * 256 + tid;                      // < 65536 exactly
        int n = idx >> 8, k = idx & 255;
        W1t[idx] = (_Float16)W1[k * 256 + n];
        return;
    }
    b -= PREP_W1_BLOCKS;
    if (b < PREP_W2_BLOCKS) {
        int idx = b * 256 + tid;                      // < 32768 exactly
        int n = idx >> 8, k = idx & 255;
        W2t[idx] = (_Float16)W2[k * 128 + n];
        return;
    }
    b -= PREP_W2_BLOCKS;
    if (b < PREP_BOUNDS_BLOCKS) {   // bounds: batch sorted; each gstart entry written exactly once
        int idx = b * 256 + tid;
        if (idx >= N_NODES) return;
        int g = batch[idx];
        if (g < 0) g = 0; if (g >= N_GRAPHS) g = N_GRAPHS - 1;
        if (idx == 0) {
            for (int j = 0; j <= g; ++j) gstart[j] = 0;
        } else {
            int gp = batch[idx - 1];
            if (gp < 0) gp = 0; if (gp >= N_GRAPHS) gp = N_GRAPHS - 1;
            for (int j = gp + 1; j <= g; ++j) gstart[j] = idx;
        }
        if (idx == N_NODES - 1) {
            for (int j = g + 1; j <= N_GRAPHS; ++j) gstart[j] = N_NODES;
        }
        return;
    }
    b -= PREP_BOUNDS_BLOCKS;
    {   // zero d_out (pool accumulates atomically much later in the stream)
        int idx = b * 256 + tid;
        if (idx < N_GRAPHS * 128) d_out[idx] = 0.f;
    }
}

// ---------------------------------------------------------------------------
// Bucket counting sort pipeline. row_ptr is a BYPRODUCT of the sort now
// (per-node counts derived from ebuf inside bucket_sort) — the old
// hist/scan_phase1/scan_phase3/memset chain is deleted.
// ---------------------------------------------------------------------------
__global__ __launch_bounds__(64) void bucket_scan(int* __restrict__ bhist,
                                                  int* __restrict__ btot) {
    int j = blockIdx.x;              // bucket
    int lane = threadIdx.x;          // 0..63
    int carry = 0;
    for (int b0 = 0; b0 < SORT_BLOCKS; b0 += 64) {
        int b = b0 + lane;
        int v = (b < SORT_BLOCKS) ? bhist[b * BH_STRIDE + j] : 0;
        int inc = v;
#pragma unroll
        for (int off = 1; off < 64; off <<= 1) {
            int u = __shfl_up(inc, off);
            if (lane >= off) inc += u;
        }
        if (b < SORT_BLOCKS) bhist[b * BH_STRIDE + j] = inc - v + carry;
        carry += __shfl(inc, 63);
    }
    if (lane == 0) btot[j] = carry;  // bucket total (all blocks)
}

__global__ __launch_bounds__(512) void bucket_base(const int* __restrict__ btot,
                                                   int* __restrict__ bbase) {
    __shared__ int lds[512];
    int t = threadIdx.x;
    int v = (t < NBUCKET) ? btot[t] : 0;
    lds[t] = v;
    __syncthreads();
#pragma unroll
    for (int off = 1; off < 512; off <<= 1) {
        int u = (t >= off) ? lds[t - off] : 0;
        __syncthreads();
        lds[t] += u;
        __syncthreads();
    }
    if (t < NBUCKET) bbase[t] = lds[t] - v;       // exclusive
    if (t == NBUCKET - 1) bbase[NBUCKET] = lds[t]; // grand total (= E_TOT)
}

__global__ __launch_bounds__(256) void bucket_bin(const int* __restrict__ ei,
                                                  const int* __restrict__ bbase,
                                                  const int* __restrict__ bhist,
                                                  int* __restrict__ ebuf) {
    __shared__ int cur[NBUCKET];
    int tid = threadIdx.x;
    for (int t = tid; t < NBUCKET; t += 256)
        cur[t] = bbase[t] + bhist[blockIdx.x * BH_STRIDE + t];
    __syncthreads();
    int base = blockIdx.x * EDGES_PER_SB;
#pragma unroll 4
    for (int k = 0; k < EDGES_PER_SB / 256; ++k) {
        int idx = base + k * 256 + tid;
        int s = 0, d = -1;
        if (idx < N_EDGES) { s = ei[idx]; d = ei[N_EDGES + idx]; }
        else if (idx < E_TOT) { s = idx - N_EDGES; d = s; }
        if (d >= 0 && d < N_NODES) {
            int p = atomicAdd(&cur[d >> 7], 1);
            ebuf[p] = (s & 0xFFFF) | ((d & 127) << 16);
        }
    }
}

__global__ __launch_bounds__(256) void bucket_sort(const int* __restrict__ bbase,
                                                   const int* __restrict__ ebuf,
                                                   int* __restrict__ ssrc,
                                                   int* __restrict__ row_ptr) {
    __shared__ int cnt[128];         // per-local-node count -> cursor
    __shared__ int sc[128];          // scan scratch
    __shared__ int stage[STAGE_CAP];
    int j = blockIdx.x;
    int tid = threadIdx.x;
    int jn0 = j << 7;
    int nNodes = N_NODES - jn0; if (nNodes > 128) nNodes = 128;
    int lo = bbase[j];
    int hi = bbase[j + 1];
    int span = hi - lo;
    if (tid < 128) cnt[tid] = 0;
    __syncthreads();
    // pass 1: per-node histogram from ebuf (L2-hot, ~span reads)
    for (int t = lo + tid; t < hi; t += 256)
        atomicAdd(&cnt[(ebuf[t] >> 16) & 127], 1);
    __syncthreads();
    if (tid < 128) sc[tid] = cnt[tid];
    __syncthreads();
#pragma unroll
    for (int off = 1; off < 128; off <<= 1) {
        int u = (tid >= off && tid < 128) ? sc[tid - off] : 0;
        __syncthreads();
        if (tid < 128) sc[tid] += u;
        __syncthreads();
    }
    if (tid < 128) {
        int excl = sc[tid] - cnt[tid];
        if (tid < nNodes) row_ptr[jn0 + tid] = lo + excl;   // CSR byproduct
        cnt[tid] = excl;                                     // reuse as cursor
    }
    if (j == NBUCKET - 1 && tid == 0) row_ptr[N_NODES] = hi; // = E_TOT
    __syncthreads();
    // pass 2: scatter into LDS stage, coalesced flush
    if (span <= STAGE_CAP) {
        for (int t = lo + tid; t < hi; t += 256) {
            int v = ebuf[t];
            int p = atomicAdd(&cnt[(v >> 16) & 127], 1);
            stage[p] = v & 0xFFFF;
        }
        __syncthreads();
        for (int t = tid; t < span; t += 256) ssrc[lo + t] = stage[t];
    } else {                         // overflow fallback (never for this input)
        for (int t = lo + tid; t < hi; t += 256) {
            int v = ebuf[t];
            int p = atomicAdd(&cnt[(v >> 16) & 127], 1);
            if (p >= 0 && p < span) ssrc[lo + p] = v & 0xFFFF;
        }
    }
}

// ---------------------------------------------------------------------------
// MFMA fp16 GEMM with folded attention dots. LDS ldk padded 48 -> 56 halfs
// (112B row stride): ds_read_b128 bank pattern (28*mlane+4*quad)%32 is 2-way
// (free, m136) vs 4-way at 48 (800K conflicts/dispatch measured round 4).
// ---------------------------------------------------------------------------
__global__ __launch_bounds__(256) void gemm_mfma_kernel(const _Float16* __restrict__ A,
                                                        const _Float16* __restrict__ Bt,
                                                        _Float16* __restrict__ C,
                                                        int mode,
                                                        const float* __restrict__ attS,
                                                        const float* __restrict__ attD,
                                                        float* __restrict__ a_src_o,
                                                        float* __restrict__ a_dst_o,
                                                        int M, int N) {
    __shared__ _Float16 As[128][56];   // ldk=56: 16B-aligned rows, 2-way banks
    __shared__ _Float16 Bs[128][56];
    __shared__ float lds_ps[128];
    __shared__ float lds_pd[128];
    const int tid = threadIdx.x;
    const int tileM = blockIdx.x * 128;
    const int tileN = blockIdx.y * 128;
    const int w = tid >> 6, lane = tid & 63;
    const int wm = (w >> 1) * 64, wn = (w & 1) * 64;
    const int quad = lane >> 4, mlane = lane & 15;
    const int srow = tid >> 2;           // 0..63 (rows srow and srow+64)
    const int schunk = (tid & 3) * 8;    // f16 offset within 32-k slab

    f32x4 zero = {0.f, 0.f, 0.f, 0.f};
    f32x4 acc[4][4];
#pragma unroll
    for (int i = 0; i < 4; ++i)
#pragma unroll
        for (int j = 0; j < 4; ++j) acc[i][j] = zero;

    const uint4* Av = reinterpret_cast<const uint4*>(A);   // 8 f16 per uint4; 32/row
    const uint4* Bv = reinterpret_cast<const uint4*>(Bt);
    const int r0 = tileM + srow, r1 = r0 + 64;
    const bool ok0 = r0 < M, ok1 = r1 < M;
    const int bn0 = tileN + srow, bn1 = bn0 + 64;          // N mult of 128: no guard
    const uint4 z4 = make_uint4(0, 0, 0, 0);

    for (int k0 = 0; k0 < 256; k0 += 32) {
        const int kc = (k0 >> 3) + (tid & 3);
        uint4 a0 = ok0 ? Av[(size_t)r0 * 32 + kc] : z4;
        uint4 a1 = ok1 ? Av[(size_t)r1 * 32 + kc] : z4;
        uint4 b0 = Bv[(size_t)bn0 * 32 + kc];
        uint4 b1 = Bv[(size_t)bn1 * 32 + kc];
        __syncthreads();
        *reinterpret_cast<uint4*>(&As[srow][schunk]) = a0;
        *reinterpret_cast<uint4*>(&As[srow + 64][schunk]) = a1;
        *reinterpret_cast<uint4*>(&Bs[srow][schunk]) = b0;
        *reinterpret_cast<uint4*>(&Bs[srow + 64][schunk]) = b1;
        __syncthreads();
        half8_t af[4], bf[4];
#pragma unroll
        for (int mt = 0; mt < 4; ++mt)
            af[mt] = *reinterpret_cast<const half8_t*>(&As[wm + mt * 16 + mlane][quad * 8]);
#pragma unroll
        for (int nt = 0; nt < 4; ++nt)
            bf[nt] = *reinterpret_cast<const half8_t*>(&Bs[wn + nt * 16 + mlane][quad * 8]);
#pragma unroll
        for (int mt = 0; mt < 4; ++mt)
#pragma unroll
            for (int nt = 0; nt < 4; ++nt)
                acc[mt][nt] = __builtin_amdgcn_mfma_f32_16x16x32_f16(af[mt], bf[nt], acc[mt][nt], 0, 0, 0);
    }
#pragma unroll
    for (int mt = 0; mt < 4; ++mt) {
#pragma unroll
        for (int i = 0; i < 4; ++i) {
            int row = tileM + wm + mt * 16 + quad * 4 + i;
            if (row < M) {
                _Float16* cp = C + (size_t)row * N + tileN + wn;
#pragma unroll
                for (int nt = 0; nt < 4; ++nt)
                    cp[nt * 16 + mlane] = (_Float16)acc[mt][nt][i];
            }
        }
    }
    if (mode == 1) {
        int hd = (tileN + wn) >> 6;          // this wave's head (64 cols/head)
        float as[4], ad[4];
#pragma unroll
        for (int nt = 0; nt < 4; ++nt) {
            as[nt] = attS[hd * 64 + nt * 16 + mlane];
            ad[nt] = attD[hd * 64 + nt * 16 + mlane];
        }
#pragma unroll
        for (int mt = 0; mt < 4; ++mt) {
#pragma unroll
            for (int i = 0; i < 4; ++i) {
                float ps = acc[mt][0][i] * as[0] + acc[mt][1][i] * as[1]
                         + acc[mt][2][i] * as[2] + acc[mt][3][i] * as[3];
                float pd = acc[mt][0][i] * ad[0] + acc[mt][1][i] * ad[1]
                         + acc[mt][2][i] * ad[2] + acc[mt][3][i] * ad[3];
#pragma unroll
                for (int off = 1; off < 16; off <<= 1) {
                    ps += __shfl_xor(ps, off);
                    pd += __shfl_xor(pd, off);
                }
                if (mlane == 0) {
                    int row = tileM + wm + mt * 16 + quad * 4 + i;
                    if (row < M) {
                        a_src_o[row * 4 + hd] = ps;
                        a_dst_o[row * 4 + hd] = pd;
                    }
                }
            }
        }
    } else if (mode == 2) {
        // single-head: wave covers cols wn..wn+63 of 128 -> partial dots
        float as[4], ad[4];
#pragma unroll
        for (int nt = 0; nt < 4; ++nt) {
            as[nt] = attS[wn + nt * 16 + mlane];
            ad[nt] = attD[wn + nt * 16 + mlane];
        }
        float psa[4][4], pda[4][4];
#pragma unroll
        for (int mt = 0; mt < 4; ++mt) {
#pragma unroll
            for (int i = 0; i < 4; ++i) {
                float ps = acc[mt][0][i] * as[0] + acc[mt][1][i] * as[1]
                         + acc[mt][2][i] * as[2] + acc[mt][3][i] * as[3];
                float pd = acc[mt][0][i] * ad[0] + acc[mt][1][i] * ad[1]
                         + acc[mt][2][i] * ad[2] + acc[mt][3][i] * ad[3];
#pragma unroll
                for (int off = 1; off < 16; off <<= 1) {
                    ps += __shfl_xor(ps, off);
                    pd += __shfl_xor(pd, off);
                }
                psa[mt][i] = ps; pda[mt][i] = pd;
            }
        }
        __syncthreads();
        if (wn == 0 && mlane == 0) {
#pragma unroll
            for (int mt = 0; mt < 4; ++mt)
#pragma unroll
                for (int i = 0; i < 4; ++i) {
                    int lr = wm + mt * 16 + quad * 4 + i;
                    lds_ps[lr] = psa[mt][i];
                    lds_pd[lr] = pda[mt][i];
                }
        }
        __syncthreads();
        if (wn == 64 && mlane == 0) {
#pragma unroll
            for (int mt = 0; mt < 4; ++mt)
#pragma unroll
                for (int i = 0; i < 4; ++i) {
                    int lr = wm + mt * 16 + quad * 4 + i;
                    int row = tileM + lr;
                    if (row < M) {
                        a_src_o[row] = psa[mt][i] + lds_ps[lr];
                        a_dst_o[row] = pda[mt][i] + lds_pd[lr];
                    }
                }
        }
    }
}

__device__ __forceinline__ float lrelu(float x) { return x > 0.f ? x : NEG_SLOPE * x; }

// ---------------------------------------------------------------------------
// Edge aggregation, layer 1 — round-2 form, the verified 65us optimum
// (4 structural variants all land 65±1us: platform random-gather ceiling).
// ---------------------------------------------------------------------------
__global__ __launch_bounds__(256) void edge1_kernel(const int* __restrict__ row_ptr,
                                                    const int* __restrict__ ssrc,
                                                    const __half* __restrict__ h1h,
                                                    const float* __restrict__ a_src,
                                                    const float* __restrict__ a_dst,
                                                    const float* __restrict__ bias,
                                                    __half* __restrict__ out) {
    int node = blockIdx.x * 4 + (threadIdx.x >> 6);
    int lane = threadIdx.x & 63;
    int hf   = lane >> 5;              // 0: even edges, 1: odd edges
    int cl   = lane & 31;              // channel-lane: ch [cl*8, cl*8+8)
    int hd   = cl >> 3;                // head = ch/64
    int start = row_ptr[node], end = row_ptr[node + 1];
    int em1 = end - 1;                 // >= start (self-loop guarantees deg>=1)
    float adh = a_dst[node * 4 + hd];

    const uint4* h1v = reinterpret_cast<const uint4*>(h1h);   // 8 halfs/uint4; 32 per row
    float4 aA0 = make_float4(0.f,0.f,0.f,0.f), aA1 = make_float4(0.f,0.f,0.f,0.f);
    float4 aB0 = make_float4(0.f,0.f,0.f,0.f), aB1 = make_float4(0.f,0.f,0.f,0.f);
    float s = 0.f;
    for (int e = start; e < end; e += 4) {
        int e0 = e + hf;
        int e1 = e + 2 + hf;
        int i0 = ssrc[e0 <= em1 ? e0 : em1];
        int i1 = ssrc[e1 <= em1 ? e1 : em1];
        float r0 = a_src[i0 * 4 + hd];
        float r1 = a_src[i1 * 4 + hd];
        uint4 q0 = h1v[(size_t)i0 * 32 + cl];
        uint4 q1 = h1v[(size_t)i1 * 32 + cl];
        float w0 = (e0 < end) ? __expf(lrelu(r0 + adh)) : 0.f;
        float w1 = (e1 < end) ? __expf(lrelu(r1 + adh)) : 0.f;
        s += w0 + w1;
        float2 f;
        f = __half22float2(*reinterpret_cast<const __half2*>(&q0.x)); aA0.x += w0*f.x; aA0.y += w0*f.y;
        f = __half22float2(*reinterpret_cast<const __half2*>(&q0.y)); aA0.z += w0*f.x; aA0.w += w0*f.y;
        f = __half22float2(*reinterpret_cast<const __half2*>(&q0.z)); aA1.x += w0*f.x; aA1.y += w0*f.y;
        f = __half22float2(*reinterpret_cast<const __half2*>(&q0.w)); aA1.z += w0*f.x; aA1.w += w0*f.y;
        f = __half22float2(*reinterpret_cast<const __half2*>(&q1.x)); aB0.x += w1*f.x; aB0.y += w1*f.y;
        f = __half22float2(*reinterpret_cast<const __half2*>(&q1.y)); aB0.z += w1*f.x; aB0.w += w1*f.y;
        f = __half22float2(*reinterpret_cast<const __half2*>(&q1.z)); aB1.x += w1*f.x; aB1.y += w1*f.y;
        f = __half22float2(*reinterpret_cast<const __half2*>(&q1.w)); aB1.z += w1*f.x; aB1.w += w1*f.y;
    }
    float4 c0, c1;
    c0.x = aA0.x + aB0.x; c0.y = aA0.y + aB0.y; c0.z = aA0.z + aB0.z; c0.w = aA0.w + aB0.w;
    c1.x = aA1.x + aB1.x; c1.y = aA1.y + aB1.y; c1.z = aA1.z + aB1.z; c1.w = aA1.w + aB1.w;
    // fold even/odd halves (lane L and L+32 cover the same channels & head)
    c0.x += __shfl_xor(c0.x, 32); c0.y += __shfl_xor(c0.y, 32);
    c0.z += __shfl_xor(c0.z, 32); c0.w += __shfl_xor(c0.w, 32);
    c1.x += __shfl_xor(c1.x, 32); c1.y += __shfl_xor(c1.y, 32);
    c1.z += __shfl_xor(c1.z, 32); c1.w += __shfl_xor(c1.w, 32);
    s += __shfl_xor(s, 32);
    float inv = 1.0f / (s + EPS_F);
    if (lane < 32) {
        const float4* b4 = reinterpret_cast<const float4*>(bias);
        float4 b0 = b4[cl * 2], b1 = b4[cl * 2 + 1];
        union { _Float16 h[8]; uint4 u; } st;
        st.h[0] = (_Float16)fmaxf(c0.x * inv + b0.x, 0.f);
        st.h[1] = (_Float16)fmaxf(c0.y * inv + b0.y, 0.f);
        st.h[2] = (_Float16)fmaxf(c0.z * inv + b0.z, 0.f);
        st.h[3] = (_Float16)fmaxf(c0.w * inv + b0.w, 0.f);
        st.h[4] = (_Float16)fmaxf(c1.x * inv + b1.x, 0.f);
        st.h[5] = (_Float16)fmaxf(c1.y * inv + b1.y, 0.f);
        st.h[6] = (_Float16)fmaxf(c1.z * inv + b1.z, 0.f);
        st.h[7] = (_Float16)fmaxf(c1.w * inv + b1.w, 0.f);
        reinterpret_cast<uint4*>(out)[(size_t)node * 32 + cl] = st.u;
    }
}

// ---------------------------------------------------------------------------
// Edge aggregation, layer 2 — round-2 form: 2 nodes per wave, 16-lane groups
// cover the 128-ch row via one uint4 gather, two edges per iteration.
// ---------------------------------------------------------------------------
__global__ __launch_bounds__(256) void edge2_kernel(const int* __restrict__ row_ptr,
                                                    const int* __restrict__ ssrc,
                                                    const __half* __restrict__ h2h,
                                                    const float* __restrict__ a_src,
                                                    const float* __restrict__ a_dst,
                                                    const float* __restrict__ bias,
                                                    float* __restrict__ out) {
    int lane = threadIdx.x & 63;
    int node = blockIdx.x * 8 + ((threadIdx.x >> 6) << 1) + (lane >> 5);
    int sub  = (lane >> 4) & 1;        // edge sub-slot within the 32-lane node group
    int cl   = lane & 15;              // channel-lane: ch [cl*8, cl*8+8)
    int start = row_ptr[node], end = row_ptr[node + 1];
    int em1 = end - 1;
    float ad = a_dst[node];

    const uint4* h2v = reinterpret_cast<const uint4*>(h2h);   // 8 halfs/uint4; 16 per row
    float4 aA0 = make_float4(0.f,0.f,0.f,0.f), aA1 = make_float4(0.f,0.f,0.f,0.f);
    float4 aB0 = make_float4(0.f,0.f,0.f,0.f), aB1 = make_float4(0.f,0.f,0.f,0.f);
    float s = 0.f;
    for (int e = start; e < end; e += 4) {
        int e0 = e + sub;
        int e1 = e + 2 + sub;
        int i0 = ssrc[e0 <= em1 ? e0 : em1];
        int i1 = ssrc[e1 <= em1 ? e1 : em1];
        float r0 = a_src[i0];
        float r1 = a_src[i1];
        uint4 q0 = h2v[(size_t)i0 * 16 + cl];
        uint4 q1 = h2v[(size_t)i1 * 16 + cl];
        float w0 = (e0 < end) ? __expf(lrelu(r0 + ad)) : 0.f;
        float w1 = (e1 < end) ? __expf(lrelu(r1 + ad)) : 0.f;
        s += w0 + w1;
        float2 f;
        f = __half22float2(*reinterpret_cast<const __half2*>(&q0.x)); aA0.x += w0*f.x; aA0.y += w0*f.y;
        f = __half22float2(*reinterpret_cast<const __half2*>(&q0.y)); aA0.z += w0*f.x; aA0.w += w0*f.y;
        f = __half22float2(*reinterpret_cast<const __half2*>(&q0.z)); aA1.x += w0*f.x; aA1.y += w0*f.y;
        f = __half22float2(*reinterpret_cast<const __half2*>(&q0.w)); aA1.z += w0*f.x; aA1.w += w0*f.y;
        f = __half22float2(*reinterpret_cast<const __half2*>(&q1.x)); aB0.x += w1*f.x; aB0.y += w1*f.y;
        f = __half22float2(*reinterpret_cast<const __half2*>(&q1.y)); aB0.z += w1*f.x; aB0.w += w1*f.y;
        f = __half22float2(*reinterpret_cast<const __half2*>(&q1.z)); aB1.x += w1*f.x; aB1.y += w1*f.y;
        f = __half22float2(*reinterpret_cast<const __half2*>(&q1.w)); aB1.z += w1*f.x; aB1.w += w1*f.y;
    }
    float4 c0, c1;
    c0.x = aA0.x + aB0.x; c0.y = aA0.y + aB0.y; c0.z = aA0.z + aB0.z; c0.w = aA0.w + aB0.w;
    c1.x = aA1.x + aB1.x; c1.y = aA1.y + aB1.y; c1.z = aA1.z + aB1.z; c1.w = aA1.w + aB1.w;
    // fold the two 16-lane edge groups within this node's 32-lane half
    c0.x += __shfl_xor(c0.x, 16); c0.y += __shfl_xor(c0.y, 16);
    c0.z += __shfl_xor(c0.z, 16); c0.w += __shfl_xor(c0.w, 16);
    c1.x += __shfl_xor(c1.x, 16); c1.y += __shfl_xor(c1.y, 16);
    c1.z += __shfl_xor(c1.z, 16); c1.w += __shfl_xor(c1.w, 16);
    s += __shfl_xor(s, 16);
    float inv = 1.0f / (s + EPS_F);
    if (sub == 0) {                     // 16 lanes per node write the 128-ch row
        const float4* b4 = reinterpret_cast<const float4*>(bias);
        float4 b0 = b4[cl * 2], b1 = b4[cl * 2 + 1];
        float4 o0, o1;
        o0.x = fmaxf(c0.x * inv + b0.x, 0.f);
        o0.y = fmaxf(c0.y * inv + b0.y, 0.f);
        o0.z = fmaxf(c0.z * inv + b0.z, 0.f);
        o0.w = fmaxf(c0.w * inv + b0.w, 0.f);
        o1.x = fmaxf(c1.x * inv + b1.x, 0.f);
        o1.y = fmaxf(c1.y * inv + b1.y, 0.f);
        o1.z = fmaxf(c1.z * inv + b1.z, 0.f);
        o1.w = fmaxf(c1.w * inv + b1.w, 0.f);
        float4* o4 = reinterpret_cast<float4*>(out) + (size_t)node * 32 + cl * 2;
        o4[0] = o0;
        o4[1] = o1;
    }
}

// ---------------------------------------------------------------------------
// Pooling with folded mean division.
// ---------------------------------------------------------------------------
#define POOL_CHUNK 64
__global__ __launch_bounds__(128) void pool_kernel(const float* __restrict__ out2,
                                                   const int* __restrict__ batch,
                                                   const int* __restrict__ gstart,
                                                   float* __restrict__ d_out) {
    int c = threadIdx.x;                 // channel 0..127
    int node0 = blockIdx.x * POOL_CHUNK;
    int nodeEnd = node0 + POOL_CHUNK; if (nodeEnd > N_NODES) nodeEnd = N_NODES;
    if (node0 >= N_NODES) return;
    int gprev = batch[node0];
    float acc = 0.f;
    for (int node = node0; node < nodeEnd; ++node) {
        int g = batch[node];
        if (g != gprev) {
            if (gprev >= 0 && gprev < N_GRAPHS) {
                float cnt = (float)(gstart[gprev + 1] - gstart[gprev]);
                if (cnt < 1.f) cnt = 1.f;
                atomicAdd(&d_out[gprev * 128 + c], acc / cnt);
            }
            acc = 0.f;
            gprev = g;
        }
        acc += out2[(size_t)node * 128 + c];
    }
    if (gprev >= 0 && gprev < N_GRAPHS) {
        float cnt = (float)(gstart[gprev + 1] - gstart[gprev]);
        if (cnt < 1.f) cnt = 1.f;
        atomicAdd(&d_out[gprev * 128 + c], acc / cnt);
    }
}

// ---------------------------------------------------------------------------
extern "C" void kernel_launch(void* const* d_in, const int* in_sizes, int n_in,
                              void* d_out_v, int out_size, void* d_ws, size_t ws_size,
                              hipStream_t stream) {
    const float* x      = (const float*)d_in[0];
    const float* W1     = (const float*)d_in[1];
    const float* att_s1 = (const float*)d_in[2];
    const float* att_d1 = (const float*)d_in[3];
    const float* bias1  = (const float*)d_in[4];
    const float* W2     = (const float*)d_in[5];
    const float* att_s2 = (const float*)d_in[6];
    const float* att_d2 = (const float*)d_in[7];
    const float* bias2  = (const float*)d_in[8];
    const int*   ei     = (const int*)d_in[9];
    const int*   batch  = (const int*)d_in[10];
    float* d_out = (float*)d_out_v;

    // Workspace layout (float units):
    //  [0, 6.4M)        xh fp16 [N,256]      ... later reused as h2h fp16 [N,128]
    //  [6.4M, 12.8M)    h1h fp16 [N,256]     ... later reused as out2 fp32 [N,128]
    //  [12.8M, 19.2M)   out1h fp16 [N,256]
    //  [19.2M, ...)     attention scalars + sort buffers + W transposes
    float* ws = (float*)d_ws;
    _Float16* xh    = (_Float16*)ws;
    _Float16* h1h   = (_Float16*)(ws + 6400000);
    _Float16* out1h = (_Float16*)(ws + 12800000);
    _Float16* h2h   = (_Float16*)ws;            // xh dead after GEMM1
    float*    out2  = ws + 6400000;             // h1h dead after edge1
    float* a_src1 = ws + 19200000;              // N*4
    float* a_dst1 = a_src1 + 200000;            // N*4
    float* a_src2 = a_dst1 + 200000;            // N
    float* a_dst2 = a_src2 + 50000;             // N
    int* row_ptr  = (int*)(a_dst2 + 50000);     // N+1 (padded to 50016)
    int* ssrc     = row_ptr + 50016;            // E_TOT
    int* ebuf     = ssrc + 850000;              // SORT_BLOCKS*EDGES_PER_SB pad
    int* bhist    = ebuf + 851968;              // SORT_BLOCKS * BH_STRIDE
    int* btot     = bhist + (SORT_BLOCKS * BH_STRIDE); // NBUCKET (pad 512)
    int* bbase    = btot + 512;                 // NBUCKET+1 (pad 512)
    int* gstart   = bbase + 512;                // N_GRAPHS+1 (pad 128)
    _Float16* W1t = (_Float16*)(gstart + 128);  // 65536 halfs [256][256]
    _Float16* W2t = W1t + 65536;                // 32768 halfs [128][256]

    // Fused prep: bucket-hist, cast x, transpose W1/W2, graph bounds, d_out=0
    // (no memset, no global-atomic histogram, no separate CSR scan chain)
    prep_kernel<<<PREP_TOTAL, 256, 0, stream>>>(x, xh, W1, W1t, W2, W2t,
                                                ei, bhist, batch, gstart, d_out);

    // Bucket counting sort; row_ptr falls out of bucket_sort
    bucket_scan<<<NBUCKET, 64, 0, stream>>>(bhist, btot);
    bucket_base<<<1, 512, 0, stream>>>(btot, bbase);
    bucket_bin<<<SORT_BLOCKS, 256, 0, stream>>>(ei, bbase, bhist, ebuf);
    bucket_sort<<<NBUCKET, 256, 0, stream>>>(bbase, ebuf, ssrc, row_ptr);

    // Layer 1: h1 = x @ W1 (MFMA fp16, att1 folded into epilogue, mode 1)
    {
        dim3 g((N_NODES + 127) / 128, H1C / 128);
        gemm_mfma_kernel<<<g, 256, 0, stream>>>(xh, W1t, h1h, 1,
                                                att_s1, att_d1, a_src1, a_dst1,
                                                N_NODES, H1C);
    }
    edge1_kernel<<<N_NODES / 4, 256, 0, stream>>>(row_ptr, ssrc, (const __half*)h1h,
                                                  a_src1, a_dst1, bias1, (__half*)out1h);

    // Layer 2: h2 = out1 @ W2 (MFMA fp16, att2 folded via LDS combine, mode 2)
    {
        dim3 g((N_NODES + 127) / 128, OUT_C / 128);
        gemm_mfma_kernel<<<g, 256, 0, stream>>>(out1h, W2t, h2h, 2,
                                                att_s2, att_d2, a_src2, a_dst2,
                                                N_NODES, OUT_C);
    }
    edge2_kernel<<<N_NODES / 8, 256, 0, stream>>>(row_ptr, ssrc, (const __half*)h2h,
                                                  a_src2, a_dst2, bias2, out2);

    // Pooling (mean division folded into the atomic flush)
    pool_kernel<<<(N_NODES + POOL_CHUNK - 1) / POOL_CHUNK, 128, 0, stream>>>(out2, batch, gstart, d_out);
}

// Round 7
// 299.608 us; speedup vs baseline: 1.1574x; 1.0087x over previous
//
#include <hip/hip_runtime.h>
#include <hip/hip_bf16.h>
#include <hip/hip_fp16.h>

// Problem constants (fixed by the reference setup)
#define N_NODES 50000
#define N_EDGES 800000
#define E_TOT   (N_EDGES + N_NODES)   // 850000 (self-loops appended)
#define IN_C    256
#define H1C     256                    // HEADS * HID_C = 4*64
#define HEADS   4
#define HID_C   64
#define OUT_C   128
#define N_GRAPHS 100
#define NEG_SLOPE 0.2f
#define EPS_F 1e-16f

// Bucket sort: order within a bucket is irrelevant (bucket_sort rebuilds
// per-node order), so bin reserves space via global atomics into FIXED
// per-bucket ebuf regions — no cross-block prefix (scan/base) needed.
#define NBUCKET 391                   // ceil(50000 / 128), bucket = dst >> 7
#define BIN_BLOCKS 104
#define EDGES_PER_SB 8192             // 104*8192 = 851968 >= E_TOT
#define EBUF_CAP 4096                 // per-bucket region (span avg ~2176, max<3072)
#define STAGE_CAP 4096                // LDS staging = EBUF_CAP (no fallback)
#define GEMM1_MB 391                  // gemm1 M-tiles; grid adds 2 N-tiles

// prep_kernel block partition
#define PREP_CAST_BLOCKS   12500      // 3,200,000 uint2 / 256
#define PREP_W1_BLOCKS     256        // 65536 / 256
#define PREP_W2_BLOCKS     128        // 32768 / 256
#define PREP_BOUNDS_BLOCKS 196
#define PREP_ZERO_BLOCKS   52         // 12800 d_out + 512 gcur
#define PREP_TOTAL (PREP_CAST_BLOCKS + PREP_W1_BLOCKS + PREP_W2_BLOCKS + PREP_BOUNDS_BLOCKS + PREP_ZERO_BLOCKS)

typedef _Float16 half8_t __attribute__((ext_vector_type(8)));
typedef float f32x4 __attribute__((ext_vector_type(4)));

// ---------------------------------------------------------------------------
// Fused prep: cast_x + W1t + W2t + bounds + zero(d_out, gcur).
// ---------------------------------------------------------------------------
__global__ __launch_bounds__(256) void prep_kernel(const float* __restrict__ x,
                                                   _Float16* __restrict__ xh,
                                                   const float* __restrict__ W1,
                                                   _Float16* __restrict__ W1t,
                                                   const float* __restrict__ W2,
                                                   _Float16* __restrict__ W2t,
                                                   const int* __restrict__ batch,
                                                   int* __restrict__ gstart,
                                                   int* __restrict__ gcur,
                                                   float* __restrict__ d_out) {
    int b = blockIdx.x;
    int tid = threadIdx.x;
    if (b < PREP_CAST_BLOCKS) {
        int idx = b * 256 + tid;                      // < 3,200,000 exactly
        float4 v = reinterpret_cast<const float4*>(x)[idx];
        union { _Float16 h[4]; uint2 u; } p;
        p.h[0] = (_Float16)v.x; p.h[1] = (_Float16)v.y;
        p.h[2] = (_Float16)v.z; p.h[3] = (_Float16)v.w;
        reinterpret_cast<uint2*>(xh)[idx] = p.u;
        return;
    }
    b -= PREP_CAST_BLOCKS;
    if (b < PREP_W1_BLOCKS) {
        int idx = b * 256 + tid;                      // < 65536 exactly
        int n = idx >> 8, k = idx & 255;
        W1t[idx] = (_Float16)W1[k * 256 + n];
        return;
    }
    b -= PREP_W1_BLOCKS;
    if (b < PREP_W2_BLOCKS) {
        int idx = b * 256 + tid;                      // < 32768 exactly
        int n = idx >> 8, k = idx & 255;
        W2t[idx] = (_Float16)W2[k * 128 + n];
        return;
    }
    b -= PREP_W2_BLOCKS;
    if (b < PREP_BOUNDS_BLOCKS) {   // bounds: batch sorted; each gstart entry written exactly once
        int idx = b * 256 + tid;
        if (idx >= N_NODES) return;
        int g = batch[idx];
        if (g < 0) g = 0; if (g >= N_GRAPHS) g = N_GRAPHS - 1;
        if (idx == 0) {
            for (int j = 0; j <= g; ++j) gstart[j] = 0;
        } else {
            int gp = batch[idx - 1];
            if (gp < 0) gp = 0; if (gp >= N_GRAPHS) gp = N_GRAPHS - 1;
            for (int j = gp + 1; j <= g; ++j) gstart[j] = idx;
        }
        if (idx == N_NODES - 1) {
            for (int j = g + 1; j <= N_GRAPHS; ++j) gstart[j] = N_NODES;
        }
        return;
    }
    b -= PREP_BOUNDS_BLOCKS;
    {   // zero d_out + gcur (bucket cursors) — pool/bin run later in stream
        int idx = b * 256 + tid;
        if (idx < N_GRAPHS * 128) d_out[idx] = 0.f;
        else {
            int k = idx - N_GRAPHS * 128;
            if (k < 512) gcur[k] = 0;
        }
    }
}

// ---------------------------------------------------------------------------
// bucket_bin: LDS histogram -> one global atomicAdd per (block,bucket) to
// reserve a run in the bucket's FIXED ebuf region -> write packed records.
// ~40K global atomics total (vs 850K in the dead scatter); record order
// within a bucket is arbitrary, which is fine (sort rebuilds node order).
// ---------------------------------------------------------------------------
__global__ __launch_bounds__(256) void bucket_bin(const int* __restrict__ ei,
                                                  int* __restrict__ gcur,
                                                  int* __restrict__ ebuf) {
    __shared__ int bh[NBUCKET];
    __shared__ int bofs[NBUCKET];
    int tid = threadIdx.x;
    for (int t = tid; t < NBUCKET; t += 256) bh[t] = 0;
    __syncthreads();
    int base = blockIdx.x * EDGES_PER_SB;
#pragma unroll 4
    for (int k = 0; k < EDGES_PER_SB / 256; ++k) {
        int idx = base + k * 256 + tid;
        int d = -1;
        if (idx < N_EDGES) d = ei[N_EDGES + idx];
        else if (idx < E_TOT) d = idx - N_EDGES;
        if (d >= 0 && d < N_NODES) atomicAdd(&bh[d >> 7], 1);
    }
    __syncthreads();
    for (int t = tid; t < NBUCKET; t += 256) {
        int c = bh[t];
        bofs[t] = (c > 0) ? atomicAdd(&gcur[t], c) : 0;
        bh[t] = 0;                     // reuse as local cursor
    }
    __syncthreads();
#pragma unroll 4
    for (int k = 0; k < EDGES_PER_SB / 256; ++k) {
        int idx = base + k * 256 + tid;
        int s = 0, d = -1;
        if (idx < N_EDGES) { s = ei[idx]; d = ei[N_EDGES + idx]; }
        else if (idx < E_TOT) { s = idx - N_EDGES; d = s; }
        if (d >= 0 && d < N_NODES) {
            int t = d >> 7;
            int p = bofs[t] + atomicAdd(&bh[t], 1);
            if (p < EBUF_CAP)          // defensive; never fires for this input
                ebuf[t * EBUF_CAP + p] = (s & 0xFFFF) | ((d & 127) << 16);
        }
    }
}

// ---------------------------------------------------------------------------
// FUSED bucket_sort + GEMM1 (single dispatch): the two are independent
// (sort: ebuf->ssrc/row_ptr; gemm: xh/W1t->h1h/att1) and edge1 needs both —
// sort's ~9us co-schedules under gemm1. LDS is a union'd byte buffer
// (gemm 29.7KB > sort 17.4KB). Blocks [0,391): sort; [391,1173): gemm tiles.
// GEMM LDS ldk=56 (112B stride): 2-way bank pattern = free (m136), vs 4-way
// at ldk=48 (800K conflicts/dispatch measured round 4).
// ---------------------------------------------------------------------------
__global__ __launch_bounds__(256) void sort_gemm1_kernel(const int* __restrict__ gcur,
                                                         const int* __restrict__ ebuf,
                                                         int* __restrict__ ssrc,
                                                         int* __restrict__ row_ptr,
                                                         const _Float16* __restrict__ A,
                                                         const _Float16* __restrict__ Bt,
                                                         _Float16* __restrict__ C,
                                                         const float* __restrict__ attS,
                                                         const float* __restrict__ attD,
                                                         float* __restrict__ a_src_o,
                                                         float* __restrict__ a_dst_o) {
    __shared__ __align__(16) char smem[29696];
    __shared__ int s_off;
    const int tid = threadIdx.x;

    if (blockIdx.x < NBUCKET) {
        // ---------------- sort path ----------------
        int* cnt   = reinterpret_cast<int*>(smem);          // 128
        int* sc    = cnt + 128;                             // 128
        int* stage = sc + 128;                              // STAGE_CAP
        int j = blockIdx.x;
        // lo = sum of bucket counts < j (L2-hot, <=390 ints)
        if (tid < 64) {
            int acc = 0;
            for (int i = tid; i < j; i += 64) {
                int c = gcur[i];
                acc += (c < EBUF_CAP) ? c : EBUF_CAP;
            }
#pragma unroll
            for (int off = 32; off > 0; off >>= 1) acc += __shfl_down(acc, off);
            if (tid == 0) s_off = acc;
        }
        if (tid < 128) cnt[tid] = 0;
        __syncthreads();
        int span = gcur[j]; if (span > EBUF_CAP) span = EBUF_CAP;
        int lo = s_off;
        const int* eb = ebuf + j * EBUF_CAP;
        // per-node histogram
        for (int t = tid; t < span; t += 256)
            atomicAdd(&cnt[(eb[t] >> 16) & 127], 1);
        __syncthreads();
        if (tid < 128) sc[tid] = cnt[tid];
        __syncthreads();
#pragma unroll
        for (int off = 1; off < 128; off <<= 1) {
            int u = (tid >= off && tid < 128) ? sc[tid - off] : 0;
            __syncthreads();
            if (tid < 128) sc[tid] += u;
            __syncthreads();
        }
        int jn0 = j << 7;
        int nNodes = N_NODES - jn0; if (nNodes > 128) nNodes = 128;
        if (tid < 128) {
            int excl = sc[tid] - cnt[tid];
            if (tid < nNodes) row_ptr[jn0 + tid] = lo + excl;   // CSR byproduct
            cnt[tid] = excl;                                     // reuse as cursor
        }
        if (j == NBUCKET - 1 && tid == 0) row_ptr[N_NODES] = lo + span;
        __syncthreads();
        // scatter to LDS stage, coalesced flush
        for (int t = tid; t < span; t += 256) {
            int v = eb[t];
            int p = atomicAdd(&cnt[(v >> 16) & 127], 1);
            stage[p] = v & 0xFFFF;
        }
        __syncthreads();
        for (int t = tid; t < span; t += 256) ssrc[lo + t] = stage[t];
        return;
    }

    // ---------------- gemm1 path (M=N_NODES, N=256, mode-1 epilogue) ----------------
    _Float16 (*As)[56] = reinterpret_cast<_Float16(*)[56]>(smem);
    _Float16 (*Bs)[56] = reinterpret_cast<_Float16(*)[56]>(smem + 14336);
    float* lds_ps = reinterpret_cast<float*>(smem + 28672);   // unused in mode 1
    float* lds_pd = reinterpret_cast<float*>(smem + 29184);
    (void)lds_ps; (void)lds_pd;
    int b2 = blockIdx.x - NBUCKET;
    const int tileM = (b2 >= GEMM1_MB ? b2 - GEMM1_MB : b2) * 128;
    const int tileN = (b2 >= GEMM1_MB) ? 128 : 0;
    const int w = tid >> 6, lane = tid & 63;
    const int wm = (w >> 1) * 64, wn = (w & 1) * 64;
    const int quad = lane >> 4, mlane = lane & 15;
    const int srow = tid >> 2;
    const int schunk = (tid & 3) * 8;

    f32x4 zero = {0.f, 0.f, 0.f, 0.f};
    f32x4 acc[4][4];
#pragma unroll
    for (int i = 0; i < 4; ++i)
#pragma unroll
        for (int j = 0; j < 4; ++j) acc[i][j] = zero;

    const uint4* Av = reinterpret_cast<const uint4*>(A);
    const uint4* Bv = reinterpret_cast<const uint4*>(Bt);
    const int r0 = tileM + srow, r1 = r0 + 64;
    const bool ok0 = r0 < N_NODES, ok1 = r1 < N_NODES;
    const int bn0 = tileN + srow, bn1 = bn0 + 64;
    const uint4 z4 = make_uint4(0, 0, 0, 0);

    for (int k0 = 0; k0 < 256; k0 += 32) {
        const int kc = (k0 >> 3) + (tid & 3);
        uint4 a0 = ok0 ? Av[(size_t)r0 * 32 + kc] : z4;
        uint4 a1 = ok1 ? Av[(size_t)r1 * 32 + kc] : z4;
        uint4 b0 = Bv[(size_t)bn0 * 32 + kc];
        uint4 b1 = Bv[(size_t)bn1 * 32 + kc];
        __syncthreads();
        *reinterpret_cast<uint4*>(&As[srow][schunk]) = a0;
        *reinterpret_cast<uint4*>(&As[srow + 64][schunk]) = a1;
        *reinterpret_cast<uint4*>(&Bs[srow][schunk]) = b0;
        *reinterpret_cast<uint4*>(&Bs[srow + 64][schunk]) = b1;
        __syncthreads();
        half8_t af[4], bf[4];
#pragma unroll
        for (int mt = 0; mt < 4; ++mt)
            af[mt] = *reinterpret_cast<const half8_t*>(&As[wm + mt * 16 + mlane][quad * 8]);
#pragma unroll
        for (int nt = 0; nt < 4; ++nt)
            bf[nt] = *reinterpret_cast<const half8_t*>(&Bs[wn + nt * 16 + mlane][quad * 8]);
#pragma unroll
        for (int mt = 0; mt < 4; ++mt)
#pragma unroll
            for (int nt = 0; nt < 4; ++nt)
                acc[mt][nt] = __builtin_amdgcn_mfma_f32_16x16x32_f16(af[mt], bf[nt], acc[mt][nt], 0, 0, 0);
    }
#pragma unroll
    for (int mt = 0; mt < 4; ++mt) {
#pragma unroll
        for (int i = 0; i < 4; ++i) {
            int row = tileM + wm + mt * 16 + quad * 4 + i;
            if (row < N_NODES) {
                _Float16* cp = C + (size_t)row * 256 + tileN + wn;
#pragma unroll
                for (int nt = 0; nt < 4; ++nt)
                    cp[nt * 16 + mlane] = (_Float16)acc[mt][nt][i];
            }
        }
    }
    {   // mode-1 epilogue: per-head attention dots
        int hd = (tileN + wn) >> 6;
        float as[4], ad[4];
#pragma unroll
        for (int nt = 0; nt < 4; ++nt) {
            as[nt] = attS[hd * 64 + nt * 16 + mlane];
            ad[nt] = attD[hd * 64 + nt * 16 + mlane];
        }
#pragma unroll
        for (int mt = 0; mt < 4; ++mt) {
#pragma unroll
            for (int i = 0; i < 4; ++i) {
                float ps = acc[mt][0][i] * as[0] + acc[mt][1][i] * as[1]
                         + acc[mt][2][i] * as[2] + acc[mt][3][i] * as[3];
                float pd = acc[mt][0][i] * ad[0] + acc[mt][1][i] * ad[1]
                         + acc[mt][2][i] * ad[2] + acc[mt][3][i] * ad[3];
#pragma unroll
                for (int off = 1; off < 16; off <<= 1) {
                    ps += __shfl_xor(ps, off);
                    pd += __shfl_xor(pd, off);
                }
                if (mlane == 0) {
                    int row = tileM + wm + mt * 16 + quad * 4 + i;
                    if (row < N_NODES) {
                        a_src_o[row * 4 + hd] = ps;
                        a_dst_o[row * 4 + hd] = pd;
                    }
                }
            }
        }
    }
}

// ---------------------------------------------------------------------------
// GEMM2 (standalone, mode-2 epilogue): h2 = out1 @ W2, att2 via LDS combine.
// ---------------------------------------------------------------------------
__global__ __launch_bounds__(256) void gemm_mfma_kernel(const _Float16* __restrict__ A,
                                                        const _Float16* __restrict__ Bt,
                                                        _Float16* __restrict__ C,
                                                        const float* __restrict__ attS,
                                                        const float* __restrict__ attD,
                                                        float* __restrict__ a_src_o,
                                                        float* __restrict__ a_dst_o,
                                                        int M, int N) {
    __shared__ _Float16 As[128][56];
    __shared__ _Float16 Bs[128][56];
    __shared__ float lds_ps[128];
    __shared__ float lds_pd[128];
    const int tid = threadIdx.x;
    const int tileM = blockIdx.x * 128;
    const int tileN = 0;
    const int w = tid >> 6, lane = tid & 63;
    const int wm = (w >> 1) * 64, wn = (w & 1) * 64;
    const int quad = lane >> 4, mlane = lane & 15;
    const int srow = tid >> 2;
    const int schunk = (tid & 3) * 8;

    f32x4 zero = {0.f, 0.f, 0.f, 0.f};
    f32x4 acc[4][4];
#pragma unroll
    for (int i = 0; i < 4; ++i)
#pragma unroll
        for (int j = 0; j < 4; ++j) acc[i][j] = zero;

    const uint4* Av = reinterpret_cast<const uint4*>(A);
    const uint4* Bv = reinterpret_cast<const uint4*>(Bt);
    const int r0 = tileM + srow, r1 = r0 + 64;
    const bool ok0 = r0 < M, ok1 = r1 < M;
    const int bn0 = tileN + srow, bn1 = bn0 + 64;
    const uint4 z4 = make_uint4(0, 0, 0, 0);

    for (int k0 = 0; k0 < 256; k0 += 32) {
        const int kc = (k0 >> 3) + (tid & 3);
        uint4 a0 = ok0 ? Av[(size_t)r0 * 32 + kc] : z4;
        uint4 a1 = ok1 ? Av[(size_t)r1 * 32 + kc] : z4;
        uint4 b0 = Bv[(size_t)bn0 * 32 + kc];
        uint4 b1 = Bv[(size_t)bn1 * 32 + kc];
        __syncthreads();
        *reinterpret_cast<uint4*>(&As[srow][schunk]) = a0;
        *reinterpret_cast<uint4*>(&As[srow + 64][schunk]) = a1;
        *reinterpret_cast<uint4*>(&Bs[srow][schunk]) = b0;
        *reinterpret_cast<uint4*>(&Bs[srow + 64][schunk]) = b1;
        __syncthreads();
        half8_t af[4], bf[4];
#pragma unroll
        for (int mt = 0; mt < 4; ++mt)
            af[mt] = *reinterpret_cast<const half8_t*>(&As[wm + mt * 16 + mlane][quad * 8]);
#pragma unroll
        for (int nt = 0; nt < 4; ++nt)
            bf[nt] = *reinterpret_cast<const half8_t*>(&Bs[wn + nt * 16 + mlane][quad * 8]);
#pragma unroll
        for (int mt = 0; mt < 4; ++mt)
#pragma unroll
            for (int nt = 0; nt < 4; ++nt)
                acc[mt][nt] = __builtin_amdgcn_mfma_f32_16x16x32_f16(af[mt], bf[nt], acc[mt][nt], 0, 0, 0);
    }
#pragma unroll
    for (int mt = 0; mt < 4; ++mt) {
#pragma unroll
        for (int i = 0; i < 4; ++i) {
            int row = tileM + wm + mt * 16 + quad * 4 + i;
            if (row < M) {
                _Float16* cp = C + (size_t)row * N + tileN + wn;
#pragma unroll
                for (int nt = 0; nt < 4; ++nt)
                    cp[nt * 16 + mlane] = (_Float16)acc[mt][nt][i];
            }
        }
    }
    {   // mode-2 epilogue: single head, two waves combine via LDS
        float as[4], ad[4];
#pragma unroll
        for (int nt = 0; nt < 4; ++nt) {
            as[nt] = attS[wn + nt * 16 + mlane];
            ad[nt] = attD[wn + nt * 16 + mlane];
        }
        float psa[4][4], pda[4][4];
#pragma unroll
        for (int mt = 0; mt < 4; ++mt) {
#pragma unroll
            for (int i = 0; i < 4; ++i) {
                float ps = acc[mt][0][i] * as[0] + acc[mt][1][i] * as[1]
                         + acc[mt][2][i] * as[2] + acc[mt][3][i] * as[3];
                float pd = acc[mt][0][i] * ad[0] + acc[mt][1][i] * ad[1]
                         + acc[mt][2][i] * ad[2] + acc[mt][3][i] * ad[3];
#pragma unroll
                for (int off = 1; off < 16; off <<= 1) {
                    ps += __shfl_xor(ps, off);
                    pd += __shfl_xor(pd, off);
                }
                psa[mt][i] = ps; pda[mt][i] = pd;
            }
        }
        __syncthreads();
        if (wn == 0 && mlane == 0) {
#pragma unroll
            for (int mt = 0; mt < 4; ++mt)
#pragma unroll
                for (int i = 0; i < 4; ++i) {
                    int lr = wm + mt * 16 + quad * 4 + i;
                    lds_ps[lr] = psa[mt][i];
                    lds_pd[lr] = pda[mt][i];
                }
        }
        __syncthreads();
        if (wn == 64 && mlane == 0) {
#pragma unroll
            for (int mt = 0; mt < 4; ++mt)
#pragma unroll
                for (int i = 0; i < 4; ++i) {
                    int lr = wm + mt * 16 + quad * 4 + i;
                    int row = tileM + lr;
                    if (row < M) {
                        a_src_o[row] = psa[mt][i] + lds_ps[lr];
                        a_dst_o[row] = pda[mt][i] + lds_pd[lr];
                    }
                }
        }
    }
}

__device__ __forceinline__ float lrelu(float x) { return x > 0.f ? x : NEG_SLOPE * x; }

// ---------------------------------------------------------------------------
// Edge aggregation, layer 1 — round-2 form, the verified 65us optimum
// (4 structural variants all land 65±1us: platform random-gather ceiling).
// ---------------------------------------------------------------------------
__global__ __launch_bounds__(256) void edge1_kernel(const int* __restrict__ row_ptr,
                                                    const int* __restrict__ ssrc,
                                                    const __half* __restrict__ h1h,
                                                    const float* __restrict__ a_src,
                                                    const float* __restrict__ a_dst,
                                                    const float* __restrict__ bias,
                                                    __half* __restrict__ out) {
    int node = blockIdx.x * 4 + (threadIdx.x >> 6);
    int lane = threadIdx.x & 63;
    int hf   = lane >> 5;              // 0: even edges, 1: odd edges
    int cl   = lane & 31;              // channel-lane: ch [cl*8, cl*8+8)
    int hd   = cl >> 3;                // head = ch/64
    int start = row_ptr[node], end = row_ptr[node + 1];
    int em1 = end - 1;                 // >= start (self-loop guarantees deg>=1)
    float adh = a_dst[node * 4 + hd];

    const uint4* h1v = reinterpret_cast<const uint4*>(h1h);   // 8 halfs/uint4; 32 per row
    float4 aA0 = make_float4(0.f,0.f,0.f,0.f), aA1 = make_float4(0.f,0.f,0.f,0.f);
    float4 aB0 = make_float4(0.f,0.f,0.f,0.f), aB1 = make_float4(0.f,0.f,0.f,0.f);
    float s = 0.f;
    for (int e = start; e < end; e += 4) {
        int e0 = e + hf;
        int e1 = e + 2 + hf;
        int i0 = ssrc[e0 <= em1 ? e0 : em1];
        int i1 = ssrc[e1 <= em1 ? e1 : em1];
        float r0 = a_src[i0 * 4 + hd];
        float r1 = a_src[i1 * 4 + hd];
        uint4 q0 = h1v[(size_t)i0 * 32 + cl];
        uint4 q1 = h1v[(size_t)i1 * 32 + cl];
        float w0 = (e0 < end) ? __expf(lrelu(r0 + adh)) : 0.f;
        float w1 = (e1 < end) ? __expf(lrelu(r1 + adh)) : 0.f;
        s += w0 + w1;
        float2 f;
        f = __half22float2(*reinterpret_cast<const __half2*>(&q0.x)); aA0.x += w0*f.x; aA0.y += w0*f.y;
        f = __half22float2(*reinterpret_cast<const __half2*>(&q0.y)); aA0.z += w0*f.x; aA0.w += w0*f.y;
        f = __half22float2(*reinterpret_cast<const __half2*>(&q0.z)); aA1.x += w0*f.x; aA1.y += w0*f.y;
        f = __half22float2(*reinterpret_cast<const __half2*>(&q0.w)); aA1.z += w0*f.x; aA1.w += w0*f.y;
        f = __half22float2(*reinterpret_cast<const __half2*>(&q1.x)); aB0.x += w1*f.x; aB0.y += w1*f.y;
        f = __half22float2(*reinterpret_cast<const __half2*>(&q1.y)); aB0.z += w1*f.x; aB0.w += w1*f.y;
        f = __half22float2(*reinterpret_cast<const __half2*>(&q1.z)); aB1.x += w1*f.x; aB1.y += w1*f.y;
        f = __half22float2(*reinterpret_cast<const __half2*>(&q1.w)); aB1.z += w1*f.x; aB1.w += w1*f.y;
    }
    float4 c0, c1;
    c0.x = aA0.x + aB0.x; c0.y = aA0.y + aB0.y; c0.z = aA0.z + aB0.z; c0.w = aA0.w + aB0.w;
    c1.x = aA1.x + aB1.x; c1.y = aA1.y + aB1.y; c1.z = aA1.z + aB1.z; c1.w = aA1.w + aB1.w;
    // fold even/odd halves (lane L and L+32 cover the same channels & head)
    c0.x += __shfl_xor(c0.x, 32); c0.y += __shfl_xor(c0.y, 32);
    c0.z += __shfl_xor(c0.z, 32); c0.w += __shfl_xor(c0.w, 32);
    c1.x += __shfl_xor(c1.x, 32); c1.y += __shfl_xor(c1.y, 32);
    c1.z += __shfl_xor(c1.z, 32); c1.w += __shfl_xor(c1.w, 32);
    s += __shfl_xor(s, 32);
    float inv = 1.0f / (s + EPS_F);
    if (lane < 32) {
        const float4* b4 = reinterpret_cast<const float4*>(bias);
        float4 b0 = b4[cl * 2], b1 = b4[cl * 2 + 1];
        union { _Float16 h[8]; uint4 u; } st;
        st.h[0] = (_Float16)fmaxf(c0.x * inv + b0.x, 0.f);
        st.h[1] = (_Float16)fmaxf(c0.y * inv + b0.y, 0.f);
        st.h[2] = (_Float16)fmaxf(c0.z * inv + b0.z, 0.f);
        st.h[3] = (_Float16)fmaxf(c0.w * inv + b0.w, 0.f);
        st.h[4] = (_Float16)fmaxf(c1.x * inv + b1.x, 0.f);
        st.h[5] = (_Float16)fmaxf(c1.y * inv + b1.y, 0.f);
        st.h[6] = (_Float16)fmaxf(c1.z * inv + b1.z, 0.f);
        st.h[7] = (_Float16)fmaxf(c1.w * inv + b1.w, 0.f);
        reinterpret_cast<uint4*>(out)[(size_t)node * 32 + cl] = st.u;
    }
}

// ---------------------------------------------------------------------------
// Edge aggregation, layer 2 — round-2 form: 2 nodes per wave, 16-lane groups
// cover the 128-ch row via one uint4 gather, two edges per iteration.
// ---------------------------------------------------------------------------
__global__ __launch_bounds__(256) void edge2_kernel(const int* __restrict__ row_ptr,
                                                    const int* __restrict__ ssrc,
                                                    const __half* __restrict__ h2h,
                                                    const float* __restrict__ a_src,
                                                    const float* __restrict__ a_dst,
                                                    const float* __restrict__ bias,
                                                    float* __restrict__ out) {
    int lane = threadIdx.x & 63;
    int node = blockIdx.x * 8 + ((threadIdx.x >> 6) << 1) + (lane >> 5);
    int sub  = (lane >> 4) & 1;        // edge sub-slot within the 32-lane node group
    int cl   = lane & 15;              // channel-lane: ch [cl*8, cl*8+8)
    int start = row_ptr[node], end = row_ptr[node + 1];
    int em1 = end - 1;
    float ad = a_dst[node];

    const uint4* h2v = reinterpret_cast<const uint4*>(h2h);   // 8 halfs/uint4; 16 per row
    float4 aA0 = make_float4(0.f,0.f,0.f,0.f), aA1 = make_float4(0.f,0.f,0.f,0.f);
    float4 aB0 = make_float4(0.f,0.f,0.f,0.f), aB1 = make_float4(0.f,0.f,0.f,0.f);
    float s = 0.f;
    for (int e = start; e < end; e += 4) {
        int e0 = e + sub;
        int e1 = e + 2 + sub;
        int i0 = ssrc[e0 <= em1 ? e0 : em1];
        int i1 = ssrc[e1 <= em1 ? e1 : em1];
        float r0 = a_src[i0];
        float r1 = a_src[i1];
        uint4 q0 = h2v[(size_t)i0 * 16 + cl];
        uint4 q1 = h2v[(size_t)i1 * 16 + cl];
        float w0 = (e0 < end) ? __expf(lrelu(r0 + ad)) : 0.f;
        float w1 = (e1 < end) ? __expf(lrelu(r1 + ad)) : 0.f;
        s += w0 + w1;
        float2 f;
        f = __half22float2(*reinterpret_cast<const __half2*>(&q0.x)); aA0.x += w0*f.x; aA0.y += w0*f.y;
        f = __half22float2(*reinterpret_cast<const __half2*>(&q0.y)); aA0.z += w0*f.x; aA0.w += w0*f.y;
        f = __half22float2(*reinterpret_cast<const __half2*>(&q0.z)); aA1.x += w0*f.x; aA1.y += w0*f.y;
        f = __half22float2(*reinterpret_cast<const __half2*>(&q0.w)); aA1.z += w0*f.x; aA1.w += w0*f.y;
        f = __half22float2(*reinterpret_cast<const __half2*>(&q1.x)); aB0.x += w1*f.x; aB0.y += w1*f.y;
        f = __half22float2(*reinterpret_cast<const __half2*>(&q1.y)); aB0.z += w1*f.x; aB0.w += w1*f.y;
        f = __half22float2(*reinterpret_cast<const __half2*>(&q1.z)); aB1.x += w1*f.x; aB1.y += w1*f.y;
        f = __half22float2(*reinterpret_cast<const __half2*>(&q1.w)); aB1.z += w1*f.x; aB1.w += w1*f.y;
    }
    float4 c0, c1;
    c0.x = aA0.x + aB0.x; c0.y = aA0.y + aB0.y; c0.z = aA0.z + aB0.z; c0.w = aA0.w + aB0.w;
    c1.x = aA1.x + aB1.x; c1.y = aA1.y + aB1.y; c1.z = aA1.z + aB1.z; c1.w = aA1.w + aB1.w;
    // fold the two 16-lane edge groups within this node's 32-lane half
    c0.x += __shfl_xor(c0.x, 16); c0.y += __shfl_xor(c0.y, 16);
    c0.z += __shfl_xor(c0.z, 16); c0.w += __shfl_xor(c0.w, 16);
    c1.x += __shfl_xor(c1.x, 16); c1.y += __shfl_xor(c1.y, 16);
    c1.z += __shfl_xor(c1.z, 16); c1.w += __shfl_xor(c1.w, 16);
    s += __shfl_xor(s, 16);
    float inv = 1.0f / (s + EPS_F);
    if (sub == 0) {                     // 16 lanes per node write the 128-ch row
        const float4* b4 = reinterpret_cast<const float4*>(bias);
        float4 b0 = b4[cl * 2], b1 = b4[cl * 2 + 1];
        float4 o0, o1;
        o0.x = fmaxf(c0.x * inv + b0.x, 0.f);
        o0.y = fmaxf(c0.y * inv + b0.y, 0.f);
        o0.z = fmaxf(c0.z * inv + b0.z, 0.f);
        o0.w = fmaxf(c0.w * inv + b0.w, 0.f);
        o1.x = fmaxf(c1.x * inv + b1.x, 0.f);
        o1.y = fmaxf(c1.y * inv + b1.y, 0.f);
        o1.z = fmaxf(c1.z * inv + b1.z, 0.f);
        o1.w = fmaxf(c1.w * inv + b1.w, 0.f);
        float4* o4 = reinterpret_cast<float4*>(out) + (size_t)node * 32 + cl * 2;
        o4[0] = o0;
        o4[1] = o1;
    }
}

// ---------------------------------------------------------------------------
// Pooling with folded mean division.
// ---------------------------------------------------------------------------
#define POOL_CHUNK 64
__global__ __launch_bounds__(128) void pool_kernel(const float* __restrict__ out2,
                                                   const int* __restrict__ batch,
                                                   const int* __restrict__ gstart,
                                                   float* __restrict__ d_out) {
    int c = threadIdx.x;                 // channel 0..127
    int node0 = blockIdx.x * POOL_CHUNK;
    int nodeEnd = node0 + POOL_CHUNK; if (nodeEnd > N_NODES) nodeEnd = N_NODES;
    if (node0 >= N_NODES) return;
    int gprev = batch[node0];
    float acc = 0.f;
    for (int node = node0; node < nodeEnd; ++node) {
        int g = batch[node];
        if (g != gprev) {
            if (gprev >= 0 && gprev < N_GRAPHS) {
                float cnt = (float)(gstart[gprev + 1] - gstart[gprev]);
                if (cnt < 1.f) cnt = 1.f;
                atomicAdd(&d_out[gprev * 128 + c], acc / cnt);
            }
            acc = 0.f;
            gprev = g;
        }
        acc += out2[(size_t)node * 128 + c];
    }
    if (gprev >= 0 && gprev < N_GRAPHS) {
        float cnt = (float)(gstart[gprev + 1] - gstart[gprev]);
        if (cnt < 1.f) cnt = 1.f;
        atomicAdd(&d_out[gprev * 128 + c], acc / cnt);
    }
}

// ---------------------------------------------------------------------------
extern "C" void kernel_launch(void* const* d_in, const int* in_sizes, int n_in,
                              void* d_out_v, int out_size, void* d_ws, size_t ws_size,
                              hipStream_t stream) {
    const float* x      = (const float*)d_in[0];
    const float* W1     = (const float*)d_in[1];
    const float* att_s1 = (const float*)d_in[2];
    const float* att_d1 = (const float*)d_in[3];
    const float* bias1  = (const float*)d_in[4];
    const float* W2     = (const float*)d_in[5];
    const float* att_s2 = (const float*)d_in[6];
    const float* att_d2 = (const float*)d_in[7];
    const float* bias2  = (const float*)d_in[8];
    const int*   ei     = (const int*)d_in[9];
    const int*   batch  = (const int*)d_in[10];
    float* d_out = (float*)d_out_v;

    // Workspace layout (float units):
    //  [0, 6.4M)        xh fp16 [N,256]      ... later reused as h2h fp16 [N,128]
    //  [6.4M, 12.8M)    h1h fp16 [N,256]     ... later reused as out2 fp32 [N,128]
    //  [12.8M, 19.2M)   out1h fp16 [N,256]
    //  [19.2M, ...)     attention scalars + CSR/sort buffers + W transposes
    float* ws = (float*)d_ws;
    _Float16* xh    = (_Float16*)ws;
    _Float16* h1h   = (_Float16*)(ws + 6400000);
    _Float16* out1h = (_Float16*)(ws + 12800000);
    _Float16* h2h   = (_Float16*)ws;            // xh dead after GEMM1
    float*    out2  = ws + 6400000;             // h1h dead after edge1
    float* a_src1 = ws + 19200000;              // N*4
    float* a_dst1 = a_src1 + 200000;            // N*4
    float* a_src2 = a_dst1 + 200000;            // N
    float* a_dst2 = a_src2 + 50000;             // N
    int* row_ptr  = (int*)(a_dst2 + 50000);     // N+1 (padded to 50016)
    int* ssrc     = row_ptr + 50016;            // E_TOT
    int* ebuf     = ssrc + 850000;              // NBUCKET * EBUF_CAP fixed regions
    int* gcur     = ebuf + (NBUCKET * EBUF_CAP);// 512 (bucket cursors/counts)
    int* gstart   = gcur + 512;                 // N_GRAPHS+1 (pad 128)
    _Float16* W1t = (_Float16*)(gstart + 128);  // 65536 halfs [256][256]
    _Float16* W2t = W1t + 65536;                // 32768 halfs [128][256]

    // 1. Fused prep: cast x, transpose W1/W2, graph bounds, zero d_out+gcur
    prep_kernel<<<PREP_TOTAL, 256, 0, stream>>>(x, xh, W1, W1t, W2, W2t,
                                                batch, gstart, gcur, d_out);

    // 2. Bin edges into fixed per-bucket regions (global-atomic reserve)
    bucket_bin<<<BIN_BLOCKS, 256, 0, stream>>>(ei, gcur, ebuf);

    // 3. FUSED: bucket sort (391 blocks) + GEMM1 (782 tiles) in one dispatch
    sort_gemm1_kernel<<<NBUCKET + GEMM1_MB * 2, 256, 0, stream>>>(
        gcur, ebuf, ssrc, row_ptr, xh, W1t, h1h,
        att_s1, att_d1, a_src1, a_dst1);

    // 4. Layer-1 edge aggregation
    edge1_kernel<<<N_NODES / 4, 256, 0, stream>>>(row_ptr, ssrc, (const __half*)h1h,
                                                  a_src1, a_dst1, bias1, (__half*)out1h);

    // 5. GEMM2: h2 = out1 @ W2 (att2 folded via LDS combine)
    gemm_mfma_kernel<<<(N_NODES + 127) / 128, 256, 0, stream>>>(
        out1h, W2t, h2h, att_s2, att_d2, a_src2, a_dst2, N_NODES, OUT_C);

    // 6. Layer-2 edge aggregation
    edge2_kernel<<<N_NODES / 8, 256, 0, stream>>>(row_ptr, ssrc, (const __half*)h2h,
                                                  a_src2, a_dst2, bias2, out2);

    // 7. Pooling (mean division folded into the atomic flush)
    pool_kernel<<<(N_NODES + POOL_CHUNK - 1) / POOL_CHUNK, 128, 0, stream>>>(out2, batch, gstart, d_out);
}

// Round 8
// 293.348 us; speedup vs baseline: 1.1821x; 1.0213x over previous
//
#include <hip/hip_runtime.h>
#include <hip/hip_bf16.h>
#include <hip/hip_fp16.h>

// Problem constants (fixed by the reference setup)
#define N_NODES 50000
#define N_EDGES 800000
#define E_TOT   (N_EDGES + N_NODES)   // 850000 (self-loops appended)
#define IN_C    256
#define H1C     256                    // HEADS * HID_C = 4*64
#define HEADS   4
#define HID_C   64
#define OUT_C   128
#define N_GRAPHS 100
#define NEG_SLOPE 0.2f
#define EPS_F 1e-16f

// Bucket sort: order within a bucket is irrelevant (bucket_sort rebuilds
// per-node order), so bin reserves space via global atomics into FIXED
// per-bucket ebuf regions — no cross-block prefix needed.
#define NBUCKET 391                   // ceil(50000 / 128), bucket = dst >> 7
#define BIN_BLOCKS 104
#define EDGES_PER_SB 8192             // 104*8192 = 851968 >= E_TOT
#define EBUF_CAP 4096                 // per-bucket region (span avg ~2176, max<3072)
#define STAGE_CAP 4096                // LDS staging = EBUF_CAP (no fallback)
#define GEMM1_MB 391                  // gemm1 M-tiles; grid adds 2 N-tiles

// prep_kernel block partition (bin FIRST: heaviest blocks dispatch earliest)
#define PREP_BIN_BLOCKS    104
#define PREP_CAST_BLOCKS   12500      // 3,200,000 uint2 / 256
#define PREP_W1_BLOCKS     256        // 65536 / 256
#define PREP_W2_BLOCKS     128        // 32768 / 256
#define PREP_BOUNDS_BLOCKS 196
#define PREP_DOUT_BLOCKS   50         // 12800 floats / 256
#define PREP_TOTAL (PREP_BIN_BLOCKS + PREP_CAST_BLOCKS + PREP_W1_BLOCKS + PREP_W2_BLOCKS + PREP_BOUNDS_BLOCKS + PREP_DOUT_BLOCKS)

typedef _Float16 half8_t __attribute__((ext_vector_type(8)));
typedef float f32x4 __attribute__((ext_vector_type(4)));

// global_load_lds helper: width=16 (global_load_lds_dwordx4), LDS dest is
// wave-uniform base + lane*16 (m104); global src address is PER-LANE, which
// is how the chunk swizzle is applied (pre-swizzled source, m173 pattern).
__device__ __forceinline__ void gll16(const void* g, void* l) {
    __builtin_amdgcn_global_load_lds(
        (const __attribute__((address_space(1))) void*)g,
        (__attribute__((address_space(3))) void*)l, 16, 0, 0);
}

// ---------------------------------------------------------------------------
// Fused prep: bucket_bin + cast_x + W1t + W2t + bounds + d_out=0.
// bin requires gcur pre-zeroed (hipMemsetAsync in stream before this).
// ---------------------------------------------------------------------------
__global__ __launch_bounds__(256) void prep_kernel(const float* __restrict__ x,
                                                   _Float16* __restrict__ xh,
                                                   const float* __restrict__ W1,
                                                   _Float16* __restrict__ W1t,
                                                   const float* __restrict__ W2,
                                                   _Float16* __restrict__ W2t,
                                                   const int* __restrict__ ei,
                                                   int* __restrict__ gcur,
                                                   int* __restrict__ ebuf,
                                                   const int* __restrict__ batch,
                                                   int* __restrict__ gstart,
                                                   float* __restrict__ d_out) {
    __shared__ int bh[NBUCKET];
    __shared__ int bofs[NBUCKET];
    int b = blockIdx.x;
    int tid = threadIdx.x;
    if (b < PREP_BIN_BLOCKS) {
        // ---- bucket_bin: LDS histogram -> one global atomicAdd per
        // (block,bucket) reserving a run in the bucket's fixed region ----
        for (int t = tid; t < NBUCKET; t += 256) bh[t] = 0;
        __syncthreads();
        int base = b * EDGES_PER_SB;
#pragma unroll 4
        for (int k = 0; k < EDGES_PER_SB / 256; ++k) {
            int idx = base + k * 256 + tid;
            int d = -1;
            if (idx < N_EDGES) d = ei[N_EDGES + idx];
            else if (idx < E_TOT) d = idx - N_EDGES;
            if (d >= 0 && d < N_NODES) atomicAdd(&bh[d >> 7], 1);
        }
        __syncthreads();
        for (int t = tid; t < NBUCKET; t += 256) {
            int c = bh[t];
            bofs[t] = (c > 0) ? atomicAdd(&gcur[t], c) : 0;
            bh[t] = 0;                 // reuse as local cursor
        }
        __syncthreads();
#pragma unroll 4
        for (int k = 0; k < EDGES_PER_SB / 256; ++k) {
            int idx = base + k * 256 + tid;
            int s = 0, d = -1;
            if (idx < N_EDGES) { s = ei[idx]; d = ei[N_EDGES + idx]; }
            else if (idx < E_TOT) { s = idx - N_EDGES; d = s; }
            if (d >= 0 && d < N_NODES) {
                int t = d >> 7;
                int p = bofs[t] + atomicAdd(&bh[t], 1);
                if (p < EBUF_CAP)      // defensive; never fires for this input
                    ebuf[t * EBUF_CAP + p] = (s & 0xFFFF) | ((d & 127) << 16);
            }
        }
        return;
    }
    b -= PREP_BIN_BLOCKS;
    if (b < PREP_CAST_BLOCKS) {
        int idx = b * 256 + tid;                      // < 3,200,000 exactly
        float4 v = reinterpret_cast<const float4*>(x)[idx];
        union { _Float16 h[4]; uint2 u; } p;
        p.h[0] = (_Float16)v.x; p.h[1] = (_Float16)v.y;
        p.h[2] = (_Float16)v.z; p.h[3] = (_Float16)v.w;
        reinterpret_cast<uint2*>(xh)[idx] = p.u;
        return;
    }
    b -= PREP_CAST_BLOCKS;
    if (b < PREP_W1_BLOCKS) {
        int idx = b * 256 + tid;                      // < 65536 exactly
        int n = idx >> 8, k = idx & 255;
        W1t[idx] = (_Float16)W1[k * 256 + n];
        return;
    }
    b -= PREP_W1_BLOCKS;
    if (b < PREP_W2_BLOCKS) {
        int idx = b * 256 + tid;                      // < 32768 exactly
        int n = idx >> 8, k = idx & 255;
        W2t[idx] = (_Float16)W2[k * 128 + n];
        return;
    }
    b -= PREP_W2_BLOCKS;
    if (b < PREP_BOUNDS_BLOCKS) {   // bounds: batch sorted; each gstart entry written exactly once
        int idx = b * 256 + tid;
        if (idx >= N_NODES) return;
        int g = batch[idx];
        if (g < 0) g = 0; if (g >= N_GRAPHS) g = N_GRAPHS - 1;
        if (idx == 0) {
            for (int j = 0; j <= g; ++j) gstart[j] = 0;
        } else {
            int gp = batch[idx - 1];
            if (gp < 0) gp = 0; if (gp >= N_GRAPHS) gp = N_GRAPHS - 1;
            for (int j = gp + 1; j <= g; ++j) gstart[j] = idx;
        }
        if (idx == N_NODES - 1) {
            for (int j = g + 1; j <= N_GRAPHS; ++j) gstart[j] = N_NODES;
        }
        return;
    }
    b -= PREP_BOUNDS_BLOCKS;
    {   // zero d_out (pool accumulates atomically much later in the stream)
        int idx = b * 256 + tid;
        if (idx < N_GRAPHS * 128) d_out[idx] = 0.f;
    }
}

// ---------------------------------------------------------------------------
// FUSED bucket_sort + GEMM1. GEMM staging rewritten with global_load_lds
// width=16 (Common-mistake #1: compiler never auto-emits; reg-staging vs
// glld measured 646 vs 874 TF, m151). LDS is linear [128 rows][64B] per
// operand; bank conflicts on ds_read_b128 fixed by chunk XOR swizzle
// (both-sides rule #21): chunk c of local row r lives at position
// c ^ ((r>>1)&3)  ->  read banks spread 16 lanes over 8 banks = 2-way (free).
// The swizzle is applied on the PER-LANE GLOBAL source address (m173) since
// glld's LDS dest is fixed at wave-base + lane*16 (m104).
// LDS: union(sort 17408B, gemm 16384B) = 17408B (was 29.7KB).
// ---------------------------------------------------------------------------
__global__ __launch_bounds__(256) void sort_gemm1_kernel(const int* __restrict__ gcur,
                                                         const int* __restrict__ ebuf,
                                                         int* __restrict__ ssrc,
                                                         int* __restrict__ row_ptr,
                                                         const _Float16* __restrict__ A,
                                                         const _Float16* __restrict__ Bt,
                                                         _Float16* __restrict__ C,
                                                         const float* __restrict__ attS,
                                                         const float* __restrict__ attD,
                                                         float* __restrict__ a_src_o,
                                                         float* __restrict__ a_dst_o) {
    __shared__ __align__(16) char smem[17408];
    __shared__ int s_off;
    const int tid = threadIdx.x;

    if (blockIdx.x < NBUCKET) {
        // ---------------- sort path ----------------
        int* cnt   = reinterpret_cast<int*>(smem);          // 128
        int* sc    = cnt + 128;                             // 128
        int* stage = sc + 128;                              // STAGE_CAP
        int j = blockIdx.x;
        if (tid < 64) {                 // lo = sum of bucket counts < j
            int acc = 0;
            for (int i = tid; i < j; i += 64) {
                int c = gcur[i];
                acc += (c < EBUF_CAP) ? c : EBUF_CAP;
            }
#pragma unroll
            for (int off = 32; off > 0; off >>= 1) acc += __shfl_down(acc, off);
            if (tid == 0) s_off = acc;
        }
        if (tid < 128) cnt[tid] = 0;
        __syncthreads();
        int span = gcur[j]; if (span > EBUF_CAP) span = EBUF_CAP;
        int lo = s_off;
        const int* eb = ebuf + j * EBUF_CAP;
        for (int t = tid; t < span; t += 256)
            atomicAdd(&cnt[(eb[t] >> 16) & 127], 1);
        __syncthreads();
        if (tid < 128) sc[tid] = cnt[tid];
        __syncthreads();
#pragma unroll
        for (int off = 1; off < 128; off <<= 1) {
            int u = (tid >= off && tid < 128) ? sc[tid - off] : 0;
            __syncthreads();
            if (tid < 128) sc[tid] += u;
            __syncthreads();
        }
        int jn0 = j << 7;
        int nNodes = N_NODES - jn0; if (nNodes > 128) nNodes = 128;
        if (tid < 128) {
            int excl = sc[tid] - cnt[tid];
            if (tid < nNodes) row_ptr[jn0 + tid] = lo + excl;   // CSR byproduct
            cnt[tid] = excl;                                     // reuse as cursor
        }
        if (j == NBUCKET - 1 && tid == 0) row_ptr[N_NODES] = lo + span;
        __syncthreads();
        for (int t = tid; t < span; t += 256) {
            int v = eb[t];
            int p = atomicAdd(&cnt[(v >> 16) & 127], 1);
            stage[p] = v & 0xFFFF;
        }
        __syncthreads();
        for (int t = tid; t < span; t += 256) ssrc[lo + t] = stage[t];
        return;
    }

    // ---------------- gemm1 path (M=N_NODES, N=256, mode-1 epilogue) ----------------
    _Float16* As = reinterpret_cast<_Float16*>(smem);          // [128][32] halfs
    _Float16* Bs = reinterpret_cast<_Float16*>(smem + 8192);   // [128][32] halfs
    int b2 = blockIdx.x - NBUCKET;
    const int tileM = (b2 >= GEMM1_MB ? b2 - GEMM1_MB : b2) * 128;
    const int tileN = (b2 >= GEMM1_MB) ? 128 : 0;
    const int w = tid >> 6, lane = tid & 63;
    const int wm = (w >> 1) * 64, wn = (w & 1) * 64;
    const int quad = lane >> 4, mlane = lane & 15;
    // glld lane geometry: wave w stages rows [w*16, w*16+16) of each half-tile
    const int lrow = lane >> 2;            // 0..15 within wave
    const int pos  = lane & 3;             // 16B chunk slot in LDS row
    const int ra0  = w * 16 + lrow;        // local rows 0..63  (half-tile 0)
    const int ra1  = ra0 + 64;             // local rows 64..127 (half-tile 1)
    const int ca0  = pos ^ ((ra0 >> 1) & 3);  // source chunk (swizzle)
    const int ca1  = pos ^ ((ra1 >> 1) & 3);

    f32x4 zero = {0.f, 0.f, 0.f, 0.f};
    f32x4 acc[4][4];
#pragma unroll
    for (int i = 0; i < 4; ++i)
#pragma unroll
        for (int j = 0; j < 4; ++j) acc[i][j] = zero;

    // rows >= M read garbage (within workspace, outputs guarded) — safe.
    const _Float16* gA0 = A + (size_t)(tileM + ra0) * 256 + ca0 * 8;
    const _Float16* gA1 = A + (size_t)(tileM + ra1) * 256 + ca1 * 8;
    const _Float16* gB0 = Bt + (size_t)(tileN + ra0) * 256 + ca0 * 8;
    const _Float16* gB1 = Bt + (size_t)(tileN + ra1) * 256 + ca1 * 8;
    _Float16* lA0 = As + w * 512;          // wave-uniform LDS bases (1KB/wave)
    _Float16* lA1 = As + 2048 + w * 512;
    _Float16* lB0 = Bs + w * 512;
    _Float16* lB1 = Bs + 2048 + w * 512;

    for (int k0 = 0; k0 < 256; k0 += 32) {
        __syncthreads();                   // prior ds_reads done before overwrite
        gll16(gA0 + k0, lA0);
        gll16(gA1 + k0, lA1);
        gll16(gB0 + k0, lB0);
        gll16(gB1 + k0, lB1);
        __syncthreads();                   // vmcnt(0) drain + barrier
        half8_t af[4], bf[4];
#pragma unroll
        for (int mt = 0; mt < 4; ++mt) {
            int ra = wm + mt * 16 + mlane;
            af[mt] = *reinterpret_cast<const half8_t*>(As + ra * 32 + ((quad ^ ((ra >> 1) & 3)) << 3));
        }
#pragma unroll
        for (int nt = 0; nt < 4; ++nt) {
            int rb = wn + nt * 16 + mlane;
            bf[nt] = *reinterpret_cast<const half8_t*>(Bs + rb * 32 + ((quad ^ ((rb >> 1) & 3)) << 3));
        }
#pragma unroll
        for (int mt = 0; mt < 4; ++mt)
#pragma unroll
            for (int nt = 0; nt < 4; ++nt)
                acc[mt][nt] = __builtin_amdgcn_mfma_f32_16x16x32_f16(af[mt], bf[nt], acc[mt][nt], 0, 0, 0);
    }
#pragma unroll
    for (int mt = 0; mt < 4; ++mt) {
#pragma unroll
        for (int i = 0; i < 4; ++i) {
            int row = tileM + wm + mt * 16 + quad * 4 + i;
            if (row < N_NODES) {
                _Float16* cp = C + (size_t)row * 256 + tileN + wn;
#pragma unroll
                for (int nt = 0; nt < 4; ++nt)
                    cp[nt * 16 + mlane] = (_Float16)acc[mt][nt][i];
            }
        }
    }
    {   // mode-1 epilogue: per-head attention dots
        int hd = (tileN + wn) >> 6;
        float as[4], ad[4];
#pragma unroll
        for (int nt = 0; nt < 4; ++nt) {
            as[nt] = attS[hd * 64 + nt * 16 + mlane];
            ad[nt] = attD[hd * 64 + nt * 16 + mlane];
        }
#pragma unroll
        for (int mt = 0; mt < 4; ++mt) {
#pragma unroll
            for (int i = 0; i < 4; ++i) {
                float ps = acc[mt][0][i] * as[0] + acc[mt][1][i] * as[1]
                         + acc[mt][2][i] * as[2] + acc[mt][3][i] * as[3];
                float pd = acc[mt][0][i] * ad[0] + acc[mt][1][i] * ad[1]
                         + acc[mt][2][i] * ad[2] + acc[mt][3][i] * ad[3];
#pragma unroll
                for (int off = 1; off < 16; off <<= 1) {
                    ps += __shfl_xor(ps, off);
                    pd += __shfl_xor(pd, off);
                }
                if (mlane == 0) {
                    int row = tileM + wm + mt * 16 + quad * 4 + i;
                    if (row < N_NODES) {
                        a_src_o[row * 4 + hd] = ps;
                        a_dst_o[row * 4 + hd] = pd;
                    }
                }
            }
        }
    }
}

// ---------------------------------------------------------------------------
// GEMM2 (standalone, mode-2 epilogue) — same glld+swizzle staging.
// ---------------------------------------------------------------------------
__global__ __launch_bounds__(256) void gemm_mfma_kernel(const _Float16* __restrict__ A,
                                                        const _Float16* __restrict__ Bt,
                                                        _Float16* __restrict__ C,
                                                        const float* __restrict__ attS,
                                                        const float* __restrict__ attD,
                                                        float* __restrict__ a_src_o,
                                                        float* __restrict__ a_dst_o,
                                                        int M, int N) {
    __shared__ __align__(16) _Float16 As[4096];   // [128][32] halfs
    __shared__ __align__(16) _Float16 Bs[4096];
    __shared__ float lds_ps[128];
    __shared__ float lds_pd[128];
    const int tid = threadIdx.x;
    const int tileM = blockIdx.x * 128;
    const int tileN = 0;
    const int w = tid >> 6, lane = tid & 63;
    const int wm = (w >> 1) * 64, wn = (w & 1) * 64;
    const int quad = lane >> 4, mlane = lane & 15;
    const int lrow = lane >> 2;
    const int pos  = lane & 3;
    const int ra0  = w * 16 + lrow;
    const int ra1  = ra0 + 64;
    const int ca0  = pos ^ ((ra0 >> 1) & 3);
    const int ca1  = pos ^ ((ra1 >> 1) & 3);

    f32x4 zero = {0.f, 0.f, 0.f, 0.f};
    f32x4 acc[4][4];
#pragma unroll
    for (int i = 0; i < 4; ++i)
#pragma unroll
        for (int j = 0; j < 4; ++j) acc[i][j] = zero;

    const _Float16* gA0 = A + (size_t)(tileM + ra0) * 256 + ca0 * 8;
    const _Float16* gA1 = A + (size_t)(tileM + ra1) * 256 + ca1 * 8;
    const _Float16* gB0 = Bt + (size_t)(tileN + ra0) * 256 + ca0 * 8;
    const _Float16* gB1 = Bt + (size_t)(tileN + ra1) * 256 + ca1 * 8;
    _Float16* lA0 = As + w * 512;
    _Float16* lA1 = As + 2048 + w * 512;
    _Float16* lB0 = Bs + w * 512;
    _Float16* lB1 = Bs + 2048 + w * 512;

    for (int k0 = 0; k0 < 256; k0 += 32) {
        __syncthreads();
        gll16(gA0 + k0, lA0);
        gll16(gA1 + k0, lA1);
        gll16(gB0 + k0, lB0);
        gll16(gB1 + k0, lB1);
        __syncthreads();
        half8_t af[4], bf[4];
#pragma unroll
        for (int mt = 0; mt < 4; ++mt) {
            int ra = wm + mt * 16 + mlane;
            af[mt] = *reinterpret_cast<const half8_t*>(As + ra * 32 + ((quad ^ ((ra >> 1) & 3)) << 3));
        }
#pragma unroll
        for (int nt = 0; nt < 4; ++nt) {
            int rb = wn + nt * 16 + mlane;
            bf[nt] = *reinterpret_cast<const half8_t*>(Bs + rb * 32 + ((quad ^ ((rb >> 1) & 3)) << 3));
        }
#pragma unroll
        for (int mt = 0; mt < 4; ++mt)
#pragma unroll
            for (int nt = 0; nt < 4; ++nt)
                acc[mt][nt] = __builtin_amdgcn_mfma_f32_16x16x32_f16(af[mt], bf[nt], acc[mt][nt], 0, 0, 0);
    }
#pragma unroll
    for (int mt = 0; mt < 4; ++mt) {
#pragma unroll
        for (int i = 0; i < 4; ++i) {
            int row = tileM + wm + mt * 16 + quad * 4 + i;
            if (row < M) {
                _Float16* cp = C + (size_t)row * N + tileN + wn;
#pragma unroll
                for (int nt = 0; nt < 4; ++nt)
                    cp[nt * 16 + mlane] = (_Float16)acc[mt][nt][i];
            }
        }
    }
    {   // mode-2 epilogue: single head, two waves combine via LDS
        float as[4], ad[4];
#pragma unroll
        for (int nt = 0; nt < 4; ++nt) {
            as[nt] = attS[wn + nt * 16 + mlane];
            ad[nt] = attD[wn + nt * 16 + mlane];
        }
        float psa[4][4], pda[4][4];
#pragma unroll
        for (int mt = 0; mt < 4; ++mt) {
#pragma unroll
            for (int i = 0; i < 4; ++i) {
                float ps = acc[mt][0][i] * as[0] + acc[mt][1][i] * as[1]
                         + acc[mt][2][i] * as[2] + acc[mt][3][i] * as[3];
                float pd = acc[mt][0][i] * ad[0] + acc[mt][1][i] * ad[1]
                         + acc[mt][2][i] * ad[2] + acc[mt][3][i] * ad[3];
#pragma unroll
                for (int off = 1; off < 16; off <<= 1) {
                    ps += __shfl_xor(ps, off);
                    pd += __shfl_xor(pd, off);
                }
                psa[mt][i] = ps; pda[mt][i] = pd;
            }
        }
        __syncthreads();
        if (wn == 0 && mlane == 0) {
#pragma unroll
            for (int mt = 0; mt < 4; ++mt)
#pragma unroll
                for (int i = 0; i < 4; ++i) {
                    int lr = wm + mt * 16 + quad * 4 + i;
                    lds_ps[lr] = psa[mt][i];
                    lds_pd[lr] = pda[mt][i];
                }
        }
        __syncthreads();
        if (wn == 64 && mlane == 0) {
#pragma unroll
            for (int mt = 0; mt < 4; ++mt)
#pragma unroll
                for (int i = 0; i < 4; ++i) {
                    int lr = wm + mt * 16 + quad * 4 + i;
                    int row = tileM + lr;
                    if (row < M) {
                        a_src_o[row] = psa[mt][i] + lds_ps[lr];
                        a_dst_o[row] = pda[mt][i] + lds_pd[lr];
                    }
                }
        }
    }
}

__device__ __forceinline__ float lrelu(float x) { return x > 0.f ? x : NEG_SLOPE * x; }

// ---------------------------------------------------------------------------
// Edge aggregation, layer 1 — round-2 form, the verified 65us optimum
// (4 structural variants all land 65±1us: platform random-gather ceiling).
// ---------------------------------------------------------------------------
__global__ __launch_bounds__(256) void edge1_kernel(const int* __restrict__ row_ptr,
                                                    const int* __restrict__ ssrc,
                                                    const __half* __restrict__ h1h,
                                                    const float* __restrict__ a_src,
                                                    const float* __restrict__ a_dst,
                                                    const float* __restrict__ bias,
                                                    __half* __restrict__ out) {
    int node = blockIdx.x * 4 + (threadIdx.x >> 6);
    int lane = threadIdx.x & 63;
    int hf   = lane >> 5;              // 0: even edges, 1: odd edges
    int cl   = lane & 31;              // channel-lane: ch [cl*8, cl*8+8)
    int hd   = cl >> 3;                // head = ch/64
    int start = row_ptr[node], end = row_ptr[node + 1];
    int em1 = end - 1;                 // >= start (self-loop guarantees deg>=1)
    float adh = a_dst[node * 4 + hd];

    const uint4* h1v = reinterpret_cast<const uint4*>(h1h);   // 8 halfs/uint4; 32 per row
    float4 aA0 = make_float4(0.f,0.f,0.f,0.f), aA1 = make_float4(0.f,0.f,0.f,0.f);
    float4 aB0 = make_float4(0.f,0.f,0.f,0.f), aB1 = make_float4(0.f,0.f,0.f,0.f);
    float s = 0.f;
    for (int e = start; e < end; e += 4) {
        int e0 = e + hf;
        int e1 = e + 2 + hf;
        int i0 = ssrc[e0 <= em1 ? e0 : em1];
        int i1 = ssrc[e1 <= em1 ? e1 : em1];
        float r0 = a_src[i0 * 4 + hd];
        float r1 = a_src[i1 * 4 + hd];
        uint4 q0 = h1v[(size_t)i0 * 32 + cl];
        uint4 q1 = h1v[(size_t)i1 * 32 + cl];
        float w0 = (e0 < end) ? __expf(lrelu(r0 + adh)) : 0.f;
        float w1 = (e1 < end) ? __expf(lrelu(r1 + adh)) : 0.f;
        s += w0 + w1;
        float2 f;
        f = __half22float2(*reinterpret_cast<const __half2*>(&q0.x)); aA0.x += w0*f.x; aA0.y += w0*f.y;
        f = __half22float2(*reinterpret_cast<const __half2*>(&q0.y)); aA0.z += w0*f.x; aA0.w += w0*f.y;
        f = __half22float2(*reinterpret_cast<const __half2*>(&q0.z)); aA1.x += w0*f.x; aA1.y += w0*f.y;
        f = __half22float2(*reinterpret_cast<const __half2*>(&q0.w)); aA1.z += w0*f.x; aA1.w += w0*f.y;
        f = __half22float2(*reinterpret_cast<const __half2*>(&q1.x)); aB0.x += w1*f.x; aB0.y += w1*f.y;
        f = __half22float2(*reinterpret_cast<const __half2*>(&q1.y)); aB0.z += w1*f.x; aB0.w += w1*f.y;
        f = __half22float2(*reinterpret_cast<const __half2*>(&q1.z)); aB1.x += w1*f.x; aB1.y += w1*f.y;
        f = __half22float2(*reinterpret_cast<const __half2*>(&q1.w)); aB1.z += w1*f.x; aB1.w += w1*f.y;
    }
    float4 c0, c1;
    c0.x = aA0.x + aB0.x; c0.y = aA0.y + aB0.y; c0.z = aA0.z + aB0.z; c0.w = aA0.w + aB0.w;
    c1.x = aA1.x + aB1.x; c1.y = aA1.y + aB1.y; c1.z = aA1.z + aB1.z; c1.w = aA1.w + aB1.w;
    // fold even/odd halves (lane L and L+32 cover the same channels & head)
    c0.x += __shfl_xor(c0.x, 32); c0.y += __shfl_xor(c0.y, 32);
    c0.z += __shfl_xor(c0.z, 32); c0.w += __shfl_xor(c0.w, 32);
    c1.x += __shfl_xor(c1.x, 32); c1.y += __shfl_xor(c1.y, 32);
    c1.z += __shfl_xor(c1.z, 32); c1.w += __shfl_xor(c1.w, 32);
    s += __shfl_xor(s, 32);
    float inv = 1.0f / (s + EPS_F);
    if (lane < 32) {
        const float4* b4 = reinterpret_cast<const float4*>(bias);
        float4 b0 = b4[cl * 2], b1 = b4[cl * 2 + 1];
        union { _Float16 h[8]; uint4 u; } st;
        st.h[0] = (_Float16)fmaxf(c0.x * inv + b0.x, 0.f);
        st.h[1] = (_Float16)fmaxf(c0.y * inv + b0.y, 0.f);
        st.h[2] = (_Float16)fmaxf(c0.z * inv + b0.z, 0.f);
        st.h[3] = (_Float16)fmaxf(c0.w * inv + b0.w, 0.f);
        st.h[4] = (_Float16)fmaxf(c1.x * inv + b1.x, 0.f);
        st.h[5] = (_Float16)fmaxf(c1.y * inv + b1.y, 0.f);
        st.h[6] = (_Float16)fmaxf(c1.z * inv + b1.z, 0.f);
        st.h[7] = (_Float16)fmaxf(c1.w * inv + b1.w, 0.f);
        reinterpret_cast<uint4*>(out)[(size_t)node * 32 + cl] = st.u;
    }
}

// ---------------------------------------------------------------------------
// Edge aggregation, layer 2 — round-2 form: 2 nodes per wave, 16-lane groups
// cover the 128-ch row via one uint4 gather, two edges per iteration.
// ---------------------------------------------------------------------------
__global__ __launch_bounds__(256) void edge2_kernel(const int* __restrict__ row_ptr,
                                                    const int* __restrict__ ssrc,
                                                    const __half* __restrict__ h2h,
                                                    const float* __restrict__ a_src,
                                                    const float* __restrict__ a_dst,
                                                    const float* __restrict__ bias,
                                                    float* __restrict__ out) {
    int lane = threadIdx.x & 63;
    int node = blockIdx.x * 8 + ((threadIdx.x >> 6) << 1) + (lane >> 5);
    int sub  = (lane >> 4) & 1;        // edge sub-slot within the 32-lane node group
    int cl   = lane & 15;              // channel-lane: ch [cl*8, cl*8+8)
    int start = row_ptr[node], end = row_ptr[node + 1];
    int em1 = end - 1;
    float ad = a_dst[node];

    const uint4* h2v = reinterpret_cast<const uint4*>(h2h);   // 8 halfs/uint4; 16 per row
    float4 aA0 = make_float4(0.f,0.f,0.f,0.f), aA1 = make_float4(0.f,0.f,0.f,0.f);
    float4 aB0 = make_float4(0.f,0.f,0.f,0.f), aB1 = make_float4(0.f,0.f,0.f,0.f);
    float s = 0.f;
    for (int e = start; e < end; e += 4) {
        int e0 = e + sub;
        int e1 = e + 2 + sub;
        int i0 = ssrc[e0 <= em1 ? e0 : em1];
        int i1 = ssrc[e1 <= em1 ? e1 : em1];
        float r0 = a_src[i0];
        float r1 = a_src[i1];
        uint4 q0 = h2v[(size_t)i0 * 16 + cl];
        uint4 q1 = h2v[(size_t)i1 * 16 + cl];
        float w0 = (e0 < end) ? __expf(lrelu(r0 + ad)) : 0.f;
        float w1 = (e1 < end) ? __expf(lrelu(r1 + ad)) : 0.f;
        s += w0 + w1;
        float2 f;
        f = __half22float2(*reinterpret_cast<const __half2*>(&q0.x)); aA0.x += w0*f.x; aA0.y += w0*f.y;
        f = __half22float2(*reinterpret_cast<const __half2*>(&q0.y)); aA0.z += w0*f.x; aA0.w += w0*f.y;
        f = __half22float2(*reinterpret_cast<const __half2*>(&q0.z)); aA1.x += w0*f.x; aA1.y += w0*f.y;
        f = __half22float2(*reinterpret_cast<const __half2*>(&q0.w)); aA1.z += w0*f.x; aA1.w += w0*f.y;
        f = __half22float2(*reinterpret_cast<const __half2*>(&q1.x)); aB0.x += w1*f.x; aB0.y += w1*f.y;
        f = __half22float2(*reinterpret_cast<const __half2*>(&q1.y)); aB0.z += w1*f.x; aB0.w += w1*f.y;
        f = __half22float2(*reinterpret_cast<const __half2*>(&q1.z)); aB1.x += w1*f.x; aB1.y += w1*f.y;
        f = __half22float2(*reinterpret_cast<const __half2*>(&q1.w)); aB1.z += w1*f.x; aB1.w += w1*f.y;
    }
    float4 c0, c1;
    c0.x = aA0.x + aB0.x; c0.y = aA0.y + aB0.y; c0.z = aA0.z + aB0.z; c0.w = aA0.w + aB0.w;
    c1.x = aA1.x + aB1.x; c1.y = aA1.y + aB1.y; c1.z = aA1.z + aB1.z; c1.w = aA1.w + aB1.w;
    // fold the two 16-lane edge groups within this node's 32-lane half
    c0.x += __shfl_xor(c0.x, 16); c0.y += __shfl_xor(c0.y, 16);
    c0.z += __shfl_xor(c0.z, 16); c0.w += __shfl_xor(c0.w, 16);
    c1.x += __shfl_xor(c1.x, 16); c1.y += __shfl_xor(c1.y, 16);
    c1.z += __shfl_xor(c1.z, 16); c1.w += __shfl_xor(c1.w, 16);
    s += __shfl_xor(s, 16);
    float inv = 1.0f / (s + EPS_F);
    if (sub == 0) {                     // 16 lanes per node write the 128-ch row
        const float4* b4 = reinterpret_cast<const float4*>(bias);
        float4 b0 = b4[cl * 2], b1 = b4[cl * 2 + 1];
        float4 o0, o1;
        o0.x = fmaxf(c0.x * inv + b0.x, 0.f);
        o0.y = fmaxf(c0.y * inv + b0.y, 0.f);
        o0.z = fmaxf(c0.z * inv + b0.z, 0.f);
        o0.w = fmaxf(c0.w * inv + b0.w, 0.f);
        o1.x = fmaxf(c1.x * inv + b1.x, 0.f);
        o1.y = fmaxf(c1.y * inv + b1.y, 0.f);
        o1.z = fmaxf(c1.z * inv + b1.z, 0.f);
        o1.w = fmaxf(c1.w * inv + b1.w, 0.f);
        float4* o4 = reinterpret_cast<float4*>(out) + (size_t)node * 32 + cl * 2;
        o4[0] = o0;
        o4[1] = o1;
    }
}

// ---------------------------------------------------------------------------
// Pooling with folded mean division.
// ---------------------------------------------------------------------------
#define POOL_CHUNK 64
__global__ __launch_bounds__(128) void pool_kernel(const float* __restrict__ out2,
                                                   const int* __restrict__ batch,
                                                   const int* __restrict__ gstart,
                                                   float* __restrict__ d_out) {
    int c = threadIdx.x;                 // channel 0..127
    int node0 = blockIdx.x * POOL_CHUNK;
    int nodeEnd = node0 + POOL_CHUNK; if (nodeEnd > N_NODES) nodeEnd = N_NODES;
    if (node0 >= N_NODES) return;
    int gprev = batch[node0];
    float acc = 0.f;
    for (int node = node0; node < nodeEnd; ++node) {
        int g = batch[node];
        if (g != gprev) {
            if (gprev >= 0 && gprev < N_GRAPHS) {
                float cnt = (float)(gstart[gprev + 1] - gstart[gprev]);
                if (cnt < 1.f) cnt = 1.f;
                atomicAdd(&d_out[gprev * 128 + c], acc / cnt);
            }
            acc = 0.f;
            gprev = g;
        }
        acc += out2[(size_t)node * 128 + c];
    }
    if (gprev >= 0 && gprev < N_GRAPHS) {
        float cnt = (float)(gstart[gprev + 1] - gstart[gprev]);
        if (cnt < 1.f) cnt = 1.f;
        atomicAdd(&d_out[gprev * 128 + c], acc / cnt);
    }
}

// ---------------------------------------------------------------------------
extern "C" void kernel_launch(void* const* d_in, const int* in_sizes, int n_in,
                              void* d_out_v, int out_size, void* d_ws, size_t ws_size,
                              hipStream_t stream) {
    const float* x      = (const float*)d_in[0];
    const float* W1     = (const float*)d_in[1];
    const float* att_s1 = (const float*)d_in[2];
    const float* att_d1 = (const float*)d_in[3];
    const float* bias1  = (const float*)d_in[4];
    const float* W2     = (const float*)d_in[5];
    const float* att_s2 = (const float*)d_in[6];
    const float* att_d2 = (const float*)d_in[7];
    const float* bias2  = (const float*)d_in[8];
    const int*   ei     = (const int*)d_in[9];
    const int*   batch  = (const int*)d_in[10];
    float* d_out = (float*)d_out_v;

    // Workspace layout (float units):
    //  [0, 6.4M)        xh fp16 [N,256]      ... later reused as h2h fp16 [N,128]
    //  [6.4M, 12.8M)    h1h fp16 [N,256]     ... later reused as out2 fp32 [N,128]
    //  [12.8M, 19.2M)   out1h fp16 [N,256]
    //  [19.2M, ...)     attention scalars + CSR/sort buffers + W transposes
    float* ws = (float*)d_ws;
    _Float16* xh    = (_Float16*)ws;
    _Float16* h1h   = (_Float16*)(ws + 6400000);
    _Float16* out1h = (_Float16*)(ws + 12800000);
    _Float16* h2h   = (_Float16*)ws;            // xh dead after GEMM1
    float*    out2  = ws + 6400000;             // h1h dead after edge1
    float* a_src1 = ws + 19200000;              // N*4
    float* a_dst1 = a_src1 + 200000;            // N*4
    float* a_src2 = a_dst1 + 200000;            // N
    float* a_dst2 = a_src2 + 50000;             // N
    int* row_ptr  = (int*)(a_dst2 + 50000);     // N+1 (padded to 50016)
    int* ssrc     = row_ptr + 50016;            // E_TOT
    int* ebuf     = ssrc + 850000;              // NBUCKET * EBUF_CAP fixed regions
    int* gcur     = ebuf + (NBUCKET * EBUF_CAP);// 512 (bucket cursors/counts)
    int* gstart   = gcur + 512;                 // N_GRAPHS+1 (pad 128)
    _Float16* W1t = (_Float16*)(gstart + 128);  // 65536 halfs [256][256]
    _Float16* W2t = W1t + 65536;                // 32768 halfs [128][256]

    // 0. gcur must be zero before the bin blocks inside prep run
    hipMemsetAsync(gcur, 0, 512 * sizeof(int), stream);

    // 1. Fused prep: bin + cast x + transpose W1/W2 + graph bounds + d_out=0
    prep_kernel<<<PREP_TOTAL, 256, 0, stream>>>(x, xh, W1, W1t, W2, W2t,
                                                ei, gcur, ebuf,
                                                batch, gstart, d_out);

    // 2. FUSED: bucket sort (391 blocks) + GEMM1 (782 tiles) in one dispatch
    sort_gemm1_kernel<<<NBUCKET + GEMM1_MB * 2, 256, 0, stream>>>(
        gcur, ebuf, ssrc, row_ptr, xh, W1t, h1h,
        att_s1, att_d1, a_src1, a_dst1);

    // 3. Layer-1 edge aggregation
    edge1_kernel<<<N_NODES / 4, 256, 0, stream>>>(row_ptr, ssrc, (const __half*)h1h,
                                                  a_src1, a_dst1, bias1, (__half*)out1h);

    // 4. GEMM2: h2 = out1 @ W2 (att2 folded via LDS combine)
    gemm_mfma_kernel<<<(N_NODES + 127) / 128, 256, 0, stream>>>(
        out1h, W2t, h2h, att_s2, att_d2, a_src2, a_dst2, N_NODES, OUT_C);

    // 5. Layer-2 edge aggregation
    edge2_kernel<<<N_NODES / 8, 256, 0, stream>>>(row_ptr, ssrc, (const __half*)h2h,
                                                  a_src2, a_dst2, bias2, out2);

    // 6. Pooling (mean division folded into the atomic flush)
    pool_kernel<<<(N_NODES + POOL_CHUNK - 1) / POOL_CHUNK, 128, 0, stream>>>(out2, batch, gstart, d_out);
}

// Round 9
// 289.849 us; speedup vs baseline: 1.1964x; 1.0121x over previous
//
#include <hip/hip_runtime.h>
#include <hip/hip_bf16.h>
#include <hip/hip_fp16.h>

// Problem constants (fixed by the reference setup)
#define N_NODES 50000
#define N_EDGES 800000
#define E_TOT   (N_EDGES + N_NODES)   // 850000 (self-loops appended)
#define IN_C    256
#define H1C     256                    // HEADS * HID_C = 4*64
#define HEADS   4
#define HID_C   64
#define OUT_C   128
#define N_GRAPHS 100
#define NEG_SLOPE 0.2f
#define EPS_F 1e-16f

// Bucket sort: order within a bucket is irrelevant (bucket_sort rebuilds
// per-node order), so bin reserves space via global atomics into FIXED
// per-bucket ebuf regions — no cross-block prefix needed.
#define NBUCKET 391                   // ceil(50000 / 128), bucket = dst >> 7
#define EDGES_PER_SB 8192             // 104*8192 = 851968 >= E_TOT
#define EBUF_CAP 4096                 // per-bucket region (span avg ~2176, max<3072)
#define STAGE_CAP 4096                // LDS staging = EBUF_CAP (no fallback)
#define GEMM1_MB 391                  // gemm1 M-tiles (full N=256 per block now)

// prep_kernel block partition (bin FIRST: heaviest blocks dispatch earliest).
// The x fp32->fp16 cast phase is GONE: gemm1 reads x directly and converts
// in-register during A-staging (removes 77MB of HBM traffic + serialization).
#define PREP_BIN_BLOCKS    104
#define PREP_W1_BLOCKS     256        // 65536 / 256
#define PREP_W2_BLOCKS     128        // 32768 / 256
#define PREP_BOUNDS_BLOCKS 196
#define PREP_DOUT_BLOCKS   50         // 12800 floats / 256
#define PREP_TOTAL (PREP_BIN_BLOCKS + PREP_W1_BLOCKS + PREP_W2_BLOCKS + PREP_BOUNDS_BLOCKS + PREP_DOUT_BLOCKS)

typedef _Float16 half8_t __attribute__((ext_vector_type(8)));
typedef float f32x4 __attribute__((ext_vector_type(4)));

// global_load_lds helper: width=16 (global_load_lds_dwordx4), LDS dest is
// wave-uniform base + lane*16 (m104); global src address is PER-LANE, which
// is how the chunk swizzle is applied (pre-swizzled source, m173 pattern).
__device__ __forceinline__ void gll16(const void* g, void* l) {
    __builtin_amdgcn_global_load_lds(
        (const __attribute__((address_space(1))) void*)g,
        (__attribute__((address_space(3))) void*)l, 16, 0, 0);
}

// ---------------------------------------------------------------------------
// Fused prep: bucket_bin + W1t + W2t + bounds + d_out=0.
// bin requires gcur pre-zeroed (hipMemsetAsync in stream before this).
// ---------------------------------------------------------------------------
__global__ __launch_bounds__(256) void prep_kernel(const float* __restrict__ W1,
                                                   _Float16* __restrict__ W1t,
                                                   const float* __restrict__ W2,
                                                   _Float16* __restrict__ W2t,
                                                   const int* __restrict__ ei,
                                                   int* __restrict__ gcur,
                                                   int* __restrict__ ebuf,
                                                   const int* __restrict__ batch,
                                                   int* __restrict__ gstart,
                                                   float* __restrict__ d_out) {
    __shared__ int bh[NBUCKET];
    __shared__ int bofs[NBUCKET];
    int b = blockIdx.x;
    int tid = threadIdx.x;
    if (b < PREP_BIN_BLOCKS) {
        // ---- bucket_bin: LDS histogram -> one global atomicAdd per
        // (block,bucket) reserving a run in the bucket's fixed region ----
        for (int t = tid; t < NBUCKET; t += 256) bh[t] = 0;
        __syncthreads();
        int base = b * EDGES_PER_SB;
#pragma unroll 4
        for (int k = 0; k < EDGES_PER_SB / 256; ++k) {
            int idx = base + k * 256 + tid;
            int d = -1;
            if (idx < N_EDGES) d = ei[N_EDGES + idx];
            else if (idx < E_TOT) d = idx - N_EDGES;
            if (d >= 0 && d < N_NODES) atomicAdd(&bh[d >> 7], 1);
        }
        __syncthreads();
        for (int t = tid; t < NBUCKET; t += 256) {
            int c = bh[t];
            bofs[t] = (c > 0) ? atomicAdd(&gcur[t], c) : 0;
            bh[t] = 0;                 // reuse as local cursor
        }
        __syncthreads();
#pragma unroll 4
        for (int k = 0; k < EDGES_PER_SB / 256; ++k) {
            int idx = base + k * 256 + tid;
            int s = 0, d = -1;
            if (idx < N_EDGES) { s = ei[idx]; d = ei[N_EDGES + idx]; }
            else if (idx < E_TOT) { s = idx - N_EDGES; d = s; }
            if (d >= 0 && d < N_NODES) {
                int t = d >> 7;
                int p = bofs[t] + atomicAdd(&bh[t], 1);
                if (p < EBUF_CAP)      // defensive; never fires for this input
                    ebuf[t * EBUF_CAP + p] = (s & 0xFFFF) | ((d & 127) << 16);
            }
        }
        return;
    }
    b -= PREP_BIN_BLOCKS;
    if (b < PREP_W1_BLOCKS) {
        int idx = b * 256 + tid;                      // < 65536 exactly
        int n = idx >> 8, k = idx & 255;
        W1t[idx] = (_Float16)W1[k * 256 + n];
        return;
    }
    b -= PREP_W1_BLOCKS;
    if (b < PREP_W2_BLOCKS) {
        int idx = b * 256 + tid;                      // < 32768 exactly
        int n = idx >> 8, k = idx & 255;
        W2t[idx] = (_Float16)W2[k * 128 + n];
        return;
    }
    b -= PREP_W2_BLOCKS;
    if (b < PREP_BOUNDS_BLOCKS) {   // bounds: batch sorted; each gstart entry written exactly once
        int idx = b * 256 + tid;
        if (idx >= N_NODES) return;
        int g = batch[idx];
        if (g < 0) g = 0; if (g >= N_GRAPHS) g = N_GRAPHS - 1;
        if (idx == 0) {
            for (int j = 0; j <= g; ++j) gstart[j] = 0;
        } else {
            int gp = batch[idx - 1];
            if (gp < 0) gp = 0; if (gp >= N_GRAPHS) gp = N_GRAPHS - 1;
            for (int j = gp + 1; j <= g; ++j) gstart[j] = idx;
        }
        if (idx == N_NODES - 1) {
            for (int j = g + 1; j <= N_GRAPHS; ++j) gstart[j] = N_NODES;
        }
        return;
    }
    b -= PREP_BOUNDS_BLOCKS;
    {   // zero d_out (pool accumulates atomically much later in the stream)
        int idx = b * 256 + tid;
        if (idx < N_GRAPHS * 128) d_out[idx] = 0.f;
    }
}

// ---------------------------------------------------------------------------
// FUSED bucket_sort + GEMM1 — 512 threads / 8 waves per block.
// GEMM1 now reads x fp32 DIRECTLY (cast removed from prep): A-staging is
// reg-staged fp32->fp16 conversion with swizzled LDS dest; B-staging is
// global_load_lds width=16 with pre-swizzled source (rule #21). Each block
// computes a full 128x256 tile (8 waves = 2 wm x 4 wn of 64x64), so x is
// read exactly ONCE from HBM. Mode-1 epilogue: wave w owns head hd = w&3.
// LDS union: sort 17408B, gemm As 8192 + Bs 16384 = 24576B.
// ---------------------------------------------------------------------------
__global__ __launch_bounds__(512) void sort_gemm1_kernel(const int* __restrict__ gcur,
                                                         const int* __restrict__ ebuf,
                                                         int* __restrict__ ssrc,
                                                         int* __restrict__ row_ptr,
                                                         const float* __restrict__ X,
                                                         const _Float16* __restrict__ Bt,
                                                         _Float16* __restrict__ C,
                                                         const float* __restrict__ attS,
                                                         const float* __restrict__ attD,
                                                         float* __restrict__ a_src_o,
                                                         float* __restrict__ a_dst_o) {
    __shared__ __align__(16) char smem[24576];
    __shared__ int s_off;
    const int tid = threadIdx.x;

    if (blockIdx.x < NBUCKET) {
        // ---------------- sort path (strides = 512) ----------------
        int* cnt   = reinterpret_cast<int*>(smem);          // 128
        int* sc    = cnt + 128;                             // 128
        int* stage = sc + 128;                              // STAGE_CAP
        int j = blockIdx.x;
        if (tid < 64) {                 // lo = sum of bucket counts < j
            int acc = 0;
            for (int i = tid; i < j; i += 64) {
                int c = gcur[i];
                acc += (c < EBUF_CAP) ? c : EBUF_CAP;
            }
#pragma unroll
            for (int off = 32; off > 0; off >>= 1) acc += __shfl_down(acc, off);
            if (tid == 0) s_off = acc;
        }
        if (tid < 128) cnt[tid] = 0;
        __syncthreads();
        int span = gcur[j]; if (span > EBUF_CAP) span = EBUF_CAP;
        int lo = s_off;
        const int* eb = ebuf + j * EBUF_CAP;
        for (int t = tid; t < span; t += 512)
            atomicAdd(&cnt[(eb[t] >> 16) & 127], 1);
        __syncthreads();
        if (tid < 128) sc[tid] = cnt[tid];
        __syncthreads();
#pragma unroll
        for (int off = 1; off < 128; off <<= 1) {
            int u = (tid >= off && tid < 128) ? sc[tid - off] : 0;
            __syncthreads();
            if (tid < 128) sc[tid] += u;
            __syncthreads();
        }
        int jn0 = j << 7;
        int nNodes = N_NODES - jn0; if (nNodes > 128) nNodes = 128;
        if (tid < 128) {
            int excl = sc[tid] - cnt[tid];
            if (tid < nNodes) row_ptr[jn0 + tid] = lo + excl;   // CSR byproduct
            cnt[tid] = excl;                                     // reuse as cursor
        }
        if (j == NBUCKET - 1 && tid == 0) row_ptr[N_NODES] = lo + span;
        __syncthreads();
        for (int t = tid; t < span; t += 512) {
            int v = eb[t];
            int p = atomicAdd(&cnt[(v >> 16) & 127], 1);
            stage[p] = v & 0xFFFF;
        }
        __syncthreads();
        for (int t = tid; t < span; t += 512) ssrc[lo + t] = stage[t];
        return;
    }

    // ---------------- gemm1 path: 128x256 tile, 8 waves ----------------
    _Float16* As = reinterpret_cast<_Float16*>(smem);          // [128][32]
    _Float16* Bs = reinterpret_cast<_Float16*>(smem + 8192);   // [256][32]
    const int tileM = (blockIdx.x - NBUCKET) * 128;
    const int w = tid >> 6, lane = tid & 63;
    const int wm = (w >> 2) * 64, wn = (w & 3) * 64;
    const int quad = lane >> 4, mlane = lane & 15;
    // A reg-staging: thread covers row arow, 16B chunk apos; swizzled dest
    const int arow = tid >> 2;             // 0..127
    const int apos = tid & 3;
    const int ac   = apos ^ ((arow >> 1) & 3);
    int axr = tileM + arow; if (axr > N_NODES - 1) axr = N_NODES - 1;  // clamp: no OOB read of x
    const float* gx = X + (size_t)axr * 256 + apos * 8;
    // B glld: wave w stages rows [w*32, w*32+32) via 2 glls; swizzled source
    const int lrow = lane >> 2, pos = lane & 3;
    const int brow0 = w * 32 + lrow, brow1 = brow0 + 16;
    const int bc0 = pos ^ ((brow0 >> 1) & 3), bc1 = pos ^ ((brow1 >> 1) & 3);
    const _Float16* gB0 = Bt + (size_t)brow0 * 256 + bc0 * 8;
    const _Float16* gB1 = Bt + (size_t)brow1 * 256 + bc1 * 8;
    _Float16* lB0 = Bs + w * 1024;         // wave-uniform: 16 rows x 64B
    _Float16* lB1 = Bs + w * 1024 + 512;

    f32x4 zero = {0.f, 0.f, 0.f, 0.f};
    f32x4 acc[4][4];
#pragma unroll
    for (int i = 0; i < 4; ++i)
#pragma unroll
        for (int j = 0; j < 4; ++j) acc[i][j] = zero;

    for (int k0 = 0; k0 < 256; k0 += 32) {
        __syncthreads();                   // prior ds_reads done before overwrite
        gll16(gB0 + k0, lB0);
        gll16(gB1 + k0, lB1);
        float4 va = *reinterpret_cast<const float4*>(gx + k0);
        float4 vb = *reinterpret_cast<const float4*>(gx + k0 + 4);
        union { _Float16 h[8]; uint4 u; } pk;
        pk.h[0] = (_Float16)va.x; pk.h[1] = (_Float16)va.y;
        pk.h[2] = (_Float16)va.z; pk.h[3] = (_Float16)va.w;
        pk.h[4] = (_Float16)vb.x; pk.h[5] = (_Float16)vb.y;
        pk.h[6] = (_Float16)vb.z; pk.h[7] = (_Float16)vb.w;
        *reinterpret_cast<uint4*>(As + arow * 32 + ac * 8) = pk.u;
        __syncthreads();                   // vmcnt(0)+lgkmcnt(0) drain + barrier
        half8_t af[4], bf[4];
#pragma unroll
        for (int mt = 0; mt < 4; ++mt) {
            int ra = wm + mt * 16 + mlane;
            af[mt] = *reinterpret_cast<const half8_t*>(As + ra * 32 + ((quad ^ ((ra >> 1) & 3)) << 3));
        }
#pragma unroll
        for (int nt = 0; nt < 4; ++nt) {
            int rb = wn + nt * 16 + mlane;
            bf[nt] = *reinterpret_cast<const half8_t*>(Bs + rb * 32 + ((quad ^ ((rb >> 1) & 3)) << 3));
        }
#pragma unroll
        for (int mt = 0; mt < 4; ++mt)
#pragma unroll
            for (int nt = 0; nt < 4; ++nt)
                acc[mt][nt] = __builtin_amdgcn_mfma_f32_16x16x32_f16(af[mt], bf[nt], acc[mt][nt], 0, 0, 0);
    }
#pragma unroll
    for (int mt = 0; mt < 4; ++mt) {
#pragma unroll
        for (int i = 0; i < 4; ++i) {
            int row = tileM + wm + mt * 16 + quad * 4 + i;
            if (row < N_NODES) {
                _Float16* cp = C + (size_t)row * 256 + wn;
#pragma unroll
                for (int nt = 0; nt < 4; ++nt)
                    cp[nt * 16 + mlane] = (_Float16)acc[mt][nt][i];
            }
        }
    }
    {   // mode-1 epilogue: wave w owns head hd = w&3 entirely (wn = hd*64)
        int hd = w & 3;
        float as[4], ad[4];
#pragma unroll
        for (int nt = 0; nt < 4; ++nt) {
            as[nt] = attS[hd * 64 + nt * 16 + mlane];
            ad[nt] = attD[hd * 64 + nt * 16 + mlane];
        }
#pragma unroll
        for (int mt = 0; mt < 4; ++mt) {
#pragma unroll
            for (int i = 0; i < 4; ++i) {
                float ps = acc[mt][0][i] * as[0] + acc[mt][1][i] * as[1]
                         + acc[mt][2][i] * as[2] + acc[mt][3][i] * as[3];
                float pd = acc[mt][0][i] * ad[0] + acc[mt][1][i] * ad[1]
                         + acc[mt][2][i] * ad[2] + acc[mt][3][i] * ad[3];
#pragma unroll
                for (int off = 1; off < 16; off <<= 1) {
                    ps += __shfl_xor(ps, off);
                    pd += __shfl_xor(pd, off);
                }
                if (mlane == 0) {
                    int row = tileM + wm + mt * 16 + quad * 4 + i;
                    if (row < N_NODES) {
                        a_src_o[row * 4 + hd] = ps;
                        a_dst_o[row * 4 + hd] = pd;
                    }
                }
            }
        }
    }
}

// ---------------------------------------------------------------------------
// GEMM2 (standalone, mode-2 epilogue) — r8 glld+swizzle staging, unchanged.
// ---------------------------------------------------------------------------
__global__ __launch_bounds__(256) void gemm_mfma_kernel(const _Float16* __restrict__ A,
                                                        const _Float16* __restrict__ Bt,
                                                        _Float16* __restrict__ C,
                                                        const float* __restrict__ attS,
                                                        const float* __restrict__ attD,
                                                        float* __restrict__ a_src_o,
                                                        float* __restrict__ a_dst_o,
                                                        int M, int N) {
    __shared__ __align__(16) _Float16 As[4096];   // [128][32] halfs
    __shared__ __align__(16) _Float16 Bs[4096];
    __shared__ float lds_ps[128];
    __shared__ float lds_pd[128];
    const int tid = threadIdx.x;
    const int tileM = blockIdx.x * 128;
    const int tileN = 0;
    const int w = tid >> 6, lane = tid & 63;
    const int wm = (w >> 1) * 64, wn = (w & 1) * 64;
    const int quad = lane >> 4, mlane = lane & 15;
    const int lrow = lane >> 2;
    const int pos  = lane & 3;
    const int ra0  = w * 16 + lrow;
    const int ra1  = ra0 + 64;
    const int ca0  = pos ^ ((ra0 >> 1) & 3);
    const int ca1  = pos ^ ((ra1 >> 1) & 3);

    f32x4 zero = {0.f, 0.f, 0.f, 0.f};
    f32x4 acc[4][4];
#pragma unroll
    for (int i = 0; i < 4; ++i)
#pragma unroll
        for (int j = 0; j < 4; ++j) acc[i][j] = zero;

    const _Float16* gA0 = A + (size_t)(tileM + ra0) * 256 + ca0 * 8;
    const _Float16* gA1 = A + (size_t)(tileM + ra1) * 256 + ca1 * 8;
    const _Float16* gB0 = Bt + (size_t)(tileN + ra0) * 256 + ca0 * 8;
    const _Float16* gB1 = Bt + (size_t)(tileN + ra1) * 256 + ca1 * 8;
    _Float16* lA0 = As + w * 512;
    _Float16* lA1 = As + 2048 + w * 512;
    _Float16* lB0 = Bs + w * 512;
    _Float16* lB1 = Bs + 2048 + w * 512;

    for (int k0 = 0; k0 < 256; k0 += 32) {
        __syncthreads();
        gll16(gA0 + k0, lA0);
        gll16(gA1 + k0, lA1);
        gll16(gB0 + k0, lB0);
        gll16(gB1 + k0, lB1);
        __syncthreads();
        half8_t af[4], bf[4];
#pragma unroll
        for (int mt = 0; mt < 4; ++mt) {
            int ra = wm + mt * 16 + mlane;
            af[mt] = *reinterpret_cast<const half8_t*>(As + ra * 32 + ((quad ^ ((ra >> 1) & 3)) << 3));
        }
#pragma unroll
        for (int nt = 0; nt < 4; ++nt) {
            int rb = wn + nt * 16 + mlane;
            bf[nt] = *reinterpret_cast<const half8_t*>(Bs + rb * 32 + ((quad ^ ((rb >> 1) & 3)) << 3));
        }
#pragma unroll
        for (int mt = 0; mt < 4; ++mt)
#pragma unroll
            for (int nt = 0; nt < 4; ++nt)
                acc[mt][nt] = __builtin_amdgcn_mfma_f32_16x16x32_f16(af[mt], bf[nt], acc[mt][nt], 0, 0, 0);
    }
#pragma unroll
    for (int mt = 0; mt < 4; ++mt) {
#pragma unroll
        for (int i = 0; i < 4; ++i) {
            int row = tileM + wm + mt * 16 + quad * 4 + i;
            if (row < M) {
                _Float16* cp = C + (size_t)row * N + tileN + wn;
#pragma unroll
                for (int nt = 0; nt < 4; ++nt)
                    cp[nt * 16 + mlane] = (_Float16)acc[mt][nt][i];
            }
        }
    }
    {   // mode-2 epilogue: single head, two waves combine via LDS
        float as[4], ad[4];
#pragma unroll
        for (int nt = 0; nt < 4; ++nt) {
            as[nt] = attS[wn + nt * 16 + mlane];
            ad[nt] = attD[wn + nt * 16 + mlane];
        }
        float psa[4][4], pda[4][4];
#pragma unroll
        for (int mt = 0; mt < 4; ++mt) {
#pragma unroll
            for (int i = 0; i < 4; ++i) {
                float ps = acc[mt][0][i] * as[0] + acc[mt][1][i] * as[1]
                         + acc[mt][2][i] * as[2] + acc[mt][3][i] * as[3];
                float pd = acc[mt][0][i] * ad[0] + acc[mt][1][i] * ad[1]
                         + acc[mt][2][i] * ad[2] + acc[mt][3][i] * ad[3];
#pragma unroll
                for (int off = 1; off < 16; off <<= 1) {
                    ps += __shfl_xor(ps, off);
                    pd += __shfl_xor(pd, off);
                }
                psa[mt][i] = ps; pda[mt][i] = pd;
            }
        }
        __syncthreads();
        if (wn == 0 && mlane == 0) {
#pragma unroll
            for (int mt = 0; mt < 4; ++mt)
#pragma unroll
                for (int i = 0; i < 4; ++i) {
                    int lr = wm + mt * 16 + quad * 4 + i;
                    lds_ps[lr] = psa[mt][i];
                    lds_pd[lr] = pda[mt][i];
                }
        }
        __syncthreads();
        if (wn == 64 && mlane == 0) {
#pragma unroll
            for (int mt = 0; mt < 4; ++mt)
#pragma unroll
                for (int i = 0; i < 4; ++i) {
                    int lr = wm + mt * 16 + quad * 4 + i;
                    int row = tileM + lr;
                    if (row < M) {
                        a_src_o[row] = psa[mt][i] + lds_ps[lr];
                        a_dst_o[row] = pda[mt][i] + lds_pd[lr];
                    }
                }
        }
    }
}

__device__ __forceinline__ float lrelu(float x) { return x > 0.f ? x : NEG_SLOPE * x; }

// ---------------------------------------------------------------------------
// Edge aggregation, layer 1 — round-2 form, the verified 65us optimum
// (4 structural variants all land 65±1us: platform random-gather ceiling).
// ---------------------------------------------------------------------------
__global__ __launch_bounds__(256) void edge1_kernel(const int* __restrict__ row_ptr,
                                                    const int* __restrict__ ssrc,
                                                    const __half* __restrict__ h1h,
                                                    const float* __restrict__ a_src,
                                                    const float* __restrict__ a_dst,
                                                    const float* __restrict__ bias,
                                                    __half* __restrict__ out) {
    int node = blockIdx.x * 4 + (threadIdx.x >> 6);
    int lane = threadIdx.x & 63;
    int hf   = lane >> 5;              // 0: even edges, 1: odd edges
    int cl   = lane & 31;              // channel-lane: ch [cl*8, cl*8+8)
    int hd   = cl >> 3;                // head = ch/64
    int start = row_ptr[node], end = row_ptr[node + 1];
    int em1 = end - 1;                 // >= start (self-loop guarantees deg>=1)
    float adh = a_dst[node * 4 + hd];

    const uint4* h1v = reinterpret_cast<const uint4*>(h1h);   // 8 halfs/uint4; 32 per row
    float4 aA0 = make_float4(0.f,0.f,0.f,0.f), aA1 = make_float4(0.f,0.f,0.f,0.f);
    float4 aB0 = make_float4(0.f,0.f,0.f,0.f), aB1 = make_float4(0.f,0.f,0.f,0.f);
    float s = 0.f;
    for (int e = start; e < end; e += 4) {
        int e0 = e + hf;
        int e1 = e + 2 + hf;
        int i0 = ssrc[e0 <= em1 ? e0 : em1];
        int i1 = ssrc[e1 <= em1 ? e1 : em1];
        float r0 = a_src[i0 * 4 + hd];
        float r1 = a_src[i1 * 4 + hd];
        uint4 q0 = h1v[(size_t)i0 * 32 + cl];
        uint4 q1 = h1v[(size_t)i1 * 32 + cl];
        float w0 = (e0 < end) ? __expf(lrelu(r0 + adh)) : 0.f;
        float w1 = (e1 < end) ? __expf(lrelu(r1 + adh)) : 0.f;
        s += w0 + w1;
        float2 f;
        f = __half22float2(*reinterpret_cast<const __half2*>(&q0.x)); aA0.x += w0*f.x; aA0.y += w0*f.y;
        f = __half22float2(*reinterpret_cast<const __half2*>(&q0.y)); aA0.z += w0*f.x; aA0.w += w0*f.y;
        f = __half22float2(*reinterpret_cast<const __half2*>(&q0.z)); aA1.x += w0*f.x; aA1.y += w0*f.y;
        f = __half22float2(*reinterpret_cast<const __half2*>(&q0.w)); aA1.z += w0*f.x; aA1.w += w0*f.y;
        f = __half22float2(*reinterpret_cast<const __half2*>(&q1.x)); aB0.x += w1*f.x; aB0.y += w1*f.y;
        f = __half22float2(*reinterpret_cast<const __half2*>(&q1.y)); aB0.z += w1*f.x; aB0.w += w1*f.y;
        f = __half22float2(*reinterpret_cast<const __half2*>(&q1.z)); aB1.x += w1*f.x; aB1.y += w1*f.y;
        f = __half22float2(*reinterpret_cast<const __half2*>(&q1.w)); aB1.z += w1*f.x; aB1.w += w1*f.y;
    }
    float4 c0, c1;
    c0.x = aA0.x + aB0.x; c0.y = aA0.y + aB0.y; c0.z = aA0.z + aB0.z; c0.w = aA0.w + aB0.w;
    c1.x = aA1.x + aB1.x; c1.y = aA1.y + aB1.y; c1.z = aA1.z + aB1.z; c1.w = aA1.w + aB1.w;
    // fold even/odd halves (lane L and L+32 cover the same channels & head)
    c0.x += __shfl_xor(c0.x, 32); c0.y += __shfl_xor(c0.y, 32);
    c0.z += __shfl_xor(c0.z, 32); c0.w += __shfl_xor(c0.w, 32);
    c1.x += __shfl_xor(c1.x, 32); c1.y += __shfl_xor(c1.y, 32);
    c1.z += __shfl_xor(c1.z, 32); c1.w += __shfl_xor(c1.w, 32);
    s += __shfl_xor(s, 32);
    float inv = 1.0f / (s + EPS_F);
    if (lane < 32) {
        const float4* b4 = reinterpret_cast<const float4*>(bias);
        float4 b0 = b4[cl * 2], b1 = b4[cl * 2 + 1];
        union { _Float16 h[8]; uint4 u; } st;
        st.h[0] = (_Float16)fmaxf(c0.x * inv + b0.x, 0.f);
        st.h[1] = (_Float16)fmaxf(c0.y * inv + b0.y, 0.f);
        st.h[2] = (_Float16)fmaxf(c0.z * inv + b0.z, 0.f);
        st.h[3] = (_Float16)fmaxf(c0.w * inv + b0.w, 0.f);
        st.h[4] = (_Float16)fmaxf(c1.x * inv + b1.x, 0.f);
        st.h[5] = (_Float16)fmaxf(c1.y * inv + b1.y, 0.f);
        st.h[6] = (_Float16)fmaxf(c1.z * inv + b1.z, 0.f);
        st.h[7] = (_Float16)fmaxf(c1.w * inv + b1.w, 0.f);
        reinterpret_cast<uint4*>(out)[(size_t)node * 32 + cl] = st.u;
    }
}

// ---------------------------------------------------------------------------
// Edge aggregation, layer 2 — round-2 form: 2 nodes per wave, 16-lane groups
// cover the 128-ch row via one uint4 gather, two edges per iteration.
// ---------------------------------------------------------------------------
__global__ __launch_bounds__(256) void edge2_kernel(const int* __restrict__ row_ptr,
                                                    const int* __restrict__ ssrc,
                                                    const __half* __restrict__ h2h,
                                                    const float* __restrict__ a_src,
                                                    const float* __restrict__ a_dst,
                                                    const float* __restrict__ bias,
                                                    float* __restrict__ out) {
    int lane = threadIdx.x & 63;
    int node = blockIdx.x * 8 + ((threadIdx.x >> 6) << 1) + (lane >> 5);
    int sub  = (lane >> 4) & 1;        // edge sub-slot within the 32-lane node group
    int cl   = lane & 15;              // channel-lane: ch [cl*8, cl*8+8)
    int start = row_ptr[node], end = row_ptr[node + 1];
    int em1 = end - 1;
    float ad = a_dst[node];

    const uint4* h2v = reinterpret_cast<const uint4*>(h2h);   // 8 halfs/uint4; 16 per row
    float4 aA0 = make_float4(0.f,0.f,0.f,0.f), aA1 = make_float4(0.f,0.f,0.f,0.f);
    float4 aB0 = make_float4(0.f,0.f,0.f,0.f), aB1 = make_float4(0.f,0.f,0.f,0.f);
    float s = 0.f;
    for (int e = start; e < end; e += 4) {
        int e0 = e + sub;
        int e1 = e + 2 + sub;
        int i0 = ssrc[e0 <= em1 ? e0 : em1];
        int i1 = ssrc[e1 <= em1 ? e1 : em1];
        float r0 = a_src[i0];
        float r1 = a_src[i1];
        uint4 q0 = h2v[(size_t)i0 * 16 + cl];
        uint4 q1 = h2v[(size_t)i1 * 16 + cl];
        float w0 = (e0 < end) ? __expf(lrelu(r0 + ad)) : 0.f;
        float w1 = (e1 < end) ? __expf(lrelu(r1 + ad)) : 0.f;
        s += w0 + w1;
        float2 f;
        f = __half22float2(*reinterpret_cast<const __half2*>(&q0.x)); aA0.x += w0*f.x; aA0.y += w0*f.y;
        f = __half22float2(*reinterpret_cast<const __half2*>(&q0.y)); aA0.z += w0*f.x; aA0.w += w0*f.y;
        f = __half22float2(*reinterpret_cast<const __half2*>(&q0.z)); aA1.x += w0*f.x; aA1.y += w0*f.y;
        f = __half22float2(*reinterpret_cast<const __half2*>(&q0.w)); aA1.z += w0*f.x; aA1.w += w0*f.y;
        f = __half22float2(*reinterpret_cast<const __half2*>(&q1.x)); aB0.x += w1*f.x; aB0.y += w1*f.y;
        f = __half22float2(*reinterpret_cast<const __half2*>(&q1.y)); aB0.z += w1*f.x; aB0.w += w1*f.y;
        f = __half22float2(*reinterpret_cast<const __half2*>(&q1.z)); aB1.x += w1*f.x; aB1.y += w1*f.y;
        f = __half22float2(*reinterpret_cast<const __half2*>(&q1.w)); aB1.z += w1*f.x; aB1.w += w1*f.y;
    }
    float4 c0, c1;
    c0.x = aA0.x + aB0.x; c0.y = aA0.y + aB0.y; c0.z = aA0.z + aB0.z; c0.w = aA0.w + aB0.w;
    c1.x = aA1.x + aB1.x; c1.y = aA1.y + aB1.y; c1.z = aA1.z + aB1.z; c1.w = aA1.w + aB1.w;
    // fold the two 16-lane edge groups within this node's 32-lane half
    c0.x += __shfl_xor(c0.x, 16); c0.y += __shfl_xor(c0.y, 16);
    c0.z += __shfl_xor(c0.z, 16); c0.w += __shfl_xor(c0.w, 16);
    c1.x += __shfl_xor(c1.x, 16); c1.y += __shfl_xor(c1.y, 16);
    c1.z += __shfl_xor(c1.z, 16); c1.w += __shfl_xor(c1.w, 16);
    s += __shfl_xor(s, 16);
    float inv = 1.0f / (s + EPS_F);
    if (sub == 0) {                     // 16 lanes per node write the 128-ch row
        const float4* b4 = reinterpret_cast<const float4*>(bias);
        float4 b0 = b4[cl * 2], b1 = b4[cl * 2 + 1];
        float4 o0, o1;
        o0.x = fmaxf(c0.x * inv + b0.x, 0.f);
        o0.y = fmaxf(c0.y * inv + b0.y, 0.f);
        o0.z = fmaxf(c0.z * inv + b0.z, 0.f);
        o0.w = fmaxf(c0.w * inv + b0.w, 0.f);
        o1.x = fmaxf(c1.x * inv + b1.x, 0.f);
        o1.y = fmaxf(c1.y * inv + b1.y, 0.f);
        o1.z = fmaxf(c1.z * inv + b1.z, 0.f);
        o1.w = fmaxf(c1.w * inv + b1.w, 0.f);
        float4* o4 = reinterpret_cast<float4*>(out) + (size_t)node * 32 + cl * 2;
        o4[0] = o0;
        o4[1] = o1;
    }
}

// ---------------------------------------------------------------------------
// Pooling with folded mean division.
// ---------------------------------------------------------------------------
#define POOL_CHUNK 64
__global__ __launch_bounds__(128) void pool_kernel(const float* __restrict__ out2,
                                                   const int* __restrict__ batch,
                                                   const int* __restrict__ gstart,
                                                   float* __restrict__ d_out) {
    int c = threadIdx.x;                 // channel 0..127
    int node0 = blockIdx.x * POOL_CHUNK;
    int nodeEnd = node0 + POOL_CHUNK; if (nodeEnd > N_NODES) nodeEnd = N_NODES;
    if (node0 >= N_NODES) return;
    int gprev = batch[node0];
    float acc = 0.f;
    for (int node = node0; node < nodeEnd; ++node) {
        int g = batch[node];
        if (g != gprev) {
            if (gprev >= 0 && gprev < N_GRAPHS) {
                float cnt = (float)(gstart[gprev + 1] - gstart[gprev]);
                if (cnt < 1.f) cnt = 1.f;
                atomicAdd(&d_out[gprev * 128 + c], acc / cnt);
            }
            acc = 0.f;
            gprev = g;
        }
        acc += out2[(size_t)node * 128 + c];
    }
    if (gprev >= 0 && gprev < N_GRAPHS) {
        float cnt = (float)(gstart[gprev + 1] - gstart[gprev]);
        if (cnt < 1.f) cnt = 1.f;
        atomicAdd(&d_out[gprev * 128 + c], acc / cnt);
    }
}

// ---------------------------------------------------------------------------
extern "C" void kernel_launch(void* const* d_in, const int* in_sizes, int n_in,
                              void* d_out_v, int out_size, void* d_ws, size_t ws_size,
                              hipStream_t stream) {
    const float* x      = (const float*)d_in[0];
    const float* W1     = (const float*)d_in[1];
    const float* att_s1 = (const float*)d_in[2];
    const float* att_d1 = (const float*)d_in[3];
    const float* bias1  = (const float*)d_in[4];
    const float* W2     = (const float*)d_in[5];
    const float* att_s2 = (const float*)d_in[6];
    const float* att_d2 = (const float*)d_in[7];
    const float* bias2  = (const float*)d_in[8];
    const int*   ei     = (const int*)d_in[9];
    const int*   batch  = (const int*)d_in[10];
    float* d_out = (float*)d_out_v;

    // Workspace layout (float units):
    //  [0, 6.4M)        h2h fp16 [N,128] (layer 2)    — xh is GONE (direct-x gemm1)
    //  [6.4M, 12.8M)    h1h fp16 [N,256]  ... later reused as out2 fp32 [N,128]
    //  [12.8M, 19.2M)   out1h fp16 [N,256]
    //  [19.2M, ...)     attention scalars + CSR/sort buffers + W transposes
    float* ws = (float*)d_ws;
    _Float16* h1h   = (_Float16*)(ws + 6400000);
    _Float16* out1h = (_Float16*)(ws + 12800000);
    _Float16* h2h   = (_Float16*)ws;
    float*    out2  = ws + 6400000;             // h1h dead after edge1
    float* a_src1 = ws + 19200000;              // N*4
    float* a_dst1 = a_src1 + 200000;            // N*4
    float* a_src2 = a_dst1 + 200000;            // N
    float* a_dst2 = a_src2 + 50000;             // N
    int* row_ptr  = (int*)(a_dst2 + 50000);     // N+1 (padded to 50016)
    int* ssrc     = row_ptr + 50016;            // E_TOT
    int* ebuf     = ssrc + 850000;              // NBUCKET * EBUF_CAP fixed regions
    int* gcur     = ebuf + (NBUCKET * EBUF_CAP);// 512 (bucket cursors/counts)
    int* gstart   = gcur + 512;                 // N_GRAPHS+1 (pad 128)
    _Float16* W1t = (_Float16*)(gstart + 128);  // 65536 halfs [256][256]
    _Float16* W2t = W1t + 65536;                // 32768 halfs [128][256]

    // 0. gcur must be zero before the bin blocks inside prep run
    hipMemsetAsync(gcur, 0, 512 * sizeof(int), stream);

    // 1. Fused prep: bin + transpose W1/W2 + graph bounds + d_out=0
    prep_kernel<<<PREP_TOTAL, 256, 0, stream>>>(W1, W1t, W2, W2t,
                                                ei, gcur, ebuf,
                                                batch, gstart, d_out);

    // 2. FUSED: bucket sort (391 blocks) + GEMM1 (391 full-N tiles), 512 thr
    sort_gemm1_kernel<<<NBUCKET + GEMM1_MB, 512, 0, stream>>>(
        gcur, ebuf, ssrc, row_ptr, x, W1t, h1h,
        att_s1, att_d1, a_src1, a_dst1);

    // 3. Layer-1 edge aggregation
    edge1_kernel<<<N_NODES / 4, 256, 0, stream>>>(row_ptr, ssrc, (const __half*)h1h,
                                                  a_src1, a_dst1, bias1, (__half*)out1h);

    // 4. GEMM2: h2 = out1 @ W2 (att2 folded via LDS combine)
    gemm_mfma_kernel<<<(N_NODES + 127) / 128, 256, 0, stream>>>(
        out1h, W2t, h2h, att_s2, att_d2, a_src2, a_dst2, N_NODES, OUT_C);

    // 5. Layer-2 edge aggregation
    edge2_kernel<<<N_NODES / 8, 256, 0, stream>>>(row_ptr, ssrc, (const __half*)h2h,
                                                  a_src2, a_dst2, bias2, out2);

    // 6. Pooling (mean division folded into the atomic flush)
    pool_kernel<<<(N_NODES + POOL_CHUNK - 1) / POOL_CHUNK, 128, 0, stream>>>(out2, batch, gstart, d_out);
}

// Round 10
// 289.625 us; speedup vs baseline: 1.1973x; 1.0008x over previous
//
#include <hip/hip_runtime.h>
#include <hip/hip_bf16.h>
#include <hip/hip_fp16.h>

// Problem constants (fixed by the reference setup)
#define N_NODES 50000
#define N_EDGES 800000
#define E_TOT   (N_EDGES + N_NODES)   // 850000 (self-loops appended)
#define IN_C    256
#define H1C     256                    // HEADS * HID_C = 4*64
#define HEADS   4
#define HID_C   64
#define OUT_C   128
#define N_GRAPHS 100
#define NEG_SLOPE 0.2f
#define EPS_F 1e-16f

// Bucket sort: order within a bucket is irrelevant (bucket_sort rebuilds
// per-node order), so bin reserves space via global atomics into FIXED
// per-bucket ebuf regions — no cross-block prefix needed.
#define NBUCKET 391                   // ceil(50000 / 128), bucket = dst >> 7
#define EDGES_PER_SB 8192             // 104*8192 = 851968 >= E_TOT
#define EBUF_CAP 4096                 // per-bucket region (span avg ~2176, max<3072)
#define STAGE_CAP 4096                // LDS staging = EBUF_CAP (no fallback)
#define GEMM1_MB 391                  // gemm1 M-tiles (full N=256 per block)

// prep_kernel block partition (bin FIRST: heaviest blocks dispatch earliest)
#define PREP_BIN_BLOCKS    104
#define PREP_W1_BLOCKS     256        // 65536 / 256
#define PREP_W2_BLOCKS     128        // 32768 / 256
#define PREP_BOUNDS_BLOCKS 196
#define PREP_DOUT_BLOCKS   50         // 12800 floats / 256
#define PREP_TOTAL (PREP_BIN_BLOCKS + PREP_W1_BLOCKS + PREP_W2_BLOCKS + PREP_BOUNDS_BLOCKS + PREP_DOUT_BLOCKS)

typedef _Float16 half8_t __attribute__((ext_vector_type(8)));
typedef float f32x4 __attribute__((ext_vector_type(4)));

// global_load_lds helper: width=16 (global_load_lds_dwordx4), LDS dest is
// wave-uniform base + lane*16 (m104); global src address is PER-LANE, which
// is how the chunk swizzle is applied (pre-swizzled source, m173 pattern).
__device__ __forceinline__ void gll16(const void* g, void* l) {
    __builtin_amdgcn_global_load_lds(
        (const __attribute__((address_space(1))) void*)g,
        (__attribute__((address_space(3))) void*)l, 16, 0, 0);
}

// ---------------------------------------------------------------------------
// Fused prep: bucket_bin + W1t + W2t + bounds + d_out=0.
// bin requires gcur pre-zeroed (hipMemsetAsync in stream before this).
// ---------------------------------------------------------------------------
__global__ __launch_bounds__(256) void prep_kernel(const float* __restrict__ W1,
                                                   _Float16* __restrict__ W1t,
                                                   const float* __restrict__ W2,
                                                   _Float16* __restrict__ W2t,
                                                   const int* __restrict__ ei,
                                                   int* __restrict__ gcur,
                                                   int* __restrict__ ebuf,
                                                   const int* __restrict__ batch,
                                                   int* __restrict__ gstart,
                                                   float* __restrict__ d_out) {
    __shared__ int bh[NBUCKET];
    __shared__ int bofs[NBUCKET];
    int b = blockIdx.x;
    int tid = threadIdx.x;
    if (b < PREP_BIN_BLOCKS) {
        // ---- bucket_bin: LDS histogram -> one global atomicAdd per
        // (block,bucket) reserving a run in the bucket's fixed region ----
        for (int t = tid; t < NBUCKET; t += 256) bh[t] = 0;
        __syncthreads();
        int base = b * EDGES_PER_SB;
#pragma unroll 4
        for (int k = 0; k < EDGES_PER_SB / 256; ++k) {
            int idx = base + k * 256 + tid;
            int d = -1;
            if (idx < N_EDGES) d = ei[N_EDGES + idx];
            else if (idx < E_TOT) d = idx - N_EDGES;
            if (d >= 0 && d < N_NODES) atomicAdd(&bh[d >> 7], 1);
        }
        __syncthreads();
        for (int t = tid; t < NBUCKET; t += 256) {
            int c = bh[t];
            bofs[t] = (c > 0) ? atomicAdd(&gcur[t], c) : 0;
            bh[t] = 0;                 // reuse as local cursor
        }
        __syncthreads();
#pragma unroll 4
        for (int k = 0; k < EDGES_PER_SB / 256; ++k) {
            int idx = base + k * 256 + tid;
            int s = 0, d = -1;
            if (idx < N_EDGES) { s = ei[idx]; d = ei[N_EDGES + idx]; }
            else if (idx < E_TOT) { s = idx - N_EDGES; d = s; }
            if (d >= 0 && d < N_NODES) {
                int t = d >> 7;
                int p = bofs[t] + atomicAdd(&bh[t], 1);
                if (p < EBUF_CAP)      // defensive; never fires for this input
                    ebuf[t * EBUF_CAP + p] = (s & 0xFFFF) | ((d & 127) << 16);
            }
        }
        return;
    }
    b -= PREP_BIN_BLOCKS;
    if (b < PREP_W1_BLOCKS) {
        int idx = b * 256 + tid;                      // < 65536 exactly
        int n = idx >> 8, k = idx & 255;
        W1t[idx] = (_Float16)W1[k * 256 + n];
        return;
    }
    b -= PREP_W1_BLOCKS;
    if (b < PREP_W2_BLOCKS) {
        int idx = b * 256 + tid;                      // < 32768 exactly
        int n = idx >> 8, k = idx & 255;
        W2t[idx] = (_Float16)W2[k * 128 + n];
        return;
    }
    b -= PREP_W2_BLOCKS;
    if (b < PREP_BOUNDS_BLOCKS) {   // bounds: batch sorted; each gstart entry written exactly once
        int idx = b * 256 + tid;
        if (idx >= N_NODES) return;
        int g = batch[idx];
        if (g < 0) g = 0; if (g >= N_GRAPHS) g = N_GRAPHS - 1;
        if (idx == 0) {
            for (int j = 0; j <= g; ++j) gstart[j] = 0;
        } else {
            int gp = batch[idx - 1];
            if (gp < 0) gp = 0; if (gp >= N_GRAPHS) gp = N_GRAPHS - 1;
            for (int j = gp + 1; j <= g; ++j) gstart[j] = idx;
        }
        if (idx == N_NODES - 1) {
            for (int j = g + 1; j <= N_GRAPHS; ++j) gstart[j] = N_NODES;
        }
        return;
    }
    b -= PREP_BOUNDS_BLOCKS;
    {   // zero d_out (pool accumulates atomically much later in the stream)
        int idx = b * 256 + tid;
        if (idx < N_GRAPHS * 128) d_out[idx] = 0.f;
    }
}

// ---------------------------------------------------------------------------
// FUSED bucket_sort + GEMM1 — 512 threads / 8 waves per block (r9 form).
// A-staging reads x fp32 directly, converts in-register, swizzled LDS dest;
// B-staging via glld width=16 with pre-swizzled source (rule #21).
// ---------------------------------------------------------------------------
__global__ __launch_bounds__(512) void sort_gemm1_kernel(const int* __restrict__ gcur,
                                                         const int* __restrict__ ebuf,
                                                         int* __restrict__ ssrc,
                                                         int* __restrict__ row_ptr,
                                                         const float* __restrict__ X,
                                                         const _Float16* __restrict__ Bt,
                                                         _Float16* __restrict__ C,
                                                         const float* __restrict__ attS,
                                                         const float* __restrict__ attD,
                                                         float* __restrict__ a_src_o,
                                                         float* __restrict__ a_dst_o) {
    __shared__ __align__(16) char smem[24576];
    __shared__ int s_off;
    const int tid = threadIdx.x;

    if (blockIdx.x < NBUCKET) {
        // ---------------- sort path (strides = 512) ----------------
        int* cnt   = reinterpret_cast<int*>(smem);          // 128
        int* sc    = cnt + 128;                             // 128
        int* stage = sc + 128;                              // STAGE_CAP
        int j = blockIdx.x;
        if (tid < 64) {                 // lo = sum of bucket counts < j
            int acc = 0;
            for (int i = tid; i < j; i += 64) {
                int c = gcur[i];
                acc += (c < EBUF_CAP) ? c : EBUF_CAP;
            }
#pragma unroll
            for (int off = 32; off > 0; off >>= 1) acc += __shfl_down(acc, off);
            if (tid == 0) s_off = acc;
        }
        if (tid < 128) cnt[tid] = 0;
        __syncthreads();
        int span = gcur[j]; if (span > EBUF_CAP) span = EBUF_CAP;
        int lo = s_off;
        const int* eb = ebuf + j * EBUF_CAP;
        for (int t = tid; t < span; t += 512)
            atomicAdd(&cnt[(eb[t] >> 16) & 127], 1);
        __syncthreads();
        if (tid < 128) sc[tid] = cnt[tid];
        __syncthreads();
#pragma unroll
        for (int off = 1; off < 128; off <<= 1) {
            int u = (tid >= off && tid < 128) ? sc[tid - off] : 0;
            __syncthreads();
            if (tid < 128) sc[tid] += u;
            __syncthreads();
        }
        int jn0 = j << 7;
        int nNodes = N_NODES - jn0; if (nNodes > 128) nNodes = 128;
        if (tid < 128) {
            int excl = sc[tid] - cnt[tid];
            if (tid < nNodes) row_ptr[jn0 + tid] = lo + excl;   // CSR byproduct
            cnt[tid] = excl;                                     // reuse as cursor
        }
        if (j == NBUCKET - 1 && tid == 0) row_ptr[N_NODES] = lo + span;
        __syncthreads();
        for (int t = tid; t < span; t += 512) {
            int v = eb[t];
            int p = atomicAdd(&cnt[(v >> 16) & 127], 1);
            stage[p] = v & 0xFFFF;
        }
        __syncthreads();
        for (int t = tid; t < span; t += 512) ssrc[lo + t] = stage[t];
        return;
    }

    // ---------------- gemm1 path: 128x256 tile, 8 waves ----------------
    _Float16* As = reinterpret_cast<_Float16*>(smem);          // [128][32]
    _Float16* Bs = reinterpret_cast<_Float16*>(smem + 8192);   // [256][32]
    const int tileM = (blockIdx.x - NBUCKET) * 128;
    const int w = tid >> 6, lane = tid & 63;
    const int wm = (w >> 2) * 64, wn = (w & 3) * 64;
    const int quad = lane >> 4, mlane = lane & 15;
    // A reg-staging: thread covers row arow, 16B chunk apos; swizzled dest
    const int arow = tid >> 2;             // 0..127
    const int apos = tid & 3;
    const int ac   = apos ^ ((arow >> 1) & 3);
    int axr = tileM + arow; if (axr > N_NODES - 1) axr = N_NODES - 1;  // clamp: no OOB read of x
    const float* gx = X + (size_t)axr * 256 + apos * 8;
    // B glld: wave w stages rows [w*32, w*32+32) via 2 glls; swizzled source
    const int lrow = lane >> 2, pos = lane & 3;
    const int brow0 = w * 32 + lrow, brow1 = brow0 + 16;
    const int bc0 = pos ^ ((brow0 >> 1) & 3), bc1 = pos ^ ((brow1 >> 1) & 3);
    const _Float16* gB0 = Bt + (size_t)brow0 * 256 + bc0 * 8;
    const _Float16* gB1 = Bt + (size_t)brow1 * 256 + bc1 * 8;
    _Float16* lB0 = Bs + w * 1024;         // wave-uniform: 16 rows x 64B
    _Float16* lB1 = Bs + w * 1024 + 512;

    f32x4 zero = {0.f, 0.f, 0.f, 0.f};
    f32x4 acc[4][4];
#pragma unroll
    for (int i = 0; i < 4; ++i)
#pragma unroll
        for (int j = 0; j < 4; ++j) acc[i][j] = zero;

    for (int k0 = 0; k0 < 256; k0 += 32) {
        __syncthreads();                   // prior ds_reads done before overwrite
        gll16(gB0 + k0, lB0);
        gll16(gB1 + k0, lB1);
        float4 va = *reinterpret_cast<const float4*>(gx + k0);
        float4 vb = *reinterpret_cast<const float4*>(gx + k0 + 4);
        union { _Float16 h[8]; uint4 u; } pk;
        pk.h[0] = (_Float16)va.x; pk.h[1] = (_Float16)va.y;
        pk.h[2] = (_Float16)va.z; pk.h[3] = (_Float16)va.w;
        pk.h[4] = (_Float16)vb.x; pk.h[5] = (_Float16)vb.y;
        pk.h[6] = (_Float16)vb.z; pk.h[7] = (_Float16)vb.w;
        *reinterpret_cast<uint4*>(As + arow * 32 + ac * 8) = pk.u;
        __syncthreads();                   // vmcnt(0)+lgkmcnt(0) drain + barrier
        half8_t af[4], bf[4];
#pragma unroll
        for (int mt = 0; mt < 4; ++mt) {
            int ra = wm + mt * 16 + mlane;
            af[mt] = *reinterpret_cast<const half8_t*>(As + ra * 32 + ((quad ^ ((ra >> 1) & 3)) << 3));
        }
#pragma unroll
        for (int nt = 0; nt < 4; ++nt) {
            int rb = wn + nt * 16 + mlane;
            bf[nt] = *reinterpret_cast<const half8_t*>(Bs + rb * 32 + ((quad ^ ((rb >> 1) & 3)) << 3));
        }
#pragma unroll
        for (int mt = 0; mt < 4; ++mt)
#pragma unroll
            for (int nt = 0; nt < 4; ++nt)
                acc[mt][nt] = __builtin_amdgcn_mfma_f32_16x16x32_f16(af[mt], bf[nt], acc[mt][nt], 0, 0, 0);
    }
#pragma unroll
    for (int mt = 0; mt < 4; ++mt) {
#pragma unroll
        for (int i = 0; i < 4; ++i) {
            int row = tileM + wm + mt * 16 + quad * 4 + i;
            if (row < N_NODES) {
                _Float16* cp = C + (size_t)row * 256 + wn;
#pragma unroll
                for (int nt = 0; nt < 4; ++nt)
                    cp[nt * 16 + mlane] = (_Float16)acc[mt][nt][i];
            }
        }
    }
    {   // mode-1 epilogue: wave w owns head hd = w&3 entirely (wn = hd*64)
        int hd = w & 3;
        float as[4], ad[4];
#pragma unroll
        for (int nt = 0; nt < 4; ++nt) {
            as[nt] = attS[hd * 64 + nt * 16 + mlane];
            ad[nt] = attD[hd * 64 + nt * 16 + mlane];
        }
#pragma unroll
        for (int mt = 0; mt < 4; ++mt) {
#pragma unroll
            for (int i = 0; i < 4; ++i) {
                float ps = acc[mt][0][i] * as[0] + acc[mt][1][i] * as[1]
                         + acc[mt][2][i] * as[2] + acc[mt][3][i] * as[3];
                float pd = acc[mt][0][i] * ad[0] + acc[mt][1][i] * ad[1]
                         + acc[mt][2][i] * ad[2] + acc[mt][3][i] * ad[3];
#pragma unroll
                for (int off = 1; off < 16; off <<= 1) {
                    ps += __shfl_xor(ps, off);
                    pd += __shfl_xor(pd, off);
                }
                if (mlane == 0) {
                    int row = tileM + wm + mt * 16 + quad * 4 + i;
                    if (row < N_NODES) {
                        a_src_o[row * 4 + hd] = ps;
                        a_dst_o[row * 4 + hd] = pd;
                    }
                }
            }
        }
    }
}

// ---------------------------------------------------------------------------
// GEMM2 (standalone, mode-2 epilogue) — r8 glld+swizzle staging, unchanged.
// ---------------------------------------------------------------------------
__global__ __launch_bounds__(256) void gemm_mfma_kernel(const _Float16* __restrict__ A,
                                                        const _Float16* __restrict__ Bt,
                                                        _Float16* __restrict__ C,
                                                        const float* __restrict__ attS,
                                                        const float* __restrict__ attD,
                                                        float* __restrict__ a_src_o,
                                                        float* __restrict__ a_dst_o,
                                                        int M, int N) {
    __shared__ __align__(16) _Float16 As[4096];   // [128][32] halfs
    __shared__ __align__(16) _Float16 Bs[4096];
    __shared__ float lds_ps[128];
    __shared__ float lds_pd[128];
    const int tid = threadIdx.x;
    const int tileM = blockIdx.x * 128;
    const int tileN = 0;
    const int w = tid >> 6, lane = tid & 63;
    const int wm = (w >> 1) * 64, wn = (w & 1) * 64;
    const int quad = lane >> 4, mlane = lane & 15;
    const int lrow = lane >> 2;
    const int pos  = lane & 3;
    const int ra0  = w * 16 + lrow;
    const int ra1  = ra0 + 64;
    const int ca0  = pos ^ ((ra0 >> 1) & 3);
    const int ca1  = pos ^ ((ra1 >> 1) & 3);

    f32x4 zero = {0.f, 0.f, 0.f, 0.f};
    f32x4 acc[4][4];
#pragma unroll
    for (int i = 0; i < 4; ++i)
#pragma unroll
        for (int j = 0; j < 4; ++j) acc[i][j] = zero;

    const _Float16* gA0 = A + (size_t)(tileM + ra0) * 256 + ca0 * 8;
    const _Float16* gA1 = A + (size_t)(tileM + ra1) * 256 + ca1 * 8;
    const _Float16* gB0 = Bt + (size_t)(tileN + ra0) * 256 + ca0 * 8;
    const _Float16* gB1 = Bt + (size_t)(tileN + ra1) * 256 + ca1 * 8;
    _Float16* lA0 = As + w * 512;
    _Float16* lA1 = As + 2048 + w * 512;
    _Float16* lB0 = Bs + w * 512;
    _Float16* lB1 = Bs + 2048 + w * 512;

    for (int k0 = 0; k0 < 256; k0 += 32) {
        __syncthreads();
        gll16(gA0 + k0, lA0);
        gll16(gA1 + k0, lA1);
        gll16(gB0 + k0, lB0);
        gll16(gB1 + k0, lB1);
        __syncthreads();
        half8_t af[4], bf[4];
#pragma unroll
        for (int mt = 0; mt < 4; ++mt) {
            int ra = wm + mt * 16 + mlane;
            af[mt] = *reinterpret_cast<const half8_t*>(As + ra * 32 + ((quad ^ ((ra >> 1) & 3)) << 3));
        }
#pragma unroll
        for (int nt = 0; nt < 4; ++nt) {
            int rb = wn + nt * 16 + mlane;
            bf[nt] = *reinterpret_cast<const half8_t*>(Bs + rb * 32 + ((quad ^ ((rb >> 1) & 3)) << 3));
        }
#pragma unroll
        for (int mt = 0; mt < 4; ++mt)
#pragma unroll
            for (int nt = 0; nt < 4; ++nt)
                acc[mt][nt] = __builtin_amdgcn_mfma_f32_16x16x32_f16(af[mt], bf[nt], acc[mt][nt], 0, 0, 0);
    }
#pragma unroll
    for (int mt = 0; mt < 4; ++mt) {
#pragma unroll
        for (int i = 0; i < 4; ++i) {
            int row = tileM + wm + mt * 16 + quad * 4 + i;
            if (row < M) {
                _Float16* cp = C + (size_t)row * N + tileN + wn;
#pragma unroll
                for (int nt = 0; nt < 4; ++nt)
                    cp[nt * 16 + mlane] = (_Float16)acc[mt][nt][i];
            }
        }
    }
    {   // mode-2 epilogue: single head, two waves combine via LDS
        float as[4], ad[4];
#pragma unroll
        for (int nt = 0; nt < 4; ++nt) {
            as[nt] = attS[wn + nt * 16 + mlane];
            ad[nt] = attD[wn + nt * 16 + mlane];
        }
        float psa[4][4], pda[4][4];
#pragma unroll
        for (int mt = 0; mt < 4; ++mt) {
#pragma unroll
            for (int i = 0; i < 4; ++i) {
                float ps = acc[mt][0][i] * as[0] + acc[mt][1][i] * as[1]
                         + acc[mt][2][i] * as[2] + acc[mt][3][i] * as[3];
                float pd = acc[mt][0][i] * ad[0] + acc[mt][1][i] * ad[1]
                         + acc[mt][2][i] * ad[2] + acc[mt][3][i] * ad[3];
#pragma unroll
                for (int off = 1; off < 16; off <<= 1) {
                    ps += __shfl_xor(ps, off);
                    pd += __shfl_xor(pd, off);
                }
                psa[mt][i] = ps; pda[mt][i] = pd;
            }
        }
        __syncthreads();
        if (wn == 0 && mlane == 0) {
#pragma unroll
            for (int mt = 0; mt < 4; ++mt)
#pragma unroll
                for (int i = 0; i < 4; ++i) {
                    int lr = wm + mt * 16 + quad * 4 + i;
                    lds_ps[lr] = psa[mt][i];
                    lds_pd[lr] = pda[mt][i];
                }
        }
        __syncthreads();
        if (wn == 64 && mlane == 0) {
#pragma unroll
            for (int mt = 0; mt < 4; ++mt)
#pragma unroll
                for (int i = 0; i < 4; ++i) {
                    int lr = wm + mt * 16 + quad * 4 + i;
                    int row = tileM + lr;
                    if (row < M) {
                        a_src_o[row] = psa[mt][i] + lds_ps[lr];
                        a_dst_o[row] = pda[mt][i] + lds_pd[lr];
                    }
                }
        }
    }
}

__device__ __forceinline__ float lrelu(float x) { return x > 0.f ? x : NEG_SLOPE * x; }

// ---------------------------------------------------------------------------
// Edge aggregation, layer 1 — round-2 form, the verified 65us optimum
// (4 structural variants all land 65±1us: platform random-gather ceiling).
// ---------------------------------------------------------------------------
__global__ __launch_bounds__(256) void edge1_kernel(const int* __restrict__ row_ptr,
                                                    const int* __restrict__ ssrc,
                                                    const __half* __restrict__ h1h,
                                                    const float* __restrict__ a_src,
                                                    const float* __restrict__ a_dst,
                                                    const float* __restrict__ bias,
                                                    __half* __restrict__ out) {
    int node = blockIdx.x * 4 + (threadIdx.x >> 6);
    int lane = threadIdx.x & 63;
    int hf   = lane >> 5;              // 0: even edges, 1: odd edges
    int cl   = lane & 31;              // channel-lane: ch [cl*8, cl*8+8)
    int hd   = cl >> 3;                // head = ch/64
    int start = row_ptr[node], end = row_ptr[node + 1];
    int em1 = end - 1;                 // >= start (self-loop guarantees deg>=1)
    float adh = a_dst[node * 4 + hd];

    const uint4* h1v = reinterpret_cast<const uint4*>(h1h);   // 8 halfs/uint4; 32 per row
    float4 aA0 = make_float4(0.f,0.f,0.f,0.f), aA1 = make_float4(0.f,0.f,0.f,0.f);
    float4 aB0 = make_float4(0.f,0.f,0.f,0.f), aB1 = make_float4(0.f,0.f,0.f,0.f);
    float s = 0.f;
    for (int e = start; e < end; e += 4) {
        int e0 = e + hf;
        int e1 = e + 2 + hf;
        int i0 = ssrc[e0 <= em1 ? e0 : em1];
        int i1 = ssrc[e1 <= em1 ? e1 : em1];
        float r0 = a_src[i0 * 4 + hd];
        float r1 = a_src[i1 * 4 + hd];
        uint4 q0 = h1v[(size_t)i0 * 32 + cl];
        uint4 q1 = h1v[(size_t)i1 * 32 + cl];
        float w0 = (e0 < end) ? __expf(lrelu(r0 + adh)) : 0.f;
        float w1 = (e1 < end) ? __expf(lrelu(r1 + adh)) : 0.f;
        s += w0 + w1;
        float2 f;
        f = __half22float2(*reinterpret_cast<const __half2*>(&q0.x)); aA0.x += w0*f.x; aA0.y += w0*f.y;
        f = __half22float2(*reinterpret_cast<const __half2*>(&q0.y)); aA0.z += w0*f.x; aA0.w += w0*f.y;
        f = __half22float2(*reinterpret_cast<const __half2*>(&q0.z)); aA1.x += w0*f.x; aA1.y += w0*f.y;
        f = __half22float2(*reinterpret_cast<const __half2*>(&q0.w)); aA1.z += w0*f.x; aA1.w += w0*f.y;
        f = __half22float2(*reinterpret_cast<const __half2*>(&q1.x)); aB0.x += w1*f.x; aB0.y += w1*f.y;
        f = __half22float2(*reinterpret_cast<const __half2*>(&q1.y)); aB0.z += w1*f.x; aB0.w += w1*f.y;
        f = __half22float2(*reinterpret_cast<const __half2*>(&q1.z)); aB1.x += w1*f.x; aB1.y += w1*f.y;
        f = __half22float2(*reinterpret_cast<const __half2*>(&q1.w)); aB1.z += w1*f.x; aB1.w += w1*f.y;
    }
    float4 c0, c1;
    c0.x = aA0.x + aB0.x; c0.y = aA0.y + aB0.y; c0.z = aA0.z + aB0.z; c0.w = aA0.w + aB0.w;
    c1.x = aA1.x + aB1.x; c1.y = aA1.y + aB1.y; c1.z = aA1.z + aB1.z; c1.w = aA1.w + aB1.w;
    // fold even/odd halves (lane L and L+32 cover the same channels & head)
    c0.x += __shfl_xor(c0.x, 32); c0.y += __shfl_xor(c0.y, 32);
    c0.z += __shfl_xor(c0.z, 32); c0.w += __shfl_xor(c0.w, 32);
    c1.x += __shfl_xor(c1.x, 32); c1.y += __shfl_xor(c1.y, 32);
    c1.z += __shfl_xor(c1.z, 32); c1.w += __shfl_xor(c1.w, 32);
    s += __shfl_xor(s, 32);
    float inv = 1.0f / (s + EPS_F);
    if (lane < 32) {
        const float4* b4 = reinterpret_cast<const float4*>(bias);
        float4 b0 = b4[cl * 2], b1 = b4[cl * 2 + 1];
        union { _Float16 h[8]; uint4 u; } st;
        st.h[0] = (_Float16)fmaxf(c0.x * inv + b0.x, 0.f);
        st.h[1] = (_Float16)fmaxf(c0.y * inv + b0.y, 0.f);
        st.h[2] = (_Float16)fmaxf(c0.z * inv + b0.z, 0.f);
        st.h[3] = (_Float16)fmaxf(c0.w * inv + b0.w, 0.f);
        st.h[4] = (_Float16)fmaxf(c1.x * inv + b1.x, 0.f);
        st.h[5] = (_Float16)fmaxf(c1.y * inv + b1.y, 0.f);
        st.h[6] = (_Float16)fmaxf(c1.z * inv + b1.z, 0.f);
        st.h[7] = (_Float16)fmaxf(c1.w * inv + b1.w, 0.f);
        reinterpret_cast<uint4*>(out)[(size_t)node * 32 + cl] = st.u;
    }
}

// ---------------------------------------------------------------------------
// Edge aggregation, layer 2 — NEW: 1 node per wave, 4 sub-slots of 16 lanes,
// 8 edges per iteration (deg/8 iterations vs deg/4). Every 16B gather
// instruction stays fully packed (64 lanes = 4 edge-rows x 256B); the
// dependent-chain count per edge HALVES. This lever exists only for edge2
// (128-ch rows need just 16 lanes); edge1's 512B rows can't pack tighter.
// ---------------------------------------------------------------------------
__global__ __launch_bounds__(256) void edge2_kernel(const int* __restrict__ row_ptr,
                                                    const int* __restrict__ ssrc,
                                                    const __half* __restrict__ h2h,
                                                    const float* __restrict__ a_src,
                                                    const float* __restrict__ a_dst,
                                                    const float* __restrict__ bias,
                                                    float* __restrict__ out) {
    int node = blockIdx.x * 4 + (threadIdx.x >> 6);
    int lane = threadIdx.x & 63;
    int sub  = lane >> 4;              // 0..3: edge sub-slot
    int cl   = lane & 15;              // channel-lane: ch [cl*8, cl*8+8)
    int start = row_ptr[node], end = row_ptr[node + 1];
    int em1 = end - 1;
    float ad = a_dst[node];

    const uint4* h2v = reinterpret_cast<const uint4*>(h2h);   // 8 halfs/uint4; 16 per row
    float4 aA0 = make_float4(0.f,0.f,0.f,0.f), aA1 = make_float4(0.f,0.f,0.f,0.f);
    float4 aB0 = make_float4(0.f,0.f,0.f,0.f), aB1 = make_float4(0.f,0.f,0.f,0.f);
    float s = 0.f;
    for (int e = start; e < end; e += 8) {
        int e0 = e + sub;
        int e1 = e + 4 + sub;
        int i0 = ssrc[e0 <= em1 ? e0 : em1];
        int i1 = ssrc[e1 <= em1 ? e1 : em1];
        float r0 = a_src[i0];
        float r1 = a_src[i1];
        uint4 q0 = h2v[(size_t)i0 * 16 + cl];
        uint4 q1 = h2v[(size_t)i1 * 16 + cl];
        float w0 = (e0 < end) ? __expf(lrelu(r0 + ad)) : 0.f;
        float w1 = (e1 < end) ? __expf(lrelu(r1 + ad)) : 0.f;
        s += w0 + w1;
        float2 f;
        f = __half22float2(*reinterpret_cast<const __half2*>(&q0.x)); aA0.x += w0*f.x; aA0.y += w0*f.y;
        f = __half22float2(*reinterpret_cast<const __half2*>(&q0.y)); aA0.z += w0*f.x; aA0.w += w0*f.y;
        f = __half22float2(*reinterpret_cast<const __half2*>(&q0.z)); aA1.x += w0*f.x; aA1.y += w0*f.y;
        f = __half22float2(*reinterpret_cast<const __half2*>(&q0.w)); aA1.z += w0*f.x; aA1.w += w0*f.y;
        f = __half22float2(*reinterpret_cast<const __half2*>(&q1.x)); aB0.x += w1*f.x; aB0.y += w1*f.y;
        f = __half22float2(*reinterpret_cast<const __half2*>(&q1.y)); aB0.z += w1*f.x; aB0.w += w1*f.y;
        f = __half22float2(*reinterpret_cast<const __half2*>(&q1.z)); aB1.x += w1*f.x; aB1.y += w1*f.y;
        f = __half22float2(*reinterpret_cast<const __half2*>(&q1.w)); aB1.z += w1*f.x; aB1.w += w1*f.y;
    }
    float4 c0, c1;
    c0.x = aA0.x + aB0.x; c0.y = aA0.y + aB0.y; c0.z = aA0.z + aB0.z; c0.w = aA0.w + aB0.w;
    c1.x = aA1.x + aB1.x; c1.y = aA1.y + aB1.y; c1.z = aA1.z + aB1.z; c1.w = aA1.w + aB1.w;
    // fold the four 16-lane sub-slots (lanes cl, cl+16, cl+32, cl+48)
    c0.x += __shfl_xor(c0.x, 16); c0.y += __shfl_xor(c0.y, 16);
    c0.z += __shfl_xor(c0.z, 16); c0.w += __shfl_xor(c0.w, 16);
    c1.x += __shfl_xor(c1.x, 16); c1.y += __shfl_xor(c1.y, 16);
    c1.z += __shfl_xor(c1.z, 16); c1.w += __shfl_xor(c1.w, 16);
    c0.x += __shfl_xor(c0.x, 32); c0.y += __shfl_xor(c0.y, 32);
    c0.z += __shfl_xor(c0.z, 32); c0.w += __shfl_xor(c0.w, 32);
    c1.x += __shfl_xor(c1.x, 32); c1.y += __shfl_xor(c1.y, 32);
    c1.z += __shfl_xor(c1.z, 32); c1.w += __shfl_xor(c1.w, 32);
    s += __shfl_xor(s, 16);
    s += __shfl_xor(s, 32);
    float inv = 1.0f / (s + EPS_F);
    if (lane < 16) {                    // 16 lanes write the node's 128-ch row
        const float4* b4 = reinterpret_cast<const float4*>(bias);
        float4 b0 = b4[cl * 2], b1 = b4[cl * 2 + 1];
        float4 o0, o1;
        o0.x = fmaxf(c0.x * inv + b0.x, 0.f);
        o0.y = fmaxf(c0.y * inv + b0.y, 0.f);
        o0.z = fmaxf(c0.z * inv + b0.z, 0.f);
        o0.w = fmaxf(c0.w * inv + b0.w, 0.f);
        o1.x = fmaxf(c1.x * inv + b1.x, 0.f);
        o1.y = fmaxf(c1.y * inv + b1.y, 0.f);
        o1.z = fmaxf(c1.z * inv + b1.z, 0.f);
        o1.w = fmaxf(c1.w * inv + b1.w, 0.f);
        float4* o4 = reinterpret_cast<float4*>(out) + (size_t)node * 32 + cl * 2;
        o4[0] = o0;
        o4[1] = o1;
    }
}

// ---------------------------------------------------------------------------
// Pooling with folded mean division.
// ---------------------------------------------------------------------------
#define POOL_CHUNK 64
__global__ __launch_bounds__(128) void pool_kernel(const float* __restrict__ out2,
                                                   const int* __restrict__ batch,
                                                   const int* __restrict__ gstart,
                                                   float* __restrict__ d_out) {
    int c = threadIdx.x;                 // channel 0..127
    int node0 = blockIdx.x * POOL_CHUNK;
    int nodeEnd = node0 + POOL_CHUNK; if (nodeEnd > N_NODES) nodeEnd = N_NODES;
    if (node0 >= N_NODES) return;
    int gprev = batch[node0];
    float acc = 0.f;
    for (int node = node0; node < nodeEnd; ++node) {
        int g = batch[node];
        if (g != gprev) {
            if (gprev >= 0 && gprev < N_GRAPHS) {
                float cnt = (float)(gstart[gprev + 1] - gstart[gprev]);
                if (cnt < 1.f) cnt = 1.f;
                atomicAdd(&d_out[gprev * 128 + c], acc / cnt);
            }
            acc = 0.f;
            gprev = g;
        }
        acc += out2[(size_t)node * 128 + c];
    }
    if (gprev >= 0 && gprev < N_GRAPHS) {
        float cnt = (float)(gstart[gprev + 1] - gstart[gprev]);
        if (cnt < 1.f) cnt = 1.f;
        atomicAdd(&d_out[gprev * 128 + c], acc / cnt);
    }
}

// ---------------------------------------------------------------------------
extern "C" void kernel_launch(void* const* d_in, const int* in_sizes, int n_in,
                              void* d_out_v, int out_size, void* d_ws, size_t ws_size,
                              hipStream_t stream) {
    const float* x      = (const float*)d_in[0];
    const float* W1     = (const float*)d_in[1];
    const float* att_s1 = (const float*)d_in[2];
    const float* att_d1 = (const float*)d_in[3];
    const float* bias1  = (const float*)d_in[4];
    const float* W2     = (const float*)d_in[5];
    const float* att_s2 = (const float*)d_in[6];
    const float* att_d2 = (const float*)d_in[7];
    const float* bias2  = (const float*)d_in[8];
    const int*   ei     = (const int*)d_in[9];
    const int*   batch  = (const int*)d_in[10];
    float* d_out = (float*)d_out_v;

    // Workspace layout (float units):
    //  [0, 6.4M)        h2h fp16 [N,128] (layer 2)    — xh is GONE (direct-x gemm1)
    //  [6.4M, 12.8M)    h1h fp16 [N,256]  ... later reused as out2 fp32 [N,128]
    //  [12.8M, 19.2M)   out1h fp16 [N,256]
    //  [19.2M, ...)     attention scalars + CSR/sort buffers + W transposes
    float* ws = (float*)d_ws;
    _Float16* h1h   = (_Float16*)(ws + 6400000);
    _Float16* out1h = (_Float16*)(ws + 12800000);
    _Float16* h2h   = (_Float16*)ws;
    float*    out2  = ws + 6400000;             // h1h dead after edge1
    float* a_src1 = ws + 19200000;              // N*4
    float* a_dst1 = a_src1 + 200000;            // N*4
    float* a_src2 = a_dst1 + 200000;            // N
    float* a_dst2 = a_src2 + 50000;             // N
    int* row_ptr  = (int*)(a_dst2 + 50000);     // N+1 (padded to 50016)
    int* ssrc     = row_ptr + 50016;            // E_TOT
    int* ebuf     = ssrc + 850000;              // NBUCKET * EBUF_CAP fixed regions
    int* gcur     = ebuf + (NBUCKET * EBUF_CAP);// 512 (bucket cursors/counts)
    int* gstart   = gcur + 512;                 // N_GRAPHS+1 (pad 128)
    _Float16* W1t = (_Float16*)(gstart + 128);  // 65536 halfs [256][256]
    _Float16* W2t = W1t + 65536;                // 32768 halfs [128][256]

    // 0. gcur must be zero before the bin blocks inside prep run
    hipMemsetAsync(gcur, 0, 512 * sizeof(int), stream);

    // 1. Fused prep: bin + transpose W1/W2 + graph bounds + d_out=0
    prep_kernel<<<PREP_TOTAL, 256, 0, stream>>>(W1, W1t, W2, W2t,
                                                ei, gcur, ebuf,
                                                batch, gstart, d_out);

    // 2. FUSED: bucket sort (391 blocks) + GEMM1 (391 full-N tiles), 512 thr
    sort_gemm1_kernel<<<NBUCKET + GEMM1_MB, 512, 0, stream>>>(
        gcur, ebuf, ssrc, row_ptr, x, W1t, h1h,
        att_s1, att_d1, a_src1, a_dst1);

    // 3. Layer-1 edge aggregation
    edge1_kernel<<<N_NODES / 4, 256, 0, stream>>>(row_ptr, ssrc, (const __half*)h1h,
                                                  a_src1, a_dst1, bias1, (__half*)out1h);

    // 4. GEMM2: h2 = out1 @ W2 (att2 folded via LDS combine)
    gemm_mfma_kernel<<<(N_NODES + 127) / 128, 256, 0, stream>>>(
        out1h, W2t, h2h, att_s2, att_d2, a_src2, a_dst2, N_NODES, OUT_C);

    // 5. Layer-2 edge aggregation (8 edges/iteration, 1 node/wave)
    edge2_kernel<<<N_NODES / 4, 256, 0, stream>>>(row_ptr, ssrc, (const __half*)h2h,
                                                  a_src2, a_dst2, bias2, out2);

    // 6. Pooling (mean division folded into the atomic flush)
    pool_kernel<<<(N_NODES + POOL_CHUNK - 1) / POOL_CHUNK, 128, 0, stream>>>(out2, batch, gstart, d_out);
}